// Round 1
// baseline (1870.885 us; speedup 1.0000x reference)
//
#include <hip/hip_runtime.h>
#include <cstddef>

// Problem constants
// m_in  raw-viewed as mi [128][16384]   fp32
// m_out raw-viewed as mo [512][16384]   fp32
// q_in  = qi [4][128][1024]             fp32
// q_out = qo [4][512][1024]             fp32
// out0  = mem_out [4][1024][1024]  (ch 0..511 = mem, ch 512..1023 = q_out copy)
// out1  = p [4][16384][1024] (post-softmax over the 16384 axis)

#define DE   128
#define DO   512
#define NMEM 16384
#define QCOL 1024
#define NBQ  4

// ---------------------------------------------------------------------------
// K1: raw scores  p[b][n][q] = (1/sqrt(128)) * sum_d mi[d][n] * qi[b][d][q]
// Tiled fp32 GEMM: Mtile=128 (n), Ntile=128 (q), Ktile=8, 256 threads, 8x8/thread
// grid (Q/128=8, N/128=128, B=4)
// ---------------------------------------------------------------------------
__global__ __launch_bounds__(256, 2)
void k1_scores(const float* __restrict__ mi, const float* __restrict__ qi,
               float* __restrict__ p)
{
    const int qb = blockIdx.x << 7;
    const int nb = blockIdx.y << 7;
    const int b  = blockIdx.z;
    const float* __restrict__ qib = qi + (size_t)b * (DE * QCOL);

    __shared__ float As[8][132];
    __shared__ float Bs[8][132];

    const int tid = threadIdx.x;
    const int tx  = tid & 15;
    const int ty  = tid >> 4;

    float acc[8][8];
#pragma unroll
    for (int i = 0; i < 8; ++i)
#pragma unroll
        for (int j = 0; j < 8; ++j) acc[i][j] = 0.f;

    // per-thread load coords: one float4 per tile per buffer
    const int ld_d = tid >> 5;          // 0..7
    const int ld_n = (tid & 31) << 2;   // 0..124 step 4

    for (int k0 = 0; k0 < DE; k0 += 8) {
        float4 av = *(const float4*)(mi  + (size_t)(k0 + ld_d) * NMEM + nb + ld_n);
        float4 bv = *(const float4*)(qib + (size_t)(k0 + ld_d) * QCOL + qb + ld_n);
        *(float4*)&As[ld_d][ld_n] = av;
        *(float4*)&Bs[ld_d][ld_n] = bv;
        __syncthreads();
#pragma unroll
        for (int kk = 0; kk < 8; ++kk) {
            float a[8], bb[8];
            *(float4*)&a[0]  = *(float4*)&As[kk][ty * 8];
            *(float4*)&a[4]  = *(float4*)&As[kk][ty * 8 + 4];
            *(float4*)&bb[0] = *(float4*)&Bs[kk][tx * 8];
            *(float4*)&bb[4] = *(float4*)&Bs[kk][tx * 8 + 4];
#pragma unroll
            for (int i = 0; i < 8; ++i)
#pragma unroll
                for (int j = 0; j < 8; ++j)
                    acc[i][j] += a[i] * bb[j];
        }
        __syncthreads();
    }

    const float scale = 0.08838834764831845f; // 1/sqrt(128)
    float* __restrict__ pb = p + ((size_t)b << 24);
#pragma unroll
    for (int i = 0; i < 8; ++i) {
        const int n = nb + ty * 8 + i;
        float4 v0, v1;
        v0.x = acc[i][0] * scale; v0.y = acc[i][1] * scale;
        v0.z = acc[i][2] * scale; v0.w = acc[i][3] * scale;
        v1.x = acc[i][4] * scale; v1.y = acc[i][5] * scale;
        v1.z = acc[i][6] * scale; v1.w = acc[i][7] * scale;
        *(float4*)(pb + ((size_t)n << 10) + qb + tx * 8)     = v0;
        *(float4*)(pb + ((size_t)n << 10) + qb + tx * 8 + 4) = v1;
    }
}

// ---------------------------------------------------------------------------
// K2a: partial sum of exp over n-chunks (no max subtraction: |p| <~ 8, safe)
// grid (4 qchunks of 256, 16 nchunks of 1024, B). partial[(nc*4+b)*1024 + q]
// ---------------------------------------------------------------------------
__global__ __launch_bounds__(256)
void k2a_psum(const float* __restrict__ p, float* __restrict__ partial)
{
    const int q  = (blockIdx.x << 8) + threadIdx.x;  // 0..1023
    const int n0 = blockIdx.y << 10;
    const int b  = blockIdx.z;
    const float* __restrict__ pb = p + ((size_t)b << 24);
    float s = 0.f;
    for (int n = 0; n < 1024; ++n)
        s += __expf(pb[((size_t)(n0 + n) << 10) + q]);
    partial[(((size_t)blockIdx.y * 4 + b) << 10) + q] = s;
}

// K2b: reduce 16 partials per column -> invsum[b*1024+q]
__global__ __launch_bounds__(256)
void k2b_red(const float* __restrict__ partial, float* __restrict__ invsum)
{
    const int col = blockIdx.x * 256 + threadIdx.x;  // 0..4095
    const int b = col >> 10, q = col & 1023;
    float s = 0.f;
#pragma unroll
    for (int nc = 0; nc < 16; ++nc)
        s += partial[(((size_t)nc * 4 + b) << 10) + q];
    invsum[col] = 1.0f / s;
}

// K3: in-place normalize p = exp(raw) * invsum[b][q]
__global__ __launch_bounds__(256)
void k3_norm(float* __restrict__ p, const float* __restrict__ invsum)
{
    const size_t stride = (size_t)gridDim.x * blockDim.x;
    for (size_t t = (size_t)blockIdx.x * 256 + threadIdx.x; t < 16777216ull; t += stride) {
        const size_t i = t << 2;
        float4 v = *(float4*)(p + i);
        const int q = (int)(i & 1023);
        const int b = (int)(i >> 24);
        const float4 inv = *(const float4*)(invsum + (b << 10) + q);
        v.x = __expf(v.x) * inv.x;
        v.y = __expf(v.y) * inv.y;
        v.z = __expf(v.z) * inv.z;
        v.w = __expf(v.w) * inv.w;
        *(float4*)(p + i) = v;
    }
}

// ---------------------------------------------------------------------------
// K4: mem[b][o][q] = sum_n mo[o][n] * p[b][n][q]
// Tiled fp32 GEMM: Mtile=128 (o), Ntile=64 (q), Ktile=16, 256 threads, 8x4/thread
// grid (Q/64=16, DO/128=4, B=4) = 256 wgs
// ---------------------------------------------------------------------------
__global__ __launch_bounds__(256, 2)
void k4_mem(const float* __restrict__ mo, const float* __restrict__ p,
            float* __restrict__ out0)
{
    const int qb = blockIdx.x << 6;
    const int ob = blockIdx.y << 7;
    const int b  = blockIdx.z;
    const float* __restrict__ pb = p + ((size_t)b << 24);

    __shared__ float As[16][132];  // [kk][o]
    __shared__ float Bs[16][68];   // [kk][q]

    const int tid = threadIdx.x;
    const int tx  = tid & 15;
    const int ty  = tid >> 4;

    float acc[8][4];
#pragma unroll
    for (int i = 0; i < 8; ++i)
#pragma unroll
        for (int j = 0; j < 4; ++j) acc[i][j] = 0.f;

    // A load coords: 2 float4 along k per thread (o and o+64)
    const int a_o  = tid >> 2;          // 0..63
    const int a_k4 = (tid & 3) << 2;    // 0,4,8,12
    // B load coords: 1 float4 per thread
    const int b_k = tid >> 4;           // 0..15
    const int b_q = (tid & 15) << 2;    // 0..60 step 4

    const float* __restrict__ moA = mo + (size_t)ob * NMEM;

    for (int k0 = 0; k0 < NMEM; k0 += 16) {
        float4 a0 = *(const float4*)(moA + (size_t)a_o * NMEM        + k0 + a_k4);
        float4 a1 = *(const float4*)(moA + (size_t)(a_o + 64) * NMEM + k0 + a_k4);
        float4 bv = *(const float4*)(pb + ((size_t)(k0 + b_k) << 10) + qb + b_q);
        As[a_k4 + 0][a_o] = a0.x; As[a_k4 + 1][a_o] = a0.y;
        As[a_k4 + 2][a_o] = a0.z; As[a_k4 + 3][a_o] = a0.w;
        As[a_k4 + 0][a_o + 64] = a1.x; As[a_k4 + 1][a_o + 64] = a1.y;
        As[a_k4 + 2][a_o + 64] = a1.z; As[a_k4 + 3][a_o + 64] = a1.w;
        *(float4*)&Bs[b_k][b_q] = bv;
        __syncthreads();
#pragma unroll
        for (int kk = 0; kk < 16; ++kk) {
            float a[8], bb[4];
            *(float4*)&a[0]  = *(float4*)&As[kk][ty * 8];
            *(float4*)&a[4]  = *(float4*)&As[kk][ty * 8 + 4];
            *(float4*)&bb[0] = *(float4*)&Bs[kk][tx * 4];
#pragma unroll
            for (int i = 0; i < 8; ++i)
#pragma unroll
                for (int j = 0; j < 4; ++j)
                    acc[i][j] += a[i] * bb[j];
        }
        __syncthreads();
    }

    // out0[((b*1024) + ob + o)*1024 + qb + q]
#pragma unroll
    for (int i = 0; i < 8; ++i) {
        const int o = ob + ty * 8 + i;
        float4 v;
        v.x = acc[i][0]; v.y = acc[i][1]; v.z = acc[i][2]; v.w = acc[i][3];
        *(float4*)(out0 + (((size_t)b << 10) + o) * 1024 + qb + tx * 4) = v;
    }
}

// K5: copy q_out into out0 channels 512..1023
__global__ __launch_bounds__(256)
void k5_copy(const float* __restrict__ qo, float* __restrict__ out0)
{
    const size_t t = (size_t)blockIdx.x * 256 + threadIdx.x;  // 0..524287
    if (t < 524288ull) {
        const size_t i = t << 2;
        const size_t b = i >> 19;  // 524288 floats per batch in q_out
        const float4 v = *(const float4*)(qo + i);
        *(float4*)(out0 + i + ((b + 1) << 19)) = v;
    }
}

extern "C" void kernel_launch(void* const* d_in, const int* in_sizes, int n_in,
                              void* d_out, int out_size, void* d_ws, size_t ws_size,
                              hipStream_t stream)
{
    const float* m_in  = (const float*)d_in[0];
    const float* m_out = (const float*)d_in[1];
    const float* q_in  = (const float*)d_in[2];
    const float* q_out = (const float*)d_in[3];

    float* out0 = (float*)d_out;              // 4,194,304 floats
    float* p    = out0 + 4194304;             // 67,108,864 floats

    // scratch inside out0's b=0 q_out-copy region (overwritten later by k5)
    float* partial = out0 + 524288;           // 65,536 floats
    float* invsum  = out0 + 524288 + 65536;   // 4,096 floats

    k1_scores<<<dim3(8, 128, 4), 256, 0, stream>>>(m_in, q_in, p);
    k2a_psum <<<dim3(4, 16, 4),  256, 0, stream>>>(p, partial);
    k2b_red  <<<dim3(16),        256, 0, stream>>>(partial, invsum);
    k3_norm  <<<dim3(2048),      256, 0, stream>>>(p, invsum);
    k4_mem   <<<dim3(16, 4, 4),  256, 0, stream>>>(m_out, p, out0);
    k5_copy  <<<dim3(2048),      256, 0, stream>>>(q_out, out0);
}

// Round 2
// 943.549 us; speedup vs baseline: 1.9828x; 1.9828x over previous
//
#include <hip/hip_runtime.h>
#include <hip/hip_bf16.h>
#include <cstddef>

// Problem constants
// m_in  raw-viewed as mi [128][16384]   fp32
// m_out raw-viewed as mo [512][16384]   fp32
// q_in  = qi [4][128][1024]             fp32
// q_out = qo [4][512][1024]             fp32
// out0  = mem_out [4][1024][1024]  (ch 0..511 = mem, ch 512..1023 = q_out copy)
// out1  = p [4][16384][1024] (post-softmax over the 16384 axis)

#define DE   128
#define DO   512
#define NMEM 16384
#define QCOL 1024

typedef __attribute__((ext_vector_type(8))) short  short8v;  // bf16x8 MFMA frag
typedef __attribute__((ext_vector_type(4))) short  short4v;  // bf16x4 (8B LDS store)
typedef __attribute__((ext_vector_type(4))) float  f32x4;

__device__ __forceinline__ short f2bf(float x) {
    union { __hip_bfloat16 h; short s; } u;
    u.h = __float2bfloat16(x);
    return u.s;
}

// ---------------------------------------------------------------------------
// K1: raw scores  p[b][n][q] = (1/sqrt(128)) * sum_d mi[d][n] * qi[b][d][q]
// (unchanged fp32 tiled GEMM this round)
// ---------------------------------------------------------------------------
__global__ __launch_bounds__(256, 2)
void k1_scores(const float* __restrict__ mi, const float* __restrict__ qi,
               float* __restrict__ p)
{
    const int qb = blockIdx.x << 7;
    const int nb = blockIdx.y << 7;
    const int b  = blockIdx.z;
    const float* __restrict__ qib = qi + (size_t)b * (DE * QCOL);

    __shared__ float As[8][132];
    __shared__ float Bs[8][132];

    const int tid = threadIdx.x;
    const int tx  = tid & 15;
    const int ty  = tid >> 4;

    float acc[8][8];
#pragma unroll
    for (int i = 0; i < 8; ++i)
#pragma unroll
        for (int j = 0; j < 8; ++j) acc[i][j] = 0.f;

    const int ld_d = tid >> 5;
    const int ld_n = (tid & 31) << 2;

    for (int k0 = 0; k0 < DE; k0 += 8) {
        float4 av = *(const float4*)(mi  + (size_t)(k0 + ld_d) * NMEM + nb + ld_n);
        float4 bv = *(const float4*)(qib + (size_t)(k0 + ld_d) * QCOL + qb + ld_n);
        *(float4*)&As[ld_d][ld_n] = av;
        *(float4*)&Bs[ld_d][ld_n] = bv;
        __syncthreads();
#pragma unroll
        for (int kk = 0; kk < 8; ++kk) {
            float a[8], bb[8];
            *(float4*)&a[0]  = *(float4*)&As[kk][ty * 8];
            *(float4*)&a[4]  = *(float4*)&As[kk][ty * 8 + 4];
            *(float4*)&bb[0] = *(float4*)&Bs[kk][tx * 8];
            *(float4*)&bb[4] = *(float4*)&Bs[kk][tx * 8 + 4];
#pragma unroll
            for (int i = 0; i < 8; ++i)
#pragma unroll
                for (int j = 0; j < 8; ++j)
                    acc[i][j] += a[i] * bb[j];
        }
        __syncthreads();
    }

    const float scale = 0.08838834764831845f; // 1/sqrt(128)
    float* __restrict__ pb = p + ((size_t)b << 24);
#pragma unroll
    for (int i = 0; i < 8; ++i) {
        const int n = nb + ty * 8 + i;
        float4 v0, v1;
        v0.x = acc[i][0] * scale; v0.y = acc[i][1] * scale;
        v0.z = acc[i][2] * scale; v0.w = acc[i][3] * scale;
        v1.x = acc[i][4] * scale; v1.y = acc[i][5] * scale;
        v1.z = acc[i][6] * scale; v1.w = acc[i][7] * scale;
        *(float4*)(pb + ((size_t)n << 10) + qb + tx * 8)     = v0;
        *(float4*)(pb + ((size_t)n << 10) + qb + tx * 8 + 4) = v1;
    }
}

// ---------------------------------------------------------------------------
// K2a: partial sum of exp over n-chunks (no max subtraction: |score| <~ 8)
// ---------------------------------------------------------------------------
__global__ __launch_bounds__(256)
void k2a_psum(const float* __restrict__ p, float* __restrict__ partial)
{
    const int q  = (blockIdx.x << 8) + threadIdx.x;
    const int n0 = blockIdx.y << 10;
    const int b  = blockIdx.z;
    const float* __restrict__ pb = p + ((size_t)b << 24);
    float s = 0.f;
    for (int n = 0; n < 1024; ++n)
        s += __expf(pb[((size_t)(n0 + n) << 10) + q]);
    partial[(((size_t)blockIdx.y * 4 + b) << 10) + q] = s;
}

__global__ __launch_bounds__(256)
void k2b_red(const float* __restrict__ partial, float* __restrict__ invsum)
{
    const int col = blockIdx.x * 256 + threadIdx.x;
    const int b = col >> 10, q = col & 1023;
    float s = 0.f;
#pragma unroll
    for (int nc = 0; nc < 16; ++nc)
        s += partial[(((size_t)nc * 4 + b) << 10) + q];
    invsum[col] = 1.0f / s;
}

// K3: in-place normalize p = exp(raw) * invsum[b][q]
__global__ __launch_bounds__(256)
void k3_norm(float* __restrict__ p, const float* __restrict__ invsum)
{
    const size_t stride = (size_t)gridDim.x * blockDim.x;
    for (size_t t = (size_t)blockIdx.x * 256 + threadIdx.x; t < 16777216ull; t += stride) {
        const size_t i = t << 2;
        float4 v = *(float4*)(p + i);
        const int q = (int)(i & 1023);
        const int b = (int)(i >> 24);
        const float4 inv = *(const float4*)(invsum + (b << 10) + q);
        v.x = __expf(v.x) * inv.x;
        v.y = __expf(v.y) * inv.y;
        v.z = __expf(v.z) * inv.z;
        v.w = __expf(v.w) * inv.w;
        *(float4*)(p + i) = v;
    }
}

// ---------------------------------------------------------------------------
// K4 (NEW): mem[b][o][q] = sum_n mo[o][n] * p[b][n][q]  via bf16 MFMA
// Tile 64(o) x 64(q), BK=32, 256 threads = 4 waves, each wave a 32x32 subtile
// (2x2 frags of 16x16x32). Double-buffered LDS, fp32->bf16 cvt during staging,
// p transposed 4x4-in-register so both LDS tiles are [row][k] k-contiguous.
// grid (16 qtiles, 8 otiles, 4 b) = 512 wgs.
// ---------------------------------------------------------------------------
#define LDK 40   // shorts per LDS row: 32 + 8 pad (80B = 5*16B, b128-aligned)

__global__ __launch_bounds__(256, 2)
void k4_mfma(const float* __restrict__ mo, const float* __restrict__ p,
             float* __restrict__ out0)
{
    const int qb = blockIdx.x << 6;
    const int ob = blockIdx.y << 6;
    const int b  = blockIdx.z;
    const float* __restrict__ pb = p + ((size_t)b << 24);

    __shared__ __align__(16) short As[2][64 * LDK];  // [o][k]
    __shared__ __align__(16) short Bs[2][64 * LDK];  // [q][k]

    const int tid  = threadIdx.x;
    const int lane = tid & 63;
    const int w    = tid >> 6;
    const int wm   = (w >> 1) << 5;   // 0/32 (o)
    const int wn   = (w & 1) << 5;    // 0/32 (q)

    const bool isB = tid < 128;
    // B staging: thread owns a 4k x 4q transpose block
    const int b_k = (tid >> 4) << 2;        // 0..28
    const int b_q = (tid & 15) << 2;        // 0..60
    // A staging: 4 float4, rows o = a_ob + j*16, k-quad a_k
    const int a_ob = (tid - 128) >> 3;      // 0..15
    const int a_k  = ((tid - 128) & 7) << 2;// 0..28

    f32x4 ld[4];

#define K4_LOAD(K0)                                                              \
    do {                                                                         \
        if (isB) {                                                               \
            _Pragma("unroll")                                                    \
            for (int i = 0; i < 4; ++i)                                          \
                ld[i] = *(const f32x4*)(pb + ((size_t)((K0) + b_k + i) << 10)    \
                                           + qb + b_q);                          \
        } else {                                                                 \
            _Pragma("unroll")                                                    \
            for (int j = 0; j < 4; ++j)                                          \
                ld[j] = *(const f32x4*)(mo + (size_t)(ob + a_ob + j * 16) * NMEM \
                                           + (K0) + a_k);                        \
        }                                                                        \
    } while (0)

#define K4_STORE(BUF)                                                            \
    do {                                                                         \
        if (isB) {                                                               \
            _Pragma("unroll")                                                    \
            for (int j = 0; j < 4; ++j) {                                        \
                short4v v;                                                       \
                v.x = f2bf(ld[0][j]); v.y = f2bf(ld[1][j]);                      \
                v.z = f2bf(ld[2][j]); v.w = f2bf(ld[3][j]);                      \
                *(short4v*)&Bs[BUF][(b_q + j) * LDK + b_k] = v;                  \
            }                                                                    \
        } else {                                                                 \
            _Pragma("unroll")                                                    \
            for (int j = 0; j < 4; ++j) {                                        \
                short4v v;                                                       \
                v.x = f2bf(ld[j][0]); v.y = f2bf(ld[j][1]);                      \
                v.z = f2bf(ld[j][2]); v.w = f2bf(ld[j][3]);                      \
                *(short4v*)&As[BUF][(a_ob + j * 16) * LDK + a_k] = v;            \
            }                                                                    \
        }                                                                        \
    } while (0)

    f32x4 acc00 = {0.f,0.f,0.f,0.f}, acc01 = {0.f,0.f,0.f,0.f};
    f32x4 acc10 = {0.f,0.f,0.f,0.f}, acc11 = {0.f,0.f,0.f,0.f};

    // prologue: tile 0 -> buf0
    K4_LOAD(0);
    K4_STORE(0);
    __syncthreads();

    const int ar = (wm + (lane & 15)) * LDK + ((lane >> 4) << 3);
    const int br = (wn + (lane & 15)) * LDK + ((lane >> 4) << 3);

    int cur = 0;
    for (int t = 0; t < NMEM / 32; ++t) {
        const bool pf = (t + 1) < NMEM / 32;
        if (pf) K4_LOAD((t + 1) * 32);

        short8v a0 = *(const short8v*)&As[cur][ar];
        short8v a1 = *(const short8v*)&As[cur][ar + 16 * LDK];
        short8v b0 = *(const short8v*)&Bs[cur][br];
        short8v b1 = *(const short8v*)&Bs[cur][br + 16 * LDK];
        acc00 = __builtin_amdgcn_mfma_f32_16x16x32_bf16(a0, b0, acc00, 0, 0, 0);
        acc01 = __builtin_amdgcn_mfma_f32_16x16x32_bf16(a0, b1, acc01, 0, 0, 0);
        acc10 = __builtin_amdgcn_mfma_f32_16x16x32_bf16(a1, b0, acc10, 0, 0, 0);
        acc11 = __builtin_amdgcn_mfma_f32_16x16x32_bf16(a1, b1, acc11, 0, 0, 0);

        if (pf) K4_STORE(cur ^ 1);
        __syncthreads();
        cur ^= 1;
    }

    // epilogue: C/D layout col=lane&15, row=(lane>>4)*4+r
    const int orow = ob + wm + ((lane >> 4) << 2);
    const int qcol = qb + wn + (lane & 15);
    float* __restrict__ outb = out0 + ((size_t)b << 20);
#pragma unroll
    for (int r = 0; r < 4; ++r) {
        outb[(size_t)(orow + r)      * 1024 + qcol]      = acc00[r];
        outb[(size_t)(orow + r)      * 1024 + qcol + 16] = acc01[r];
        outb[(size_t)(orow + r + 16) * 1024 + qcol]      = acc10[r];
        outb[(size_t)(orow + r + 16) * 1024 + qcol + 16] = acc11[r];
    }
#undef K4_LOAD
#undef K4_STORE
}

// K5: copy q_out into out0 channels 512..1023
__global__ __launch_bounds__(256)
void k5_copy(const float* __restrict__ qo, float* __restrict__ out0)
{
    const size_t t = (size_t)blockIdx.x * 256 + threadIdx.x;
    if (t < 524288ull) {
        const size_t i = t << 2;
        const size_t b = i >> 19;
        const float4 v = *(const float4*)(qo + i);
        *(float4*)(out0 + i + ((b + 1) << 19)) = v;
    }
}

extern "C" void kernel_launch(void* const* d_in, const int* in_sizes, int n_in,
                              void* d_out, int out_size, void* d_ws, size_t ws_size,
                              hipStream_t stream)
{
    const float* m_in  = (const float*)d_in[0];
    const float* m_out = (const float*)d_in[1];
    const float* q_in  = (const float*)d_in[2];
    const float* q_out = (const float*)d_in[3];

    float* out0 = (float*)d_out;              // 4,194,304 floats
    float* p    = out0 + 4194304;             // 67,108,864 floats

    // scratch inside out0's b=0 q_out-copy region (overwritten later by k5)
    float* partial = out0 + 524288;           // 65,536 floats
    float* invsum  = out0 + 524288 + 65536;   // 4,096 floats

    k1_scores<<<dim3(8, 128, 4), 256, 0, stream>>>(m_in, q_in, p);
    k2a_psum <<<dim3(4, 16, 4),  256, 0, stream>>>(p, partial);
    k2b_red  <<<dim3(16),        256, 0, stream>>>(partial, invsum);
    k3_norm  <<<dim3(2048),      256, 0, stream>>>(p, invsum);
    k4_mfma  <<<dim3(16, 8, 4),  256, 0, stream>>>(m_out, p, out0);
    k5_copy  <<<dim3(2048),      256, 0, stream>>>(q_out, out0);
}

// Round 3
// 600.872 us; speedup vs baseline: 3.1136x; 1.5703x over previous
//
#include <hip/hip_runtime.h>
#include <hip/hip_bf16.h>
#include <cstddef>

// m_in  raw-viewed as mi [128][16384]   fp32
// m_out raw-viewed as mo [512][16384]   fp32
// q_in  = qi [4][128][1024]             fp32
// q_out = qo [4][512][1024]             fp32
// out0  = mem_out [4][1024][1024]  (ch 0..511 = mem, ch 512..1023 = q_out copy)
// out1  = p [4][16384][1024] softmax over the 16384 axis

#define DE   128
#define DO   512
#define NMEM 16384
#define QCOL 1024

typedef __attribute__((ext_vector_type(8))) short  short8v;
typedef __attribute__((ext_vector_type(4))) short  short4v;
typedef __attribute__((ext_vector_type(4))) float  f32x4;

__device__ __forceinline__ short f2bf(float x) {
    union { __hip_bfloat16 h; short s; } u;
    u.h = __float2bfloat16(x);
    return u.s;
}

// ---------------------------------------------------------------------------
// K1: e[b][n][q] = exp(score * 1/sqrt(128)); also per-(128n)-tile column sums
// fp32 tiled GEMM 128x128, Ktile=8, 256 thr, 8x8/thread. grid (8,128,4).
// partial[ntile(128)][b(4)][q(1024)]
// ---------------------------------------------------------------------------
__global__ __launch_bounds__(256, 2)
void k1_scores(const float* __restrict__ mi, const float* __restrict__ qi,
               float* __restrict__ p, float* __restrict__ partial)
{
    const int qb = blockIdx.x << 7;
    const int nb = blockIdx.y << 7;
    const int b  = blockIdx.z;
    const float* __restrict__ qib = qi + (size_t)b * (DE * QCOL);

    __shared__ float As[8][132];
    __shared__ float Bs[8][132];
    __shared__ float red[16][128];

    const int tid = threadIdx.x;
    const int tx  = tid & 15;
    const int ty  = tid >> 4;

    float acc[8][8];
#pragma unroll
    for (int i = 0; i < 8; ++i)
#pragma unroll
        for (int j = 0; j < 8; ++j) acc[i][j] = 0.f;

    const int ld_d = tid >> 5;
    const int ld_n = (tid & 31) << 2;

    for (int k0 = 0; k0 < DE; k0 += 8) {
        float4 av = *(const float4*)(mi  + (size_t)(k0 + ld_d) * NMEM + nb + ld_n);
        float4 bv = *(const float4*)(qib + (size_t)(k0 + ld_d) * QCOL + qb + ld_n);
        *(float4*)&As[ld_d][ld_n] = av;
        *(float4*)&Bs[ld_d][ld_n] = bv;
        __syncthreads();
#pragma unroll
        for (int kk = 0; kk < 8; ++kk) {
            float a[8], bb[8];
            *(float4*)&a[0]  = *(float4*)&As[kk][ty * 8];
            *(float4*)&a[4]  = *(float4*)&As[kk][ty * 8 + 4];
            *(float4*)&bb[0] = *(float4*)&Bs[kk][tx * 8];
            *(float4*)&bb[4] = *(float4*)&Bs[kk][tx * 8 + 4];
#pragma unroll
            for (int i = 0; i < 8; ++i)
#pragma unroll
                for (int j = 0; j < 8; ++j)
                    acc[i][j] += a[i] * bb[j];
        }
        __syncthreads();
    }

    const float scale = 0.08838834764831845f; // 1/sqrt(128)
    float* __restrict__ pb = p + ((size_t)b << 24);
    float cs[8];
#pragma unroll
    for (int j = 0; j < 8; ++j) cs[j] = 0.f;

#pragma unroll
    for (int i = 0; i < 8; ++i) {
        const int n = nb + ty * 8 + i;
        float e[8];
#pragma unroll
        for (int j = 0; j < 8; ++j) {
            e[j] = __expf(acc[i][j] * scale);
            cs[j] += e[j];
        }
        *(float4*)(pb + ((size_t)n << 10) + qb + tx * 8)     = *(float4*)&e[0];
        *(float4*)(pb + ((size_t)n << 10) + qb + tx * 8 + 4) = *(float4*)&e[4];
    }

    // column-sum reduce over ty (16) for each of the block's 128 q columns
#pragma unroll
    for (int j = 0; j < 8; ++j) red[ty][tx * 8 + j] = cs[j];
    __syncthreads();
    if (tid < 128) {
        float s = 0.f;
#pragma unroll
        for (int t = 0; t < 16; ++t) s += red[t][tid];
        partial[(size_t)blockIdx.y * 4096 + (b << 10) + qb + tid] = s;
    }
}

// K2b: invsum[b*1024+q] = 1 / sum over 128 ntile partials
__global__ __launch_bounds__(256)
void k2b_red(const float* __restrict__ partial, float* __restrict__ invsum)
{
    const int col = blockIdx.x * 256 + threadIdx.x;  // 0..4095
    float s = 0.f;
    for (int nt = 0; nt < 128; ++nt)
        s += partial[(size_t)nt * 4096 + col];
    invsum[col] = 1.0f / s;
}

// K3: in-place normalize p = e * invsum[b][q]  (exp already applied in k1)
__global__ __launch_bounds__(256)
void k3_norm(float* __restrict__ p, const float* __restrict__ invsum)
{
    const size_t stride = (size_t)gridDim.x * blockDim.x;
    for (size_t t = (size_t)blockIdx.x * 256 + threadIdx.x; t < 16777216ull; t += stride) {
        const size_t i = t << 2;
        float4 v = *(float4*)(p + i);
        const int q = (int)(i & 1023);
        const int b = (int)(i >> 24);
        const float4 inv = *(const float4*)(invsum + (b << 10) + q);
        v.x *= inv.x; v.y *= inv.y; v.z *= inv.z; v.w *= inv.w;
        *(float4*)(p + i) = v;
    }
}

// ---------------------------------------------------------------------------
// K4: mem[b][o][q] = sum_n mo[o][n] * p[b][n][q]  via bf16 MFMA
// Tile 64x64, BK=64, 256 thr = 4 waves (each 32x32 = 2x2 frags, 2 k-slices
// -> 8 MFMA/step). LDS rows exactly 64 bf16 (128B) with bijective 16B-granule
// XOR swizzle: granule ^= (row&7) -> 2-way banks (free) on b128 frag reads.
// Double-buffered. grid (16,8,4)=512 wgs.
// ---------------------------------------------------------------------------
__global__ __launch_bounds__(256, 4)
void k4_mfma(const float* __restrict__ mo, const float* __restrict__ p,
             float* __restrict__ out0)
{
    const int qb = blockIdx.x << 6;
    const int ob = blockIdx.y << 6;
    const int b  = blockIdx.z;
    const float* __restrict__ pb = p + ((size_t)b << 24);

    __shared__ __align__(16) short As[2][64 * 64];  // [o][k] swizzled
    __shared__ __align__(16) short Bs[2][64 * 64];  // [q][k(=n)] swizzled

    const int tid  = threadIdx.x;
    const int lane = tid & 63;
    const int w    = tid >> 6;
    const int wm   = (w >> 1) << 5;   // 0/32 (o)
    const int wn   = (w & 1) << 5;    // 0/32 (q)

    // A staging: thread loads 4 f32x4: rows o = aro+16j, k quad ak4
    const int aro = tid >> 4;               // 0..15
    const int ak4 = (tid & 15) << 2;        // 0..60
    const int sA  = aro * 64 + ((((ak4 >> 3) ^ (aro & 7))) << 3) + (ak4 & 7);
    // B staging: thread loads 4x4 block: n = bn+i, q = bq4+j; writes transposed
    const int bn  = (tid >> 4) << 2;        // 0..60
    const int bq4 = (tid & 15) << 2;        // 0..60
    const int bg  = bn >> 3;                // k granule of the 4-short write
    const int bko = bn & 7;                 // 0 or 4

    f32x4 aA[4], aB[4];

#define K4_LOAD(K0)                                                              \
    do {                                                                         \
        _Pragma("unroll")                                                        \
        for (int j = 0; j < 4; ++j)                                              \
            aA[j] = *(const f32x4*)(mo + (size_t)(ob + aro + 16 * j) * NMEM      \
                                       + (K0) + ak4);                            \
        _Pragma("unroll")                                                        \
        for (int i = 0; i < 4; ++i)                                              \
            aB[i] = *(const f32x4*)(pb + ((size_t)((K0) + bn + i) << 10)         \
                                       + qb + bq4);                              \
    } while (0)

#define K4_STORE(BUF)                                                            \
    do {                                                                         \
        _Pragma("unroll")                                                        \
        for (int j = 0; j < 4; ++j) {                                            \
            short4v v;                                                           \
            v.x = f2bf(aA[j][0]); v.y = f2bf(aA[j][1]);                          \
            v.z = f2bf(aA[j][2]); v.w = f2bf(aA[j][3]);                          \
            *(short4v*)&As[BUF][sA + j * 1024] = v;                              \
        }                                                                        \
        _Pragma("unroll")                                                        \
        for (int j = 0; j < 4; ++j) {                                            \
            short4v v;                                                           \
            v.x = f2bf(aB[0][j]); v.y = f2bf(aB[1][j]);                          \
            v.z = f2bf(aB[2][j]); v.w = f2bf(aB[3][j]);                          \
            const int r = bq4 + j;                                               \
            *(short4v*)&Bs[BUF][r * 64 + ((bg ^ (r & 7)) << 3) + bko] = v;       \
        }                                                                        \
    } while (0)

    f32x4 acc[2][2];
#pragma unroll
    for (int i = 0; i < 2; ++i)
#pragma unroll
        for (int j = 0; j < 2; ++j) acc[i][j] = (f32x4){0.f, 0.f, 0.f, 0.f};

    K4_LOAD(0);
    K4_STORE(0);
    __syncthreads();

    const int la = lane & 15;
    const int kg = lane >> 4;          // 0..3
    const int ar = wm + la;            // A frag row base
    const int br = wn + la;            // B frag row base
    const int a7 = ar & 7;
    const int b7 = br & 7;

    int cur = 0;
    for (int t = 0; t < NMEM / 64; ++t) {
        const bool pf = (t + 1) < NMEM / 64;
        if (pf) K4_LOAD((t + 1) * 64);

        short8v af[2][2], bf[2][2];
#pragma unroll
        for (int fm = 0; fm < 2; ++fm)
#pragma unroll
            for (int s = 0; s < 2; ++s)
                af[fm][s] = *(const short8v*)
                    &As[cur][(ar + 16 * fm) * 64 + ((((s << 2) + kg) ^ a7) << 3)];
#pragma unroll
        for (int fn = 0; fn < 2; ++fn)
#pragma unroll
            for (int s = 0; s < 2; ++s)
                bf[fn][s] = *(const short8v*)
                    &Bs[cur][(br + 16 * fn) * 64 + ((((s << 2) + kg) ^ b7) << 3)];

#pragma unroll
        for (int fm = 0; fm < 2; ++fm)
#pragma unroll
            for (int fn = 0; fn < 2; ++fn) {
                acc[fm][fn] = __builtin_amdgcn_mfma_f32_16x16x32_bf16(
                    af[fm][0], bf[fn][0], acc[fm][fn], 0, 0, 0);
                acc[fm][fn] = __builtin_amdgcn_mfma_f32_16x16x32_bf16(
                    af[fm][1], bf[fn][1], acc[fm][fn], 0, 0, 0);
            }

        if (pf) K4_STORE(cur ^ 1);
        __syncthreads();
        cur ^= 1;
    }

    // epilogue: C/D layout col=lane&15, row=(lane>>4)*4+r
    const int orow = ob + wm + (kg << 2);
    const int qcol = qb + wn + la;
    float* __restrict__ outb = out0 + ((size_t)b << 20);
#pragma unroll
    for (int fm = 0; fm < 2; ++fm)
#pragma unroll
        for (int fn = 0; fn < 2; ++fn)
#pragma unroll
            for (int r = 0; r < 4; ++r)
                outb[(size_t)(orow + 16 * fm + r) * 1024 + qcol + 16 * fn] =
                    acc[fm][fn][r];
#undef K4_LOAD
#undef K4_STORE
}

// K5: copy q_out into out0 channels 512..1023 (also wipes scratch regions)
__global__ __launch_bounds__(256)
void k5_copy(const float* __restrict__ qo, float* __restrict__ out0)
{
    const size_t t = (size_t)blockIdx.x * 256 + threadIdx.x;
    if (t < 524288ull) {
        const size_t i = t << 2;
        const size_t b = i >> 19;
        const float4 v = *(const float4*)(qo + i);
        *(float4*)(out0 + i + ((b + 1) << 19)) = v;
    }
}

extern "C" void kernel_launch(void* const* d_in, const int* in_sizes, int n_in,
                              void* d_out, int out_size, void* d_ws, size_t ws_size,
                              hipStream_t stream)
{
    const float* m_in  = (const float*)d_in[0];
    const float* m_out = (const float*)d_in[1];
    const float* q_in  = (const float*)d_in[2];
    const float* q_out = (const float*)d_in[3];

    float* out0 = (float*)d_out;              // 4,194,304 floats
    float* p    = out0 + 4194304;             // 67,108,864 floats

    // scratch in out0's q_out-copy regions (overwritten later by k5):
    // b=0 region: partial[128][4][1024] = 524288 floats (exact fit)
    // b=1 region: invsum[4][1024]
    float* partial = out0 + 524288;
    float* invsum  = out0 + 1048576 + 524288;

    k1_scores<<<dim3(8, 128, 4), 256, 0, stream>>>(m_in, q_in, p, partial);
    k2b_red  <<<dim3(16),        256, 0, stream>>>(partial, invsum);
    k3_norm  <<<dim3(2048),      256, 0, stream>>>(p, invsum);
    k4_mfma  <<<dim3(16, 8, 4),  256, 0, stream>>>(m_out, p, out0);
    k5_copy  <<<dim3(2048),      256, 0, stream>>>(q_out, out0);
}

// Round 4
// 591.893 us; speedup vs baseline: 3.1608x; 1.0152x over previous
//
#include <hip/hip_runtime.h>
#include <hip/hip_bf16.h>
#include <cstddef>

// m_in  raw-viewed as mi [128][16384]   fp32
// m_out raw-viewed as mo [512][16384]   fp32
// q_in  = qi [4][128][1024]             fp32
// q_out = qo [4][512][1024]             fp32
// out0  = mem_out [4][1024][1024]  (ch 0..511 = mem, ch 512..1023 = q_out copy)
// out1  = p [4][16384][1024] softmax over the 16384 axis

#define DE   128
#define DO   512
#define NMEM 16384
#define QCOL 1024

typedef __attribute__((ext_vector_type(8))) short  short8v;
typedef __attribute__((ext_vector_type(4))) short  short4v;
typedef __attribute__((ext_vector_type(4))) float  f32x4;

__device__ __forceinline__ short f2bf(float x) {
    union { __hip_bfloat16 h; short s; } u;
    u.h = __float2bfloat16(x);
    return u.s;
}
__device__ __forceinline__ float bf2f(short s) {
    union { __hip_bfloat16 h; short s; } u;
    u.s = s;
    return __bfloat162float(u.h);
}

// bank-balanced LDS swizzle: granule ^= fsw(row); mixes row bits 0..5
#define FSW(r) ((((r) >> 3) ^ (r)) & 7)

// ---------------------------------------------------------------------------
// K1: e[b][n][q] = exp(score/sqrt(128)) + per-128n-tile column sums.
// fp32 tiled GEMM 128x128, Ktile=8, 256 thr, 8x8/thread. grid (8,128,4).
// WS==1: writes bf16 e to ews. WS==0: writes fp32 e to p.
// ---------------------------------------------------------------------------
template <int WS>
__global__ __launch_bounds__(256, 2)
void k1_scores(const float* __restrict__ mi, const float* __restrict__ qi,
               float* __restrict__ p, short* __restrict__ ews,
               float* __restrict__ partial)
{
    const int qb = blockIdx.x << 7;
    const int nb = blockIdx.y << 7;
    const int b  = blockIdx.z;
    const float* __restrict__ qib = qi + (size_t)b * (DE * QCOL);

    __shared__ float As[8][132];
    __shared__ float Bs[8][132];
    __shared__ float red[16][128];

    const int tid = threadIdx.x;
    const int tx  = tid & 15;
    const int ty  = tid >> 4;

    float acc[8][8];
#pragma unroll
    for (int i = 0; i < 8; ++i)
#pragma unroll
        for (int j = 0; j < 8; ++j) acc[i][j] = 0.f;

    const int ld_d = tid >> 5;
    const int ld_n = (tid & 31) << 2;

    for (int k0 = 0; k0 < DE; k0 += 8) {
        float4 av = *(const float4*)(mi  + (size_t)(k0 + ld_d) * NMEM + nb + ld_n);
        float4 bv = *(const float4*)(qib + (size_t)(k0 + ld_d) * QCOL + qb + ld_n);
        *(float4*)&As[ld_d][ld_n] = av;
        *(float4*)&Bs[ld_d][ld_n] = bv;
        __syncthreads();
#pragma unroll
        for (int kk = 0; kk < 8; ++kk) {
            float a[8], bb[8];
            *(float4*)&a[0]  = *(float4*)&As[kk][ty * 8];
            *(float4*)&a[4]  = *(float4*)&As[kk][ty * 8 + 4];
            *(float4*)&bb[0] = *(float4*)&Bs[kk][tx * 8];
            *(float4*)&bb[4] = *(float4*)&Bs[kk][tx * 8 + 4];
#pragma unroll
            for (int i = 0; i < 8; ++i)
#pragma unroll
                for (int j = 0; j < 8; ++j)
                    acc[i][j] += a[i] * bb[j];
        }
        __syncthreads();
    }

    const float scale = 0.08838834764831845f; // 1/sqrt(128)
    float cs[8];
#pragma unroll
    for (int j = 0; j < 8; ++j) cs[j] = 0.f;

#pragma unroll
    for (int i = 0; i < 8; ++i) {
        const int n = nb + ty * 8 + i;
        float e[8];
#pragma unroll
        for (int j = 0; j < 8; ++j) {
            e[j] = __expf(acc[i][j] * scale);
            cs[j] += e[j];
        }
        if (WS) {
            short8v v;
#pragma unroll
            for (int j = 0; j < 8; ++j) v[j] = f2bf(e[j]);
            *(short8v*)(ews + ((size_t)b << 24) + ((size_t)n << 10) + qb + tx * 8) = v;
        } else {
            float* __restrict__ pb = p + ((size_t)b << 24);
            *(float4*)(pb + ((size_t)n << 10) + qb + tx * 8)     = *(float4*)&e[0];
            *(float4*)(pb + ((size_t)n << 10) + qb + tx * 8 + 4) = *(float4*)&e[4];
        }
    }

#pragma unroll
    for (int j = 0; j < 8; ++j) red[ty][tx * 8 + j] = cs[j];
    __syncthreads();
    if (tid < 128) {
        float s = 0.f;
#pragma unroll
        for (int t = 0; t < 16; ++t) s += red[t][tid];
        partial[(size_t)blockIdx.y * 4096 + (b << 10) + qb + tid] = s;
    }
}

// K2b: invsum[col] = 1 / sum over 128 ntile partials. grid 128 x 256thr.
__global__ __launch_bounds__(256)
void k2b_red(const float* __restrict__ partial, float* __restrict__ invsum)
{
    __shared__ float red[8][32];
    const int col = blockIdx.x * 32 + (threadIdx.x & 31);
    const int g   = threadIdx.x >> 5;
    float s = 0.f;
#pragma unroll
    for (int r = 0; r < 16; ++r)
        s += partial[(size_t)(g * 16 + r) * 4096 + col];
    red[g][threadIdx.x & 31] = s;
    __syncthreads();
    if (threadIdx.x < 32) {
        float t = 0.f;
#pragma unroll
        for (int g2 = 0; g2 < 8; ++g2) t += red[g2][threadIdx.x];
        invsum[col] = 1.0f / t;
    }
}

// K3 (WS==1): p = bf2f(ews) * invsum ; (WS==0): p *= invsum in place
template <int WS>
__global__ __launch_bounds__(256)
void k3_norm(float* __restrict__ p, const short* __restrict__ ews,
             const float* __restrict__ invsum)
{
    const size_t stride = (size_t)gridDim.x * blockDim.x;
    if (WS) {
        for (size_t t = (size_t)blockIdx.x * 256 + threadIdx.x; t < 8388608ull; t += stride) {
            const size_t i = t << 3;
            const int q = (int)(i & 1023);
            const int b = (int)(i >> 24);
            const float4 inv0 = *(const float4*)(invsum + (b << 10) + q);
            const float4 inv1 = *(const float4*)(invsum + (b << 10) + q + 4);
            short8v v = *(const short8v*)(ews + i);
            float4 o0, o1;
            o0.x = bf2f(v[0]) * inv0.x; o0.y = bf2f(v[1]) * inv0.y;
            o0.z = bf2f(v[2]) * inv0.z; o0.w = bf2f(v[3]) * inv0.w;
            o1.x = bf2f(v[4]) * inv1.x; o1.y = bf2f(v[5]) * inv1.y;
            o1.z = bf2f(v[6]) * inv1.z; o1.w = bf2f(v[7]) * inv1.w;
            *(float4*)(p + i)     = o0;
            *(float4*)(p + i + 4) = o1;
        }
    } else {
        for (size_t t = (size_t)blockIdx.x * 256 + threadIdx.x; t < 16777216ull; t += stride) {
            const size_t i = t << 2;
            float4 v = *(float4*)(p + i);
            const int q = (int)(i & 1023);
            const int b = (int)(i >> 24);
            const float4 inv = *(const float4*)(invsum + (b << 10) + q);
            v.x *= inv.x; v.y *= inv.y; v.z *= inv.z; v.w *= inv.w;
            *(float4*)(p + i) = v;
        }
    }
}

// ---------------------------------------------------------------------------
// K4: mem[b][o][q] = sum_n mo[o][n] * p[b][n][q]  via bf16 MFMA
// Tile 64x64, BK=128, 256 thr = 4 waves (each 32x32 = 2x2 frags, 4 k-slices
// -> 16 MFMA/step, 128 steps). LDS rows 128 bf16 (256B, 16 granules of 16B),
// granule ^= FSW(row): all stores/reads bank-balanced. Double-buffered.
// grid (16,8,4) = 512 wgs = 2 blocks/CU.
// ---------------------------------------------------------------------------
__global__ __launch_bounds__(256, 2)
void k4_mfma(const float* __restrict__ mo, const float* __restrict__ p,
             float* __restrict__ out0)
{
    const int qb = blockIdx.x << 6;
    const int ob = blockIdx.y << 6;
    const int b  = blockIdx.z;
    const float* __restrict__ pb = p + ((size_t)b << 24);

    __shared__ __align__(16) short As[2][64 * 128];  // [o][k] swizzled
    __shared__ __align__(16) short Bs[2][64 * 128];  // [q][k(=n)] swizzled

    const int tid  = threadIdx.x;
    const int lane = tid & 63;
    const int w    = tid >> 6;
    const int wm   = (w >> 1) << 5;   // 0/32 (o)
    const int wn   = (w & 1) << 5;    // 0/32 (q)

    // A staging: 4 rows (aro+16j), k-span [ak8, ak8+8)
    const int aro = tid >> 4;               // 0..15
    const int ak8 = (tid & 15) << 3;        // 0..120
    // B staging: 8 p-rows (bn8+i), 4 q (bq4..+3); transposed write
    const int bn8 = (tid >> 4) << 3;        // 0..120
    const int bq4 = (tid & 15) << 2;        // 0..60

    // precomputed swizzled store offsets (shorts)
    int sA[4], sB[4];
#pragma unroll
    for (int j = 0; j < 4; ++j) {
        const int rlA = aro + 16 * j;
        sA[j] = rlA * 128 + ((((ak8 >> 3) ^ FSW(rlA))) << 3);
        const int rlB = bq4 + j;
        sB[j] = rlB * 128 + ((((bn8 >> 3) ^ FSW(rlB))) << 3);
    }

    const float* __restrict__ gA = mo + (size_t)(ob + aro) * NMEM + ak8;
    const float* __restrict__ gB = pb + (size_t)bn8 * QCOL + qb + bq4;

    f32x4 aA[4][2], aB[8];

#define K4_LOAD(K0)                                                              \
    do {                                                                         \
        _Pragma("unroll")                                                        \
        for (int j = 0; j < 4; ++j) {                                            \
            aA[j][0] = *(const f32x4*)(gA + (size_t)(16 * j) * NMEM + (K0));     \
            aA[j][1] = *(const f32x4*)(gA + (size_t)(16 * j) * NMEM + (K0) + 4); \
        }                                                                        \
        _Pragma("unroll")                                                        \
        for (int i = 0; i < 8; ++i)                                              \
            aB[i] = *(const f32x4*)(gB + ((size_t)(K0) + i) * QCOL);             \
    } while (0)

#define K4_STORE(BUF)                                                            \
    do {                                                                         \
        _Pragma("unroll")                                                        \
        for (int j = 0; j < 4; ++j) {                                            \
            short8v v;                                                           \
            _Pragma("unroll")                                                    \
            for (int h = 0; h < 4; ++h) { v[h] = f2bf(aA[j][0][h]);              \
                                          v[h + 4] = f2bf(aA[j][1][h]); }        \
            *(short8v*)&As[BUF][sA[j]] = v;                                      \
        }                                                                        \
        _Pragma("unroll")                                                        \
        for (int j = 0; j < 4; ++j) {                                            \
            short8v v;                                                           \
            _Pragma("unroll")                                                    \
            for (int i = 0; i < 8; ++i) v[i] = f2bf(aB[i][j]);                   \
            *(short8v*)&Bs[BUF][sB[j]] = v;                                      \
        }                                                                        \
    } while (0)

    f32x4 acc[2][2];
#pragma unroll
    for (int i = 0; i < 2; ++i)
#pragma unroll
        for (int j = 0; j < 2; ++j) acc[i][j] = (f32x4){0.f, 0.f, 0.f, 0.f};

    K4_LOAD(0);
    K4_STORE(0);
    __syncthreads();

    const int la = lane & 15;
    const int kg = lane >> 4;          // 0..3

    // precomputed swizzled frag-read offsets
    int rA[2][4], rB[2][4];
#pragma unroll
    for (int fm = 0; fm < 2; ++fm) {
        const int rowA = wm + la + 16 * fm;
        const int rowB = wn + la + 16 * fm;
#pragma unroll
        for (int s = 0; s < 4; ++s) {
            rA[fm][s] = rowA * 128 + ((((s << 2) + kg) ^ FSW(rowA)) << 3);
            rB[fm][s] = rowB * 128 + ((((s << 2) + kg) ^ FSW(rowB)) << 3);
        }
    }

    int cur = 0;
    for (int t = 0; t < NMEM / 128; ++t) {
        const bool pf = (t + 1) < NMEM / 128;
        if (pf) K4_LOAD((t + 1) * 128);

#pragma unroll
        for (int s = 0; s < 4; ++s) {
            short8v a0 = *(const short8v*)&As[cur][rA[0][s]];
            short8v a1 = *(const short8v*)&As[cur][rA[1][s]];
            short8v b0 = *(const short8v*)&Bs[cur][rB[0][s]];
            short8v b1 = *(const short8v*)&Bs[cur][rB[1][s]];
            acc[0][0] = __builtin_amdgcn_mfma_f32_16x16x32_bf16(a0, b0, acc[0][0], 0, 0, 0);
            acc[0][1] = __builtin_amdgcn_mfma_f32_16x16x32_bf16(a0, b1, acc[0][1], 0, 0, 0);
            acc[1][0] = __builtin_amdgcn_mfma_f32_16x16x32_bf16(a1, b0, acc[1][0], 0, 0, 0);
            acc[1][1] = __builtin_amdgcn_mfma_f32_16x16x32_bf16(a1, b1, acc[1][1], 0, 0, 0);
        }

        if (pf) K4_STORE(cur ^ 1);
        __syncthreads();
        cur ^= 1;
    }

    // epilogue: C/D layout col=lane&15, row=(lane>>4)*4+r
    const int orow = ob + wm + (kg << 2);
    const int qcol = qb + wn + la;
    float* __restrict__ outb = out0 + ((size_t)b << 20);
#pragma unroll
    for (int fm = 0; fm < 2; ++fm)
#pragma unroll
        for (int fn = 0; fn < 2; ++fn)
#pragma unroll
            for (int r = 0; r < 4; ++r)
                outb[(size_t)(orow + 16 * fm + r) * 1024 + qcol + 16 * fn] =
                    acc[fm][fn][r];
#undef K4_LOAD
#undef K4_STORE
}

// K5: copy q_out into out0 channels 512..1023 (also wipes scratch regions)
__global__ __launch_bounds__(256)
void k5_copy(const float* __restrict__ qo, float* __restrict__ out0)
{
    const size_t t = (size_t)blockIdx.x * 256 + threadIdx.x;
    if (t < 524288ull) {
        const size_t i = t << 2;
        const size_t b = i >> 19;
        const float4 v = *(const float4*)(qo + i);
        *(float4*)(out0 + i + ((b + 1) << 19)) = v;
    }
}

extern "C" void kernel_launch(void* const* d_in, const int* in_sizes, int n_in,
                              void* d_out, int out_size, void* d_ws, size_t ws_size,
                              hipStream_t stream)
{
    const float* m_in  = (const float*)d_in[0];
    const float* m_out = (const float*)d_in[1];
    const float* q_in  = (const float*)d_in[2];
    const float* q_out = (const float*)d_in[3];

    float* out0 = (float*)d_out;              // 4,194,304 floats
    float* p    = out0 + 4194304;             // 67,108,864 floats
    short* ews  = (short*)d_ws;               // 67,108,864 bf16 (134 MB) if avail

    // scratch in out0's q_out-copy regions (overwritten later by k5):
    float* partial = out0 + 524288;           // b=0 region: [128][4][1024]
    float* invsum  = out0 + 1048576 + 524288; // b=1 region: [4][1024]

    const bool big_ws = ws_size >= (size_t)NMEM * QCOL * 4 * sizeof(short);

    if (big_ws) {
        k1_scores<1><<<dim3(8, 128, 4), 256, 0, stream>>>(m_in, q_in, p, ews, partial);
        k2b_red     <<<dim3(128),       256, 0, stream>>>(partial, invsum);
        k3_norm<1>  <<<dim3(2048),      256, 0, stream>>>(p, ews, invsum);
    } else {
        k1_scores<0><<<dim3(8, 128, 4), 256, 0, stream>>>(m_in, q_in, p, ews, partial);
        k2b_red     <<<dim3(128),       256, 0, stream>>>(partial, invsum);
        k3_norm<0>  <<<dim3(2048),      256, 0, stream>>>(p, ews, invsum);
    }
    k4_mfma<<<dim3(16, 8, 4), 256, 0, stream>>>(m_out, p, out0);
    k5_copy<<<dim3(2048),     256, 0, stream>>>(q_out, out0);
}

// Round 6
// 530.676 us; speedup vs baseline: 3.5255x; 1.1154x over previous
//
#include <hip/hip_runtime.h>
#include <hip/hip_bf16.h>
#include <cstddef>

// m_in  raw-viewed as mi [128][16384]   fp32
// m_out raw-viewed as mo [512][16384]   fp32
// q_in  = qi [4][128][1024]             fp32
// q_out = qo [4][512][1024]             fp32
// out0  = mem_out [4][1024][1024]  (ch 0..511 = mem, ch 512..1023 = q_out copy)
// out1  = p [4][16384][1024] softmax over the 16384 axis
//
// ws (gated on ws_size):
//   [0,134MB)    eT/pT bf16 [4][1024][16384]  (k1 writes e, k3 rewrites p)
//   [134,150MB)  mobf bf16 [512][16384]

#define DE   128
#define DO   512
#define NMEM 16384
#define QCOL 1024

typedef __attribute__((ext_vector_type(8))) short  short8v;
typedef __attribute__((ext_vector_type(4))) float  f32x4;

__device__ __forceinline__ short f2bf(float x) {
    union { __hip_bfloat16 h; short s; } u;
    u.h = __float2bfloat16(x);
    return u.s;
}
__device__ __forceinline__ float bf2f(short s) {
    union { __hip_bfloat16 h; short s; } u;
    u.s = s;
    return __bfloat162float(u.h);
}

// bank-balancing XOR swizzle (granule-level), bijective per 8-row stripe
#define FSW(r) ((((r) >> 3) ^ (r)) & 7)

__device__ __forceinline__ void gl16(const short* g, short* l) {
    __builtin_amdgcn_global_load_lds(
        (const __attribute__((address_space(1))) void*)g,
        (__attribute__((address_space(3))) void*)l, 16, 0, 0);
}

// ===========================================================================
// BIG-WS PATH
// ===========================================================================

// K1 (big): fp32 scores GEMM + exp + partial col sums + LDS-transposed bf16
// e write: eT[b][q][n]. 128x128 tile, Ktile=8, 256 thr. grid (8,128,4).
__global__ __launch_bounds__(256, 2)
void k1_eT(const float* __restrict__ mi, const float* __restrict__ qi,
           short* __restrict__ eT, float* __restrict__ partial)
{
    const int qb = blockIdx.x << 7;
    const int nb = blockIdx.y << 7;
    const int b  = blockIdx.z;
    const float* __restrict__ qib = qi + (size_t)b * (DE * QCOL);

    __shared__ float As[8][132];
    __shared__ float Bs[8][132];
    __shared__ float red[16][128];
    __shared__ __align__(16) short T[128 * 128];

    const int tid = threadIdx.x;
    const int tx  = tid & 15;
    const int ty  = tid >> 4;

    float acc[8][8];
#pragma unroll
    for (int i = 0; i < 8; ++i)
#pragma unroll
        for (int j = 0; j < 8; ++j) acc[i][j] = 0.f;

    const int ld_d = tid >> 5;
    const int ld_n = (tid & 31) << 2;

    for (int k0 = 0; k0 < DE; k0 += 8) {
        float4 av = *(const float4*)(mi  + (size_t)(k0 + ld_d) * NMEM + nb + ld_n);
        float4 bv = *(const float4*)(qib + (size_t)(k0 + ld_d) * QCOL + qb + ld_n);
        *(float4*)&As[ld_d][ld_n] = av;
        *(float4*)&Bs[ld_d][ld_n] = bv;
        __syncthreads();
#pragma unroll
        for (int kk = 0; kk < 8; ++kk) {
            float a[8], bb[8];
            *(float4*)&a[0]  = *(float4*)&As[kk][ty * 8];
            *(float4*)&a[4]  = *(float4*)&As[kk][ty * 8 + 4];
            *(float4*)&bb[0] = *(float4*)&Bs[kk][tx * 8];
            *(float4*)&bb[4] = *(float4*)&Bs[kk][tx * 8 + 4];
#pragma unroll
            for (int i = 0; i < 8; ++i)
#pragma unroll
                for (int j = 0; j < 8; ++j)
                    acc[i][j] += a[i] * bb[j];
        }
        __syncthreads();
    }

    const float scale = 0.08838834764831845f; // 1/sqrt(128)
    float cs[8];
#pragma unroll
    for (int j = 0; j < 8; ++j) cs[j] = 0.f;
#pragma unroll
    for (int i = 0; i < 8; ++i)
#pragma unroll
        for (int j = 0; j < 8; ++j) {
            acc[i][j] = __expf(acc[i][j] * scale);
            cs[j] += acc[i][j];
        }

    // transpose-store: row q_loc = tx*8+j, granule ty (n = ty*8..+8) at ty^FSW
#pragma unroll
    for (int j = 0; j < 8; ++j) {
        const int ql = tx * 8 + j;
        const int fq = (tx ^ j) & 7;          // == FSW(ql)
        short8v v;
#pragma unroll
        for (int i = 0; i < 8; ++i) v[i] = f2bf(acc[i][j]);
        *(short8v*)&T[ql * 128 + ((ty ^ fq) << 3)] = v;
    }
#pragma unroll
    for (int j = 0; j < 8; ++j) red[ty][tx * 8 + j] = cs[j];
    __syncthreads();

    if (tid < 128) {
        float s = 0.f;
#pragma unroll
        for (int t = 0; t < 16; ++t) s += red[t][tid];
        partial[(size_t)blockIdx.y * 4096 + (b << 10) + qb + tid] = s;
    }

    {
        const int ql = tid >> 1;
        const int h  = tid & 1;
        const int fq = FSW(ql);
        short* dst = eT + ((size_t)b << 24) + (size_t)(qb + ql) * NMEM + nb;
#pragma unroll
        for (int k = 0; k < 8; ++k) {
            const int m = h * 8 + k;
            short8v v = *(const short8v*)&T[ql * 128 + ((m ^ fq) << 3)];
            *(short8v*)(dst + m * 8) = v;
        }
    }
}

// K3 (big): eT bf16 [q][n] * invsum[q] -> pT bf16 in place + p fp32 [n][q].
// Block = 64 q x 128 n. grid (16,128,4).
__global__ __launch_bounds__(256)
void k3_big(float* __restrict__ p, short* __restrict__ eT,
            const float* __restrict__ invsum)
{
    const int qb = blockIdx.x << 6;
    const int nb = blockIdx.y << 7;
    const int b  = blockIdx.z;

    __shared__ __align__(16) float P[64 * 128];

    const int tid = threadIdx.x;

    {
        const int ql  = tid >> 2;
        const int nc  = (tid & 3) << 5;
        const int fq  = FSW(ql);
        const float inv = invsum[(b << 10) + qb + ql];
        short* rowp = eT + ((size_t)b << 24) + (size_t)(qb + ql) * NMEM + nb + nc;
#pragma unroll
        for (int k = 0; k < 4; ++k) {
            short8v v = *(const short8v*)(rowp + k * 8);
            float f[8];
#pragma unroll
            for (int h = 0; h < 8; ++h) f[h] = bf2f(v[h]) * inv;
            short8v w;
#pragma unroll
            for (int h = 0; h < 8; ++h) w[h] = f2bf(f[h]);
            *(short8v*)(rowp + k * 8) = w;
            const int gg0 = (nc >> 2) + k * 2;
            *(f32x4*)&P[ql * 128 + (((gg0)     ^ fq) << 2)] = *(f32x4*)&f[0];
            *(f32x4*)&P[ql * 128 + (((gg0 + 1) ^ fq) << 2)] = *(f32x4*)&f[4];
        }
    }
    __syncthreads();

    {
        const int tx  = tid & 15;
        const int tyy = tid >> 4;
        float* pb = p + ((size_t)b << 24);
#pragma unroll
        for (int r = 0; r < 2; ++r) {
            const int gg = tyy + 16 * r;
            f32x4 v[4];
#pragma unroll
            for (int i = 0; i < 4; ++i) {
                const int ql = tx * 4 + i;
                v[i] = *(const f32x4*)&P[ql * 128 + ((gg ^ FSW(ql)) << 2)];
            }
#pragma unroll
            for (int jj = 0; jj < 4; ++jj) {
                f32x4 o = {v[0][jj], v[1][jj], v[2][jj], v[3][jj]};
                *(f32x4*)(pb + (size_t)(nb + gg * 4 + jj) * QCOL + qb + tx * 4) = o;
            }
        }
    }
}

// convm: mo fp32 [512][16384] -> mobf bf16. 1,048,576 short8-units total.
// grid 1024 x 256 thr x 4 units = exact cover.
__global__ __launch_bounds__(256)
void convm(const float* __restrict__ mo, short* __restrict__ mobf)
{
    const size_t u = (size_t)blockIdx.x * 256 + threadIdx.x;  // 0..262143
#pragma unroll
    for (int r = 0; r < 4; ++r) {
        const size_t i = (u + (size_t)r * 262144) << 3;       // float index
        f32x4 a = *(const f32x4*)(mo + i);
        f32x4 c = *(const f32x4*)(mo + i + 4);
        short8v v;
#pragma unroll
        for (int h = 0; h < 4; ++h) { v[h] = f2bf(a[h]); v[h + 4] = f2bf(c[h]); }
        *(short8v*)(mobf + i) = v;
    }
}

// K4 (big): mem = mo * pT^T, pure bf16 B^T GEMM. 64x64 tile, BK=128,
// 4 waves (32x32 each, 2x2 frags, 4 k-slices -> 16 MFMA/step).
// gl_lds(16B) staging, pre-swizzled global src, linear LDS dest, swizzled
// frag reads. grid 512 flat XCD-swizzled. HASMOBF=0: A reg-staged from fp32.
template <int HASMOBF>
__global__ __launch_bounds__(256, 2)
void k4_gl(const float* __restrict__ mo, const short* __restrict__ mobf,
           const short* __restrict__ pT, float* __restrict__ out0)
{
    const int sw = ((blockIdx.x & 7) << 6) | (blockIdx.x >> 3);
    const int b  = sw >> 7;
    const int ot = (sw & 127) >> 4;
    const int qt = sw & 15;
    const int ob = ot << 6;
    const int qb = qt << 6;

    __shared__ __align__(16) short As[2][64 * 128];
    __shared__ __align__(16) short Bs[2][64 * 128];

    const int tid  = threadIdx.x;
    const int lane = tid & 63;
    const int w    = tid >> 6;
    const int w16  = w << 4;
    const int wm   = (w >> 1) << 5;
    const int wn   = (w & 1) << 5;

    const int ln4 = lane >> 4;
    const int lg  = lane & 15;
    size_t off[4];
    int    lbo[4];
#pragma unroll
    for (int i = 0; i < 4; ++i) {
        const int rl = w16 + i * 4 + ln4;
        const int gs = lg ^ FSW(rl);
        off[i] = (size_t)rl * NMEM + gs * 8;
        lbo[i] = (w16 + i * 4) * 128;
    }
    const short* pTb = pT + (((size_t)(b << 10) + qb) * NMEM);
    const short* moA = mobf + (size_t)ob * NMEM;

    const int aro = tid >> 4;
    const int ak8 = (tid & 15) << 3;
    int sAf[4];
    f32x4 aA[4][2];
    const float* gA = mo + (size_t)(ob + aro) * NMEM + ak8;
#pragma unroll
    for (int j = 0; j < 4; ++j) {
        const int rl = aro + 16 * j;
        sAf[j] = rl * 128 + (((ak8 >> 3) ^ FSW(rl)) << 3);
    }

#define STAGE_B(BUF, K0)                                                       \
    do {                                                                       \
        _Pragma("unroll")                                                      \
        for (int i = 0; i < 4; ++i)                                            \
            gl16(pTb + off[i] + (K0), &Bs[BUF][lbo[i]]);                       \
    } while (0)
#define STAGE_A(BUF, K0)                                                       \
    do {                                                                       \
        _Pragma("unroll")                                                      \
        for (int i = 0; i < 4; ++i)                                            \
            gl16(moA + off[i] + (K0), &As[BUF][lbo[i]]);                       \
    } while (0)
#define LOADA_REG(K0)                                                          \
    do {                                                                       \
        _Pragma("unroll")                                                      \
        for (int j = 0; j < 4; ++j) {                                          \
            aA[j][0] = *(const f32x4*)(gA + (size_t)(16 * j) * NMEM + (K0));   \
            aA[j][1] = *(const f32x4*)(gA + (size_t)(16 * j) * NMEM + (K0)+4); \
        }                                                                      \
    } while (0)
#define STOREA_REG(BUF)                                                        \
    do {                                                                       \
        _Pragma("unroll")                                                      \
        for (int j = 0; j < 4; ++j) {                                          \
            short8v v;                                                         \
            _Pragma("unroll")                                                  \
            for (int h = 0; h < 4; ++h) { v[h] = f2bf(aA[j][0][h]);            \
                                          v[h + 4] = f2bf(aA[j][1][h]); }      \
            *(short8v*)&As[BUF][sAf[j]] = v;                                   \
        }                                                                      \
    } while (0)

    f32x4 acc[2][2];
#pragma unroll
    for (int i = 0; i < 2; ++i)
#pragma unroll
        for (int j = 0; j < 2; ++j) acc[i][j] = (f32x4){0.f, 0.f, 0.f, 0.f};

    if (HASMOBF) { STAGE_A(0, 0); } else { LOADA_REG(0); STOREA_REG(0); }
    STAGE_B(0, 0);
    __syncthreads();

    const int la = lane & 15;
    const int kg = lane >> 4;

    int rA[2][4], rB[2][4];
#pragma unroll
    for (int fm = 0; fm < 2; ++fm) {
        const int rowA = wm + la + 16 * fm;
        const int rowB = wn + la + 16 * fm;
#pragma unroll
        for (int s = 0; s < 4; ++s) {
            rA[fm][s] = rowA * 128 + ((((s << 2) + kg) ^ FSW(rowA)) << 3);
            rB[fm][s] = rowB * 128 + ((((s << 2) + kg) ^ FSW(rowB)) << 3);
        }
    }

    int cur = 0;
    for (int t = 0; t < NMEM / 128; ++t) {
        const bool pf = (t + 1) < NMEM / 128;
        if (pf) {
            if (HASMOBF) STAGE_A(cur ^ 1, (size_t)(t + 1) * 128);
            else         LOADA_REG((t + 1) * 128);
            STAGE_B(cur ^ 1, (size_t)(t + 1) * 128);
        }
#pragma unroll
        for (int s = 0; s < 4; ++s) {
            short8v a0 = *(const short8v*)&As[cur][rA[0][s]];
            short8v a1 = *(const short8v*)&As[cur][rA[1][s]];
            short8v b0 = *(const short8v*)&Bs[cur][rB[0][s]];
            short8v b1 = *(const short8v*)&Bs[cur][rB[1][s]];
            acc[0][0] = __builtin_amdgcn_mfma_f32_16x16x32_bf16(a0, b0, acc[0][0], 0, 0, 0);
            acc[0][1] = __builtin_amdgcn_mfma_f32_16x16x32_bf16(a0, b1, acc[0][1], 0, 0, 0);
            acc[1][0] = __builtin_amdgcn_mfma_f32_16x16x32_bf16(a1, b0, acc[1][0], 0, 0, 0);
            acc[1][1] = __builtin_amdgcn_mfma_f32_16x16x32_bf16(a1, b1, acc[1][1], 0, 0, 0);
        }
        if (!HASMOBF && pf) STOREA_REG(cur ^ 1);
        __syncthreads();
        cur ^= 1;
    }

    const int orow = ob + wm + (kg << 2);
    const int qcol = qb + wn + la;
    float* __restrict__ outb = out0 + ((size_t)b << 20);
#pragma unroll
    for (int fm = 0; fm < 2; ++fm)
#pragma unroll
        for (int fn = 0; fn < 2; ++fn)
#pragma unroll
            for (int r = 0; r < 4; ++r)
                outb[(size_t)(orow + 16 * fm + r) * 1024 + qcol + 16 * fn] =
                    acc[fm][fn][r];
#undef STAGE_A
#undef STAGE_B
#undef LOADA_REG
#undef STOREA_REG
}

// ===========================================================================
// SMALL-WS FALLBACK PATH (R4 pipeline, passed at 592us)
// ===========================================================================

// K1 (small): scores GEMM + exp -> fp32 e into p, + partial col sums
__global__ __launch_bounds__(256, 2)
void k1_p(const float* __restrict__ mi, const float* __restrict__ qi,
          float* __restrict__ p, float* __restrict__ partial)
{
    const int qb = blockIdx.x << 7;
    const int nb = blockIdx.y << 7;
    const int b  = blockIdx.z;
    const float* __restrict__ qib = qi + (size_t)b * (DE * QCOL);

    __shared__ float As[8][132];
    __shared__ float Bs[8][132];
    __shared__ float red[16][128];

    const int tid = threadIdx.x;
    const int tx  = tid & 15;
    const int ty  = tid >> 4;

    float acc[8][8];
#pragma unroll
    for (int i = 0; i < 8; ++i)
#pragma unroll
        for (int j = 0; j < 8; ++j) acc[i][j] = 0.f;

    const int ld_d = tid >> 5;
    const int ld_n = (tid & 31) << 2;

    for (int k0 = 0; k0 < DE; k0 += 8) {
        float4 av = *(const float4*)(mi  + (size_t)(k0 + ld_d) * NMEM + nb + ld_n);
        float4 bv = *(const float4*)(qib + (size_t)(k0 + ld_d) * QCOL + qb + ld_n);
        *(float4*)&As[ld_d][ld_n] = av;
        *(float4*)&Bs[ld_d][ld_n] = bv;
        __syncthreads();
#pragma unroll
        for (int kk = 0; kk < 8; ++kk) {
            float a[8], bb[8];
            *(float4*)&a[0]  = *(float4*)&As[kk][ty * 8];
            *(float4*)&a[4]  = *(float4*)&As[kk][ty * 8 + 4];
            *(float4*)&bb[0] = *(float4*)&Bs[kk][tx * 8];
            *(float4*)&bb[4] = *(float4*)&Bs[kk][tx * 8 + 4];
#pragma unroll
            for (int i = 0; i < 8; ++i)
#pragma unroll
                for (int j = 0; j < 8; ++j)
                    acc[i][j] += a[i] * bb[j];
        }
        __syncthreads();
    }

    const float scale = 0.08838834764831845f;
    float cs[8];
#pragma unroll
    for (int j = 0; j < 8; ++j) cs[j] = 0.f;
    float* __restrict__ pb = p + ((size_t)b << 24);
#pragma unroll
    for (int i = 0; i < 8; ++i) {
        const int n = nb + ty * 8 + i;
        float e[8];
#pragma unroll
        for (int j = 0; j < 8; ++j) {
            e[j] = __expf(acc[i][j] * scale);
            cs[j] += e[j];
        }
        *(float4*)(pb + ((size_t)n << 10) + qb + tx * 8)     = *(float4*)&e[0];
        *(float4*)(pb + ((size_t)n << 10) + qb + tx * 8 + 4) = *(float4*)&e[4];
    }

#pragma unroll
    for (int j = 0; j < 8; ++j) red[ty][tx * 8 + j] = cs[j];
    __syncthreads();
    if (tid < 128) {
        float s = 0.f;
#pragma unroll
        for (int t = 0; t < 16; ++t) s += red[t][tid];
        partial[(size_t)blockIdx.y * 4096 + (b << 10) + qb + tid] = s;
    }
}

// K3 (small): p *= invsum in place
__global__ __launch_bounds__(256)
void k3_small(float* __restrict__ p, const float* __restrict__ invsum)
{
    const size_t stride = (size_t)gridDim.x * blockDim.x;
    for (size_t t = (size_t)blockIdx.x * 256 + threadIdx.x; t < 16777216ull; t += stride) {
        const size_t i = t << 2;
        float4 v = *(float4*)(p + i);
        const int q = (int)(i & 1023);
        const int b = (int)(i >> 24);
        const float4 inv = *(const float4*)(invsum + (b << 10) + q);
        v.x *= inv.x; v.y *= inv.y; v.z *= inv.z; v.w *= inv.w;
        *(float4*)(p + i) = v;
    }
}

// K4 (small): R4 reg-staged MFMA GEMM. 64x64 tile, BK=128. grid (16,8,4).
__global__ __launch_bounds__(256, 2)
void k4_reg(const float* __restrict__ mo, const float* __restrict__ p,
            float* __restrict__ out0)
{
    const int qb = blockIdx.x << 6;
    const int ob = blockIdx.y << 6;
    const int b  = blockIdx.z;
    const float* __restrict__ pb = p + ((size_t)b << 24);

    __shared__ __align__(16) short As[2][64 * 128];
    __shared__ __align__(16) short Bs[2][64 * 128];

    const int tid  = threadIdx.x;
    const int lane = tid & 63;
    const int w    = tid >> 6;
    const int wm   = (w >> 1) << 5;
    const int wn   = (w & 1) << 5;

    const int aro = tid >> 4;
    const int ak8 = (tid & 15) << 3;
    const int bn8 = (tid >> 4) << 3;
    const int bq4 = (tid & 15) << 2;

    int sA[4], sB[4];
#pragma unroll
    for (int j = 0; j < 4; ++j) {
        const int rlA = aro + 16 * j;
        sA[j] = rlA * 128 + ((((ak8 >> 3) ^ FSW(rlA))) << 3);
        const int rlB = bq4 + j;
        sB[j] = rlB * 128 + ((((bn8 >> 3) ^ FSW(rlB))) << 3);
    }

    const float* __restrict__ gA = mo + (size_t)(ob + aro) * NMEM + ak8;
    const float* __restrict__ gB = pb + (size_t)bn8 * QCOL + qb + bq4;

    f32x4 aA[4][2], aB[8];

#define K4_LOAD(K0)                                                              \
    do {                                                                         \
        _Pragma("unroll")                                                        \
        for (int j = 0; j < 4; ++j) {                                            \
            aA[j][0] = *(const f32x4*)(gA + (size_t)(16 * j) * NMEM + (K0));     \
            aA[j][1] = *(const f32x4*)(gA + (size_t)(16 * j) * NMEM + (K0) + 4); \
        }                                                                        \
        _Pragma("unroll")                                                        \
        for (int i = 0; i < 8; ++i)                                              \
            aB[i] = *(const f32x4*)(gB + ((size_t)(K0) + i) * QCOL);             \
    } while (0)

#define K4_STORE(BUF)                                                            \
    do {                                                                         \
        _Pragma("unroll")                                                        \
        for (int j = 0; j < 4; ++j) {                                            \
            short8v v;                                                           \
            _Pragma("unroll")                                                    \
            for (int h = 0; h < 4; ++h) { v[h] = f2bf(aA[j][0][h]);              \
                                          v[h + 4] = f2bf(aA[j][1][h]); }        \
            *(short8v*)&As[BUF][sA[j]] = v;                                      \
        }                                                                        \
        _Pragma("unroll")                                                        \
        for (int j = 0; j < 4; ++j) {                                            \
            short8v v;                                                           \
            _Pragma("unroll")                                                    \
            for (int i = 0; i < 8; ++i) v[i] = f2bf(aB[i][j]);                   \
            *(short8v*)&Bs[BUF][sB[j]] = v;                                      \
        }                                                                        \
    } while (0)

    f32x4 acc[2][2];
#pragma unroll
    for (int i = 0; i < 2; ++i)
#pragma unroll
        for (int j = 0; j < 2; ++j) acc[i][j] = (f32x4){0.f, 0.f, 0.f, 0.f};

    K4_LOAD(0);
    K4_STORE(0);
    __syncthreads();

    const int la = lane & 15;
    const int kg = lane >> 4;

    int rA[2][4], rB[2][4];
#pragma unroll
    for (int fm = 0; fm < 2; ++fm) {
        const int rowA = wm + la + 16 * fm;
        const int rowB = wn + la + 16 * fm;
#pragma unroll
        for (int s = 0; s < 4; ++s) {
            rA[fm][s] = rowA * 128 + ((((s << 2) + kg) ^ FSW(rowA)) << 3);
            rB[fm][s] = rowB * 128 + ((((s << 2) + kg) ^ FSW(rowB)) << 3);
        }
    }

    int cur = 0;
    for (int t = 0; t < NMEM / 128; ++t) {
        const bool pf = (t + 1) < NMEM / 128;
        if (pf) K4_LOAD((t + 1) * 128);

#pragma unroll
        for (int s = 0; s < 4; ++s) {
            short8v a0 = *(const short8v*)&As[cur][rA[0][s]];
            short8v a1 = *(const short8v*)&As[cur][rA[1][s]];
            short8v b0 = *(const short8v*)&Bs[cur][rB[0][s]];
            short8v b1 = *(const short8v*)&Bs[cur][rB[1][s]];
            acc[0][0] = __builtin_amdgcn_mfma_f32_16x16x32_bf16(a0, b0, acc[0][0], 0, 0, 0);
            acc[0][1] = __builtin_amdgcn_mfma_f32_16x16x32_bf16(a0, b1, acc[0][1], 0, 0, 0);
            acc[1][0] = __builtin_amdgcn_mfma_f32_16x16x32_bf16(a1, b0, acc[1][0], 0, 0, 0);
            acc[1][1] = __builtin_amdgcn_mfma_f32_16x16x32_bf16(a1, b1, acc[1][1], 0, 0, 0);
        }

        if (pf) K4_STORE(cur ^ 1);
        __syncthreads();
        cur ^= 1;
    }

    const int orow = ob + wm + (kg << 2);
    const int qcol = qb + wn + la;
    float* __restrict__ outb = out0 + ((size_t)b << 20);
#pragma unroll
    for (int fm = 0; fm < 2; ++fm)
#pragma unroll
        for (int fn = 0; fn < 2; ++fn)
#pragma unroll
            for (int r = 0; r < 4; ++r)
                outb[(size_t)(orow + 16 * fm + r) * 1024 + qcol + 16 * fn] =
                    acc[fm][fn][r];
#undef K4_LOAD
#undef K4_STORE
}

// ===========================================================================
// SHARED
// ===========================================================================

// K2b: invsum[col] = 1 / sum over 128 ntile partials. grid 128 x 256thr.
__global__ __launch_bounds__(256)
void k2b_red(const float* __restrict__ partial, float* __restrict__ invsum)
{
    __shared__ float red[8][32];
    const int col = blockIdx.x * 32 + (threadIdx.x & 31);
    const int g   = threadIdx.x >> 5;
    float s = 0.f;
#pragma unroll
    for (int r = 0; r < 16; ++r)
        s += partial[(size_t)(g * 16 + r) * 4096 + col];
    red[g][threadIdx.x & 31] = s;
    __syncthreads();
    if (threadIdx.x < 32) {
        float t = 0.f;
#pragma unroll
        for (int g2 = 0; g2 < 8; ++g2) t += red[g2][threadIdx.x];
        invsum[col] = 1.0f / t;
    }
}

// K5: copy q_out into out0 channels 512..1023 (also wipes scratch regions)
__global__ __launch_bounds__(256)
void k5_copy(const float* __restrict__ qo, float* __restrict__ out0)
{
    const size_t t = (size_t)blockIdx.x * 256 + threadIdx.x;
    if (t < 524288ull) {
        const size_t i = t << 2;
        const size_t b = i >> 19;
        const float4 v = *(const float4*)(qo + i);
        *(float4*)(out0 + i + ((b + 1) << 19)) = v;
    }
}

extern "C" void kernel_launch(void* const* d_in, const int* in_sizes, int n_in,
                              void* d_out, int out_size, void* d_ws, size_t ws_size,
                              hipStream_t stream)
{
    const float* m_in  = (const float*)d_in[0];
    const float* m_out = (const float*)d_in[1];
    const float* q_in  = (const float*)d_in[2];
    const float* q_out = (const float*)d_in[3];

    float* out0 = (float*)d_out;              // 4,194,304 floats
    float* p    = out0 + 4194304;             // 67,108,864 floats

    short* eT   = (short*)d_ws;               // 134MB bf16 [4][1024][16384]
    short* mobf = (short*)d_ws + 67108864;    // +16MB bf16 [512][16384]

    // scratch in out0's q_out-copy regions (overwritten later by k5):
    float* partial = out0 + 524288;           // b=0 region: [128][4][1024]
    float* invsum  = out0 + 1048576 + 524288; // b=1 region: [4][1024]

    const size_t need_eT   = 134217728ull;
    const size_t need_full = need_eT + 16777216ull;

    if (ws_size >= need_eT) {
        if (ws_size >= need_full)
            convm<<<dim3(1024), 256, 0, stream>>>(m_out, mobf);

        k1_eT  <<<dim3(8, 128, 4),  256, 0, stream>>>(m_in, q_in, eT, partial);
        k2b_red<<<dim3(128),        256, 0, stream>>>(partial, invsum);
        k3_big <<<dim3(16, 128, 4), 256, 0, stream>>>(p, eT, invsum);

        if (ws_size >= need_full)
            k4_gl<1><<<dim3(512), 256, 0, stream>>>(m_out, mobf, eT, out0);
        else
            k4_gl<0><<<dim3(512), 256, 0, stream>>>(m_out, mobf, eT, out0);
    } else {
        k1_p    <<<dim3(8, 128, 4), 256, 0, stream>>>(m_in, q_in, p, partial);
        k2b_red <<<dim3(128),       256, 0, stream>>>(partial, invsum);
        k3_small<<<dim3(2048),      256, 0, stream>>>(p, invsum);
        k4_reg  <<<dim3(16, 8, 4),  256, 0, stream>>>(m_out, p, out0);
    }
    k5_copy<<<dim3(2048), 256, 0, stream>>>(q_out, out0);
}

// Round 8
// 390.057 us; speedup vs baseline: 4.7964x; 1.3605x over previous
//
#include <hip/hip_runtime.h>
#include <hip/hip_bf16.h>
#include <cstddef>

// m_in  raw-viewed as mi [128][16384]   fp32
// m_out raw-viewed as mo [512][16384]   fp32
// q_in  = qi [4][128][1024]             fp32
// q_out = qo [4][512][1024]             fp32
// out0  = mem_out [4][1024][1024]  (ch 0..511 = mem, ch 512..1023 = q_out copy)
// out1  = p [4][16384][1024] softmax over the 16384 axis
//
// ws (gated on ws_size):
//   [0,134MB)    eT/pT bf16 [4][1024][16384]  (k1 writes e, k3 rewrites p)
//   [134,150MB)  mobf bf16 [512][16384]

#define DE   128
#define DO   512
#define NMEM 16384
#define QCOL 1024

typedef __attribute__((ext_vector_type(8))) short    short8v;
typedef __attribute__((ext_vector_type(8))) _Float16 half8v;
typedef __attribute__((ext_vector_type(4))) float    f32x4;

__device__ __forceinline__ short f2bf(float x) {
    union { __hip_bfloat16 h; short s; } u;
    u.h = __float2bfloat16(x);
    return u.s;
}
__device__ __forceinline__ float bf2f(short s) {
    union { __hip_bfloat16 h; short s; } u;
    u.s = s;
    return __bfloat162float(u.h);
}

// bank-balancing XOR swizzle (granule-level), bijective per 8-row stripe
#define FSW(r) ((((r) >> 3) ^ (r)) & 7)

__device__ __forceinline__ void gl16(const short* g, short* l) {
    __builtin_amdgcn_global_load_lds(
        (const __attribute__((address_space(1))) void*)g,
        (__attribute__((address_space(3))) void*)l, 16, 0, 0);
}

// ===========================================================================
// BIG-WS PATH
// ===========================================================================

// K1 (big, MFMA): scoresT tile C[q][n] = sum_d qi[d][q]*mi[d][n] via f16 MFMA,
// then e = exp(C/sqrt(128)) -> eT bf16 [b][q][n] + per-128n-tile column sums.
// Block 128q x 128n, K=128 (one shot). 4 waves (2x2), 4x4 frags, 4 k-slices.
// grid (8 qt, 128 nt, 4 b).
__global__ __launch_bounds__(256, 2)
void k1_mfma(const float* __restrict__ mi, const float* __restrict__ qi,
             short* __restrict__ eT, float* __restrict__ partial)
{
    const int qb = blockIdx.x << 7;
    const int nb = blockIdx.y << 7;
    const int b  = blockIdx.z;

    __shared__ __align__(16) short AfBf[2][128 * 128]; // f16 as shorts
    __shared__ float red2[2][128];

    short* Af = AfBf[0];   // [q][d] swizzled
    short* Bf = AfBf[1];   // [n][d] swizzled
    short* T  = AfBf[0];   // reused after MFMA: [q][n] bf16 swizzled

    const int tid  = threadIdx.x;
    const int lane = tid & 63;
    const int w    = tid >> 6;
    const int wq   = (w >> 1) << 6;   // 0/64
    const int wn2  = (w & 1) << 6;    // 0/64
    const int la   = lane & 15;
    const int kg   = lane >> 4;

    // ---- staging: thread covers 8 d-rows x (2 x 4 cols) of qi and mi,
    //      reg-transpose to [col][d] f16, swizzled. (BUGFIX R8: both halves)
    {
        const int d8 = (tid >> 4) << 3;       // 0..120
        const int c4 = (tid & 15) << 2;       // 0..60
        const float* qib = qi + (size_t)b * (DE * QCOL) + (size_t)d8 * QCOL + qb;
        const float* mib = mi + (size_t)d8 * NMEM + nb;
#pragma unroll
        for (int half = 0; half < 2; ++half) {
            const int c = c4 + (half << 6);   // 0..124
            f32x4 qv[8], mv[8];
#pragma unroll
            for (int i = 0; i < 8; ++i) {
                qv[i] = *(const f32x4*)(qib + (size_t)i * QCOL + c);
                mv[i] = *(const f32x4*)(mib + (size_t)i * NMEM + c);
            }
#pragma unroll
            for (int j = 0; j < 4; ++j) {
                const int row = c + j;
                const int off = row * 128 + ((((d8 >> 3) ^ FSW(row))) << 3);
                half8v av, bv;
#pragma unroll
                for (int i = 0; i < 8; ++i) {
                    av[i] = (_Float16)qv[i][j];
                    bv[i] = (_Float16)mv[i][j];
                }
                *(half8v*)&Af[off] = av;
                *(half8v*)&Bf[off] = bv;
            }
        }
    }
    __syncthreads();

    // ---- MFMA: 64 per wave
    f32x4 acc[4][4];
#pragma unroll
    for (int i = 0; i < 4; ++i)
#pragma unroll
        for (int j = 0; j < 4; ++j) acc[i][j] = (f32x4){0.f, 0.f, 0.f, 0.f};

#pragma unroll
    for (int ks = 0; ks < 4; ++ks) {
        half8v af[4], bf[4];
#pragma unroll
        for (int f = 0; f < 4; ++f) {
            const int ra = wq  + f * 16 + la;
            const int rb = wn2 + f * 16 + la;
            af[f] = *(const half8v*)&Af[ra * 128 + ((((ks << 2) + kg) ^ FSW(ra)) << 3)];
            bf[f] = *(const half8v*)&Bf[rb * 128 + ((((ks << 2) + kg) ^ FSW(rb)) << 3)];
        }
#pragma unroll
        for (int fm = 0; fm < 4; ++fm)
#pragma unroll
            for (int fn = 0; fn < 4; ++fn)
                acc[fm][fn] = __builtin_amdgcn_mfma_f32_16x16x32_f16(
                    af[fm], bf[fn], acc[fm][fn], 0, 0, 0);
    }

    // ---- epilogue: e = exp(score*scale); colsums (over n) per q-row
    const float scale = 0.08838834764831845f; // 1/sqrt(128)
#pragma unroll
    for (int fm = 0; fm < 4; ++fm)
#pragma unroll
        for (int fn = 0; fn < 4; ++fn)
#pragma unroll
            for (int r = 0; r < 4; ++r)
                acc[fm][fn][r] = __expf(acc[fm][fn][r] * scale);

    float val[4][4];
#pragma unroll
    for (int fm = 0; fm < 4; ++fm)
#pragma unroll
        for (int r = 0; r < 4; ++r) {
            float s = acc[fm][0][r] + acc[fm][1][r] + acc[fm][2][r] + acc[fm][3][r];
            s += __shfl_xor(s, 1);
            s += __shfl_xor(s, 2);
            s += __shfl_xor(s, 4);
            s += __shfl_xor(s, 8);
            val[fm][r] = s;   // sum over this wave's 64 n, replicated in 16 lanes
        }

    __syncthreads();   // all Af/Bf reads done; T may now overwrite Af

    // T[q][n] bf16 (swizzled) from C frags: row=q=(kg*4+r)+fm*16+wq, col=n
#pragma unroll
    for (int fm = 0; fm < 4; ++fm)
#pragma unroll
        for (int r = 0; r < 4; ++r) {
            const int ql = wq + fm * 16 + (kg << 2) + r;
            const int fq = FSW(ql);
#pragma unroll
            for (int fn = 0; fn < 4; ++fn) {
                const int nl = wn2 + fn * 16 + la;
                T[ql * 128 + (((nl >> 3) ^ fq) << 3) + (nl & 7)] =
                    f2bf(acc[fm][fn][r]);
            }
        }
    if (la == 0) {
#pragma unroll
        for (int fm = 0; fm < 4; ++fm)
#pragma unroll
            for (int r = 0; r < 4; ++r)
                red2[w & 1][wq + fm * 16 + (kg << 2) + r] = val[fm][r];
    }
    __syncthreads();

    if (tid < 128) {
        partial[(size_t)blockIdx.y * 4096 + (b << 10) + qb + tid] =
            red2[0][tid] + red2[1][tid];
    }

    // gather T -> eT global (128B contiguous per thread)
    {
        const int ql = tid >> 1;
        const int h  = tid & 1;
        const int fq = FSW(ql);
        short* dst = eT + ((size_t)b << 24) + (size_t)(qb + ql) * NMEM + nb;
#pragma unroll
        for (int k = 0; k < 8; ++k) {
            const int m = h * 8 + k;
            short8v v = *(const short8v*)&T[ql * 128 + ((m ^ fq) << 3)];
            *(short8v*)(dst + m * 8) = v;
        }
    }
}

// K3 (big): eT bf16 [q][n] * invsum[q] -> pT bf16 in place + p fp32 [n][q].
// Block = 64 q x 128 n. grid (16,128,4).
__global__ __launch_bounds__(256)
void k3_big(float* __restrict__ p, short* __restrict__ eT,
            const float* __restrict__ invsum)
{
    const int qb = blockIdx.x << 6;
    const int nb = blockIdx.y << 7;
    const int b  = blockIdx.z;

    __shared__ __align__(16) float P[64 * 128];

    const int tid = threadIdx.x;

    {
        const int ql  = tid >> 2;
        const int nc  = (tid & 3) << 5;
        const int fq  = FSW(ql);
        const float inv = invsum[(b << 10) + qb + ql];
        short* rowp = eT + ((size_t)b << 24) + (size_t)(qb + ql) * NMEM + nb + nc;
#pragma unroll
        for (int k = 0; k < 4; ++k) {
            short8v v = *(const short8v*)(rowp + k * 8);
            float f[8];
#pragma unroll
            for (int h = 0; h < 8; ++h) f[h] = bf2f(v[h]) * inv;
            short8v w;
#pragma unroll
            for (int h = 0; h < 8; ++h) w[h] = f2bf(f[h]);
            *(short8v*)(rowp + k * 8) = w;
            const int gg0 = (nc >> 2) + k * 2;
            *(f32x4*)&P[ql * 128 + (((gg0)     ^ fq) << 2)] = *(f32x4*)&f[0];
            *(f32x4*)&P[ql * 128 + (((gg0 + 1) ^ fq) << 2)] = *(f32x4*)&f[4];
        }
    }
    __syncthreads();

    {
        const int tx  = tid & 15;
        const int tyy = tid >> 4;
        float* pb = p + ((size_t)b << 24);
#pragma unroll
        for (int r = 0; r < 2; ++r) {
            const int gg = tyy + 16 * r;
            f32x4 v[4];
#pragma unroll
            for (int i = 0; i < 4; ++i) {
                const int ql = tx * 4 + i;
                v[i] = *(const f32x4*)&P[ql * 128 + ((gg ^ FSW(ql)) << 2)];
            }
#pragma unroll
            for (int jj = 0; jj < 4; ++jj) {
                f32x4 o = {v[0][jj], v[1][jj], v[2][jj], v[3][jj]};
                *(f32x4*)(pb + (size_t)(nb + gg * 4 + jj) * QCOL + qb + tx * 4) = o;
            }
        }
    }
}

// convm: mo fp32 [512][16384] -> mobf bf16. grid 1024 x 256 thr x 4 units.
__global__ __launch_bounds__(256)
void convm(const float* __restrict__ mo, short* __restrict__ mobf)
{
    const size_t u = (size_t)blockIdx.x * 256 + threadIdx.x;  // 0..262143
#pragma unroll
    for (int r = 0; r < 4; ++r) {
        const size_t i = (u + (size_t)r * 262144) << 3;       // float index
        f32x4 a = *(const f32x4*)(mo + i);
        f32x4 c = *(const f32x4*)(mo + i + 4);
        short8v v;
#pragma unroll
        for (int h = 0; h < 4; ++h) { v[h] = f2bf(a[h]); v[h + 4] = f2bf(c[h]); }
        *(short8v*)(mobf + i) = v;
    }
}

// K4 (big): mem = mo * pT^T, pure bf16 B^T GEMM. 64x64 tile, BK=128,
// 4 waves (32x32 each, 2x2 frags, 4 k-slices -> 16 MFMA/step).
// gl_lds(16B) staging, pre-swizzled global src, linear LDS dest, swizzled
// frag reads. grid 512 flat XCD-swizzled. HASMOBF=0: A reg-staged from fp32.
template <int HASMOBF>
__global__ __launch_bounds__(256, 2)
void k4_gl(const float* __restrict__ mo, const short* __restrict__ mobf,
           const short* __restrict__ pT, float* __restrict__ out0)
{
    const int sw = ((blockIdx.x & 7) << 6) | (blockIdx.x >> 3);
    const int b  = sw >> 7;
    const int ot = (sw & 127) >> 4;
    const int qt = sw & 15;
    const int ob = ot << 6;
    const int qb = qt << 6;

    __shared__ __align__(16) short As[2][64 * 128];
    __shared__ __align__(16) short Bs[2][64 * 128];

    const int tid  = threadIdx.x;
    const int lane = tid & 63;
    const int w    = tid >> 6;
    const int w16  = w << 4;
    const int wm   = (w >> 1) << 5;
    const int wn   = (w & 1) << 5;

    const int ln4 = lane >> 4;
    const int lg  = lane & 15;
    size_t off[4];
    int    lbo[4];
#pragma unroll
    for (int i = 0; i < 4; ++i) {
        const int rl = w16 + i * 4 + ln4;
        const int gs = lg ^ FSW(rl);
        off[i] = (size_t)rl * NMEM + gs * 8;
        lbo[i] = (w16 + i * 4) * 128;
    }
    const short* pTb = pT + (((size_t)(b << 10) + qb) * NMEM);
    const short* moA = mobf + (size_t)ob * NMEM;

    const int aro = tid >> 4;
    const int ak8 = (tid & 15) << 3;
    int sAf[4];
    f32x4 aA[4][2];
    const float* gA = mo + (size_t)(ob + aro) * NMEM + ak8;
#pragma unroll
    for (int j = 0; j < 4; ++j) {
        const int rl = aro + 16 * j;
        sAf[j] = rl * 128 + (((ak8 >> 3) ^ FSW(rl)) << 3);
    }

#define STAGE_B(BUF, K0)                                                       \
    do {                                                                       \
        _Pragma("unroll")                                                      \
        for (int i = 0; i < 4; ++i)                                            \
            gl16(pTb + off[i] + (K0), &Bs[BUF][lbo[i]]);                       \
    } while (0)
#define STAGE_A(BUF, K0)                                                       \
    do {                                                                       \
        _Pragma("unroll")                                                      \
        for (int i = 0; i < 4; ++i)                                            \
            gl16(moA + off[i] + (K0), &As[BUF][lbo[i]]);                       \
    } while (0)
#define LOADA_REG(K0)                                                          \
    do {                                                                       \
        _Pragma("unroll")                                                      \
        for (int j = 0; j < 4; ++j) {                                          \
            aA[j][0] = *(const f32x4*)(gA + (size_t)(16 * j) * NMEM + (K0));   \
            aA[j][1] = *(const f32x4*)(gA + (size_t)(16 * j) * NMEM + (K0)+4); \
        }                                                                      \
    } while (0)
#define STOREA_REG(BUF)                                                        \
    do {                                                                       \
        _Pragma("unroll")                                                      \
        for (int j = 0; j < 4; ++j) {                                          \
            short8v v;                                                         \
            _Pragma("unroll")                                                  \
            for (int h = 0; h < 4; ++h) { v[h] = f2bf(aA[j][0][h]);            \
                                          v[h + 4] = f2bf(aA[j][1][h]); }      \
            *(short8v*)&As[BUF][sAf[j]] = v;                                   \
        }                                                                      \
    } while (0)

    f32x4 acc[2][2];
#pragma unroll
    for (int i = 0; i < 2; ++i)
#pragma unroll
        for (int j = 0; j < 2; ++j) acc[i][j] = (f32x4){0.f, 0.f, 0.f, 0.f};

    if (HASMOBF) { STAGE_A(0, 0); } else { LOADA_REG(0); STOREA_REG(0); }
    STAGE_B(0, 0);
    __syncthreads();

    const int la = lane & 15;
    const int kg = lane >> 4;

    int rA[2][4], rB[2][4];
#pragma unroll
    for (int fm = 0; fm < 2; ++fm) {
        const int rowA = wm + la + 16 * fm;
        const int rowB = wn + la + 16 * fm;
#pragma unroll
        for (int s = 0; s < 4; ++s) {
            rA[fm][s] = rowA * 128 + ((((s << 2) + kg) ^ FSW(rowA)) << 3);
            rB[fm][s] = rowB * 128 + ((((s << 2) + kg) ^ FSW(rowB)) << 3);
        }
    }

    int cur = 0;
    for (int t = 0; t < NMEM / 128; ++t) {
        const bool pf = (t + 1) < NMEM / 128;
        if (pf) {
            if (HASMOBF) STAGE_A(cur ^ 1, (size_t)(t + 1) * 128);
            else         LOADA_REG((t + 1) * 128);
            STAGE_B(cur ^ 1, (size_t)(t + 1) * 128);
        }
#pragma unroll
        for (int s = 0; s < 4; ++s) {
            short8v a0 = *(const short8v*)&As[cur][rA[0][s]];
            short8v a1 = *(const short8v*)&As[cur][rA[1][s]];
            short8v b0 = *(const short8v*)&Bs[cur][rB[0][s]];
            short8v b1 = *(const short8v*)&Bs[cur][rB[1][s]];
            acc[0][0] = __builtin_amdgcn_mfma_f32_16x16x32_bf16(a0, b0, acc[0][0], 0, 0, 0);
            acc[0][1] = __builtin_amdgcn_mfma_f32_16x16x32_bf16(a0, b1, acc[0][1], 0, 0, 0);
            acc[1][0] = __builtin_amdgcn_mfma_f32_16x16x32_bf16(a1, b0, acc[1][0], 0, 0, 0);
            acc[1][1] = __builtin_amdgcn_mfma_f32_16x16x32_bf16(a1, b1, acc[1][1], 0, 0, 0);
        }
        if (!HASMOBF && pf) STOREA_REG(cur ^ 1);
        __syncthreads();
        cur ^= 1;
    }

    const int orow = ob + wm + (kg << 2);
    const int qcol = qb + wn + la;
    float* __restrict__ outb = out0 + ((size_t)b << 20);
#pragma unroll
    for (int fm = 0; fm < 2; ++fm)
#pragma unroll
        for (int fn = 0; fn < 2; ++fn)
#pragma unroll
            for (int r = 0; r < 4; ++r)
                outb[(size_t)(orow + 16 * fm + r) * 1024 + qcol + 16 * fn] =
                    acc[fm][fn][r];
#undef STAGE_A
#undef STAGE_B
#undef LOADA_REG
#undef STOREA_REG
}

// ===========================================================================
// SMALL-WS FALLBACK PATH (R4 pipeline)
// ===========================================================================

__global__ __launch_bounds__(256, 2)
void k1_p(const float* __restrict__ mi, const float* __restrict__ qi,
          float* __restrict__ p, float* __restrict__ partial)
{
    const int qb = blockIdx.x << 7;
    const int nb = blockIdx.y << 7;
    const int b  = blockIdx.z;
    const float* __restrict__ qib = qi + (size_t)b * (DE * QCOL);

    __shared__ float As[8][132];
    __shared__ float Bs[8][132];
    __shared__ float red[16][128];

    const int tid = threadIdx.x;
    const int tx  = tid & 15;
    const int ty  = tid >> 4;

    float acc[8][8];
#pragma unroll
    for (int i = 0; i < 8; ++i)
#pragma unroll
        for (int j = 0; j < 8; ++j) acc[i][j] = 0.f;

    const int ld_d = tid >> 5;
    const int ld_n = (tid & 31) << 2;

    for (int k0 = 0; k0 < DE; k0 += 8) {
        float4 av = *(const float4*)(mi  + (size_t)(k0 + ld_d) * NMEM + nb + ld_n);
        float4 bv = *(const float4*)(qib + (size_t)(k0 + ld_d) * QCOL + qb + ld_n);
        *(float4*)&As[ld_d][ld_n] = av;
        *(float4*)&Bs[ld_d][ld_n] = bv;
        __syncthreads();
#pragma unroll
        for (int kk = 0; kk < 8; ++kk) {
            float a[8], bb[8];
            *(float4*)&a[0]  = *(float4*)&As[kk][ty * 8];
            *(float4*)&a[4]  = *(float4*)&As[kk][ty * 8 + 4];
            *(float4*)&bb[0] = *(float4*)&Bs[kk][tx * 8];
            *(float4*)&bb[4] = *(float4*)&Bs[kk][tx * 8 + 4];
#pragma unroll
            for (int i = 0; i < 8; ++i)
#pragma unroll
                for (int j = 0; j < 8; ++j)
                    acc[i][j] += a[i] * bb[j];
        }
        __syncthreads();
    }

    const float scale = 0.08838834764831845f;
    float cs[8];
#pragma unroll
    for (int j = 0; j < 8; ++j) cs[j] = 0.f;
    float* __restrict__ pb = p + ((size_t)b << 24);
#pragma unroll
    for (int i = 0; i < 8; ++i) {
        const int n = nb + ty * 8 + i;
        float e[8];
#pragma unroll
        for (int j = 0; j < 8; ++j) {
            e[j] = __expf(acc[i][j] * scale);
            cs[j] += e[j];
        }
        *(float4*)(pb + ((size_t)n << 10) + qb + tx * 8)     = *(float4*)&e[0];
        *(float4*)(pb + ((size_t)n << 10) + qb + tx * 8 + 4) = *(float4*)&e[4];
    }

#pragma unroll
    for (int j = 0; j < 8; ++j) red[ty][tx * 8 + j] = cs[j];
    __syncthreads();
    if (tid < 128) {
        float s = 0.f;
#pragma unroll
        for (int t = 0; t < 16; ++t) s += red[t][tid];
        partial[(size_t)blockIdx.y * 4096 + (b << 10) + qb + tid] = s;
    }
}

__global__ __launch_bounds__(256)
void k3_small(float* __restrict__ p, const float* __restrict__ invsum)
{
    const size_t stride = (size_t)gridDim.x * blockDim.x;
    for (size_t t = (size_t)blockIdx.x * 256 + threadIdx.x; t < 16777216ull; t += stride) {
        const size_t i = t << 2;
        float4 v = *(float4*)(p + i);
        const int q = (int)(i & 1023);
        const int b = (int)(i >> 24);
        const float4 inv = *(const float4*)(invsum + (b << 10) + q);
        v.x *= inv.x; v.y *= inv.y; v.z *= inv.z; v.w *= inv.w;
        *(float4*)(p + i) = v;
    }
}

__global__ __launch_bounds__(256, 2)
void k4_reg(const float* __restrict__ mo, const float* __restrict__ p,
            float* __restrict__ out0)
{
    const int qb = blockIdx.x << 6;
    const int ob = blockIdx.y << 6;
    const int b  = blockIdx.z;
    const float* __restrict__ pb = p + ((size_t)b << 24);

    __shared__ __align__(16) short As[2][64 * 128];
    __shared__ __align__(16) short Bs[2][64 * 128];

    const int tid  = threadIdx.x;
    const int lane = tid & 63;
    const int w    = tid >> 6;
    const int wm   = (w >> 1) << 5;
    const int wn   = (w & 1) << 5;

    const int aro = tid >> 4;
    const int ak8 = (tid & 15) << 3;
    const int bn8 = (tid >> 4) << 3;
    const int bq4 = (tid & 15) << 2;

    int sA[4], sB[4];
#pragma unroll
    for (int j = 0; j < 4; ++j) {
        const int rlA = aro + 16 * j;
        sA[j] = rlA * 128 + ((((ak8 >> 3) ^ FSW(rlA))) << 3);
        const int rlB = bq4 + j;
        sB[j] = rlB * 128 + ((((bn8 >> 3) ^ FSW(rlB))) << 3);
    }

    const float* __restrict__ gA = mo + (size_t)(ob + aro) * NMEM + ak8;
    const float* __restrict__ gB = pb + (size_t)bn8 * QCOL + qb + bq4;

    f32x4 aA[4][2], aB[8];

#define K4_LOAD(K0)                                                              \
    do {                                                                         \
        _Pragma("unroll")                                                        \
        for (int j = 0; j < 4; ++j) {                                            \
            aA[j][0] = *(const f32x4*)(gA + (size_t)(16 * j) * NMEM + (K0));     \
            aA[j][1] = *(const f32x4*)(gA + (size_t)(16 * j) * NMEM + (K0) + 4); \
        }                                                                        \
        _Pragma("unroll")                                                        \
        for (int i = 0; i < 8; ++i)                                              \
            aB[i] = *(const f32x4*)(gB + ((size_t)(K0) + i) * QCOL);             \
    } while (0)

#define K4_STORE(BUF)                                                            \
    do {                                                                         \
        _Pragma("unroll")                                                        \
        for (int j = 0; j < 4; ++j) {                                            \
            short8v v;                                                           \
            _Pragma("unroll")                                                    \
            for (int h = 0; h < 4; ++h) { v[h] = f2bf(aA[j][0][h]);              \
                                          v[h + 4] = f2bf(aA[j][1][h]); }        \
            *(short8v*)&As[BUF][sA[j]] = v;                                      \
        }                                                                        \
        _Pragma("unroll")                                                        \
        for (int j = 0; j < 4; ++j) {                                            \
            short8v v;                                                           \
            _Pragma("unroll")                                                    \
            for (int i = 0; i < 8; ++i) v[i] = f2bf(aB[i][j]);                   \
            *(short8v*)&Bs[BUF][sB[j]] = v;                                      \
        }                                                                        \
    } while (0)

    f32x4 acc[2][2];
#pragma unroll
    for (int i = 0; i < 2; ++i)
#pragma unroll
        for (int j = 0; j < 2; ++j) acc[i][j] = (f32x4){0.f, 0.f, 0.f, 0.f};

    K4_LOAD(0);
    K4_STORE(0);
    __syncthreads();

    const int la = lane & 15;
    const int kg = lane >> 4;

    int rA[2][4], rB[2][4];
#pragma unroll
    for (int fm = 0; fm < 2; ++fm) {
        const int rowA = wm + la + 16 * fm;
        const int rowB = wn + la + 16 * fm;
#pragma unroll
        for (int s = 0; s < 4; ++s) {
            rA[fm][s] = rowA * 128 + ((((s << 2) + kg) ^ FSW(rowA)) << 3);
            rB[fm][s] = rowB * 128 + ((((s << 2) + kg) ^ FSW(rowB)) << 3);
        }
    }

    int cur = 0;
    for (int t = 0; t < NMEM / 128; ++t) {
        const bool pf = (t + 1) < NMEM / 128;
        if (pf) K4_LOAD((t + 1) * 128);

#pragma unroll
        for (int s = 0; s < 4; ++s) {
            short8v a0 = *(const short8v*)&As[cur][rA[0][s]];
            short8v a1 = *(const short8v*)&As[cur][rA[1][s]];
            short8v b0 = *(const short8v*)&Bs[cur][rB[0][s]];
            short8v b1 = *(const short8v*)&Bs[cur][rB[1][s]];
            acc[0][0] = __builtin_amdgcn_mfma_f32_16x16x32_bf16(a0, b0, acc[0][0], 0, 0, 0);
            acc[0][1] = __builtin_amdgcn_mfma_f32_16x16x32_bf16(a0, b1, acc[0][1], 0, 0, 0);
            acc[1][0] = __builtin_amdgcn_mfma_f32_16x16x32_bf16(a1, b0, acc[1][0], 0, 0, 0);
            acc[1][1] = __builtin_amdgcn_mfma_f32_16x16x32_bf16(a1, b1, acc[1][1], 0, 0, 0);
        }

        if (pf) K4_STORE(cur ^ 1);
        __syncthreads();
        cur ^= 1;
    }

    const int orow = ob + wm + (kg << 2);
    const int qcol = qb + wn + la;
    float* __restrict__ outb = out0 + ((size_t)b << 20);
#pragma unroll
    for (int fm = 0; fm < 2; ++fm)
#pragma unroll
        for (int fn = 0; fn < 2; ++fn)
#pragma unroll
            for (int r = 0; r < 4; ++r)
                outb[(size_t)(orow + 16 * fm + r) * 1024 + qcol + 16 * fn] =
                    acc[fm][fn][r];
#undef K4_LOAD
#undef K4_STORE
}

// ===========================================================================
// SHARED
// ===========================================================================

__global__ __launch_bounds__(256)
void k2b_red(const float* __restrict__ partial, float* __restrict__ invsum)
{
    __shared__ float red[8][32];
    const int col = blockIdx.x * 32 + (threadIdx.x & 31);
    const int g   = threadIdx.x >> 5;
    float s = 0.f;
#pragma unroll
    for (int r = 0; r < 16; ++r)
        s += partial[(size_t)(g * 16 + r) * 4096 + col];
    red[g][threadIdx.x & 31] = s;
    __syncthreads();
    if (threadIdx.x < 32) {
        float t = 0.f;
#pragma unroll
        for (int g2 = 0; g2 < 8; ++g2) t += red[g2][threadIdx.x];
        invsum[col] = 1.0f / t;
    }
}

__global__ __launch_bounds__(256)
void k5_copy(const float* __restrict__ qo, float* __restrict__ out0)
{
    const size_t t = (size_t)blockIdx.x * 256 + threadIdx.x;
    if (t < 524288ull) {
        const size_t i = t << 2;
        const size_t b = i >> 19;
        const float4 v = *(const float4*)(qo + i);
        *(float4*)(out0 + i + ((b + 1) << 19)) = v;
    }
}

extern "C" void kernel_launch(void* const* d_in, const int* in_sizes, int n_in,
                              void* d_out, int out_size, void* d_ws, size_t ws_size,
                              hipStream_t stream)
{
    const float* m_in  = (const float*)d_in[0];
    const float* m_out = (const float*)d_in[1];
    const float* q_in  = (const float*)d_in[2];
    const float* q_out = (const float*)d_in[3];

    float* out0 = (float*)d_out;              // 4,194,304 floats
    float* p    = out0 + 4194304;             // 67,108,864 floats

    short* eT   = (short*)d_ws;               // 134MB bf16 [4][1024][16384]
    short* mobf = (short*)d_ws + 67108864;    // +16MB bf16 [512][16384]

    // scratch in out0's q_out-copy regions (overwritten later by k5):
    float* partial = out0 + 524288;           // b=0 region: [128][4][1024]
    float* invsum  = out0 + 1048576 + 524288; // b=1 region: [4][1024]

    const size_t need_eT   = 134217728ull;
    const size_t need_full = need_eT + 16777216ull;

    if (ws_size >= need_eT) {
        if (ws_size >= need_full)
            convm<<<dim3(1024), 256, 0, stream>>>(m_out, mobf);

        k1_mfma<<<dim3(8, 128, 4),  256, 0, stream>>>(m_in, q_in, eT, partial);
        k2b_red<<<dim3(128),        256, 0, stream>>>(partial, invsum);
        k3_big <<<dim3(16, 128, 4), 256, 0, stream>>>(p, eT, invsum);

        if (ws_size >= need_full)
            k4_gl<1><<<dim3(512), 256, 0, stream>>>(m_out, mobf, eT, out0);
        else
            k4_gl<0><<<dim3(512), 256, 0, stream>>>(m_out, mobf, eT, out0);
    } else {
        k1_p    <<<dim3(8, 128, 4), 256, 0, stream>>>(m_in, q_in, p, partial);
        k2b_red <<<dim3(128),       256, 0, stream>>>(partial, invsum);
        k3_small<<<dim3(2048),      256, 0, stream>>>(p, invsum);
        k4_reg  <<<dim3(16, 8, 4),  256, 0, stream>>>(m_out, p, out0);
    }
    k5_copy<<<dim3(2048), 256, 0, stream>>>(q_out, out0);
}

// Round 9
// 306.825 us; speedup vs baseline: 6.0976x; 1.2713x over previous
//
#include <hip/hip_runtime.h>
#include <hip/hip_bf16.h>
#include <cstddef>

// m_in  raw-viewed as mi [128][16384]   fp32
// m_out raw-viewed as mo [512][16384]   fp32
// q_in  = qi [4][128][1024]             fp32
// q_out = qo [4][512][1024]             fp32
// out0  = mem_out [4][1024][1024]  (ch 0..511 = mem, ch 512..1023 = q_out copy)
// out1  = p [4][16384][1024] softmax over the 16384 axis
//
// ws layout (gated on ws_size):
//   [0,134MB)      eT bf16 [4][1024][16384]  (raw e = exp(score/sqrt(128)))
//   [134,151MB)    mobf bf16 [512][16384]
//   [151,175MB)    split-K partials: 3 x 2M fp32

#define DE   128
#define DO   512
#define NMEM 16384
#define QCOL 1024

typedef __attribute__((ext_vector_type(8))) short    short8v;
typedef __attribute__((ext_vector_type(8))) _Float16 half8v;
typedef __attribute__((ext_vector_type(4))) float    f32x4;

__device__ __forceinline__ short f2bf(float x) {
    union { __hip_bfloat16 h; short s; } u;
    u.h = __float2bfloat16(x);
    return u.s;
}
__device__ __forceinline__ float bf2f(short s) {
    union { __hip_bfloat16 h; short s; } u;
    u.s = s;
    return __bfloat162float(u.h);
}

// bank-balancing XOR swizzle (granule-level), bijective per 8-row stripe
#define FSW(r) ((((r) >> 3) ^ (r)) & 7)

__device__ __forceinline__ void gl16(const short* g, short* l) {
    __builtin_amdgcn_global_load_lds(
        (const __attribute__((address_space(1))) void*)g,
        (__attribute__((address_space(3))) void*)l, 16, 0, 0);
}

// ===========================================================================
// BIG-WS PATH
// ===========================================================================

// K1 (big, MFMA): scoresT tile C[q][n] via f16 MFMA, e=exp -> eT bf16 [b][q][n]
// + per-128n-tile column sums. Block 128q x 128n, K=128. grid (8,128,4).
__global__ __launch_bounds__(256, 2)
void k1_mfma(const float* __restrict__ mi, const float* __restrict__ qi,
             short* __restrict__ eT, float* __restrict__ partial)
{
    const int qb = blockIdx.x << 7;
    const int nb = blockIdx.y << 7;
    const int b  = blockIdx.z;

    __shared__ __align__(16) short AfBf[2][128 * 128]; // f16 as shorts
    __shared__ float red2[2][128];

    short* Af = AfBf[0];   // [q][d] swizzled
    short* Bf = AfBf[1];   // [n][d] swizzled
    short* T  = AfBf[0];   // reused after MFMA: [q][n] bf16 swizzled

    const int tid  = threadIdx.x;
    const int lane = tid & 63;
    const int w    = tid >> 6;
    const int wq   = (w >> 1) << 6;   // 0/64
    const int wn2  = (w & 1) << 6;    // 0/64
    const int la   = lane & 15;
    const int kg   = lane >> 4;

    // staging: thread covers 8 d-rows x (2 x 4 cols), reg-transpose, swizzled
    {
        const int d8 = (tid >> 4) << 3;       // 0..120
        const int c4 = (tid & 15) << 2;       // 0..60
        const float* qib = qi + (size_t)b * (DE * QCOL) + (size_t)d8 * QCOL + qb;
        const float* mib = mi + (size_t)d8 * NMEM + nb;
#pragma unroll
        for (int half = 0; half < 2; ++half) {
            const int c = c4 + (half << 6);   // 0..124
            f32x4 qv[8], mv[8];
#pragma unroll
            for (int i = 0; i < 8; ++i) {
                qv[i] = *(const f32x4*)(qib + (size_t)i * QCOL + c);
                mv[i] = *(const f32x4*)(mib + (size_t)i * NMEM + c);
            }
#pragma unroll
            for (int j = 0; j < 4; ++j) {
                const int row = c + j;
                const int off = row * 128 + ((((d8 >> 3) ^ FSW(row))) << 3);
                half8v av, bv;
#pragma unroll
                for (int i = 0; i < 8; ++i) {
                    av[i] = (_Float16)qv[i][j];
                    bv[i] = (_Float16)mv[i][j];
                }
                *(half8v*)&Af[off] = av;
                *(half8v*)&Bf[off] = bv;
            }
        }
    }
    __syncthreads();

    f32x4 acc[4][4];
#pragma unroll
    for (int i = 0; i < 4; ++i)
#pragma unroll
        for (int j = 0; j < 4; ++j) acc[i][j] = (f32x4){0.f, 0.f, 0.f, 0.f};

#pragma unroll
    for (int ks = 0; ks < 4; ++ks) {
        half8v af[4], bf[4];
#pragma unroll
        for (int f = 0; f < 4; ++f) {
            const int ra = wq  + f * 16 + la;
            const int rb = wn2 + f * 16 + la;
            af[f] = *(const half8v*)&Af[ra * 128 + ((((ks << 2) + kg) ^ FSW(ra)) << 3)];
            bf[f] = *(const half8v*)&Bf[rb * 128 + ((((ks << 2) + kg) ^ FSW(rb)) << 3)];
        }
#pragma unroll
        for (int fm = 0; fm < 4; ++fm)
#pragma unroll
            for (int fn = 0; fn < 4; ++fn)
                acc[fm][fn] = __builtin_amdgcn_mfma_f32_16x16x32_f16(
                    af[fm], bf[fn], acc[fm][fn], 0, 0, 0);
    }

    const float scale = 0.08838834764831845f; // 1/sqrt(128)
#pragma unroll
    for (int fm = 0; fm < 4; ++fm)
#pragma unroll
        for (int fn = 0; fn < 4; ++fn)
#pragma unroll
            for (int r = 0; r < 4; ++r)
                acc[fm][fn][r] = __expf(acc[fm][fn][r] * scale);

    float val[4][4];
#pragma unroll
    for (int fm = 0; fm < 4; ++fm)
#pragma unroll
        for (int r = 0; r < 4; ++r) {
            float s = acc[fm][0][r] + acc[fm][1][r] + acc[fm][2][r] + acc[fm][3][r];
            s += __shfl_xor(s, 1);
            s += __shfl_xor(s, 2);
            s += __shfl_xor(s, 4);
            s += __shfl_xor(s, 8);
            val[fm][r] = s;
        }

    __syncthreads();   // Af/Bf reads done; T may overwrite Af

#pragma unroll
    for (int fm = 0; fm < 4; ++fm)
#pragma unroll
        for (int r = 0; r < 4; ++r) {
            const int ql = wq + fm * 16 + (kg << 2) + r;
            const int fq = FSW(ql);
#pragma unroll
            for (int fn = 0; fn < 4; ++fn) {
                const int nl = wn2 + fn * 16 + la;
                T[ql * 128 + (((nl >> 3) ^ fq) << 3) + (nl & 7)] =
                    f2bf(acc[fm][fn][r]);
            }
        }
    if (la == 0) {
#pragma unroll
        for (int fm = 0; fm < 4; ++fm)
#pragma unroll
            for (int r = 0; r < 4; ++r)
                red2[w & 1][wq + fm * 16 + (kg << 2) + r] = val[fm][r];
    }
    __syncthreads();

    if (tid < 128) {
        partial[(size_t)blockIdx.y * 4096 + (b << 10) + qb + tid] =
            red2[0][tid] + red2[1][tid];
    }

    {
        const int ql = tid >> 1;
        const int h  = tid & 1;
        const int fq = FSW(ql);
        short* dst = eT + ((size_t)b << 24) + (size_t)(qb + ql) * NMEM + nb;
#pragma unroll
        for (int k = 0; k < 8; ++k) {
            const int m = h * 8 + k;
            short8v v = *(const short8v*)&T[ql * 128 + ((m ^ fq) << 3)];
            *(short8v*)(dst + m * 8) = v;
        }
    }
}

// K3 (big): read eT bf16 [q][n] (read-only), scale by invsum[q], write
// p fp32 [n][q] via LDS transpose. Block = 64 q x 128 n. grid (16,128,4).
__global__ __launch_bounds__(256)
void k3_big(float* __restrict__ p, const short* __restrict__ eT,
            const float* __restrict__ invsum)
{
    const int qb = blockIdx.x << 6;
    const int nb = blockIdx.y << 7;
    const int b  = blockIdx.z;

    __shared__ __align__(16) float P[64 * 128];

    const int tid = threadIdx.x;

    {
        const int ql  = tid >> 2;
        const int nc  = (tid & 3) << 5;
        const int fq  = FSW(ql);
        const float inv = invsum[(b << 10) + qb + ql];
        const short* rowp = eT + ((size_t)b << 24) + (size_t)(qb + ql) * NMEM + nb + nc;
#pragma unroll
        for (int k = 0; k < 4; ++k) {
            short8v v = *(const short8v*)(rowp + k * 8);
            float f[8];
#pragma unroll
            for (int h = 0; h < 8; ++h) f[h] = bf2f(v[h]) * inv;
            const int gg0 = (nc >> 2) + k * 2;
            *(f32x4*)&P[ql * 128 + (((gg0)     ^ fq) << 2)] = *(f32x4*)&f[0];
            *(f32x4*)&P[ql * 128 + (((gg0 + 1) ^ fq) << 2)] = *(f32x4*)&f[4];
        }
    }
    __syncthreads();

    {
        const int tx  = tid & 15;
        const int tyy = tid >> 4;
        float* pb = p + ((size_t)b << 24);
#pragma unroll
        for (int r = 0; r < 2; ++r) {
            const int gg = tyy + 16 * r;
            f32x4 v[4];
#pragma unroll
            for (int i = 0; i < 4; ++i) {
                const int ql = tx * 4 + i;
                v[i] = *(const f32x4*)&P[ql * 128 + ((gg ^ FSW(ql)) << 2)];
            }
#pragma unroll
            for (int jj = 0; jj < 4; ++jj) {
                f32x4 o = {v[0][jj], v[1][jj], v[2][jj], v[3][jj]};
                *(f32x4*)(pb + (size_t)(nb + gg * 4 + jj) * QCOL + qb + tx * 4) = o;
            }
        }
    }
}

// convm: mo fp32 [512][16384] -> mobf bf16. grid 1024 x 256 thr x 4 units.
__global__ __launch_bounds__(256)
void convm(const float* __restrict__ mo, short* __restrict__ mobf)
{
    const size_t u = (size_t)blockIdx.x * 256 + threadIdx.x;  // 0..262143
#pragma unroll
    for (int r = 0; r < 4; ++r) {
        const size_t i = (u + (size_t)r * 262144) << 3;       // float index
        f32x4 a = *(const f32x4*)(mo + i);
        f32x4 c = *(const f32x4*)(mo + i + 4);
        short8v v;
#pragma unroll
        for (int h = 0; h < 4; ++h) { v[h] = f2bf(a[h]); v[h + 4] = f2bf(c[h]); }
        *(short8v*)(mobf + i) = v;
    }
}

// ---------------------------------------------------------------------------
// K4 split-K: mem_raw[b][o][q] = sum_n mobf[o][n]*eT[b][q][n], K split x4.
// 128x128 tile, 4 waves each 64x64 (4x4 frags), BK=64, gl_lds staging.
// split 0 -> out0 mem region (raw); splits 1..3 -> part[]. Combine applies
// (s0+s1+s2+s3)*invsum. grid 512 flat XCD-swizzled, 2 blocks/CU.
// ---------------------------------------------------------------------------
__global__ __launch_bounds__(256, 2)
void k4_sk(const short* __restrict__ mobf, const short* __restrict__ eT,
           float* __restrict__ out0, float* __restrict__ part)
{
    const int sw    = ((blockIdx.x & 7) << 6) | (blockIdx.x >> 3);
    const int split = sw >> 7;          // 0..3
    const int tile  = sw & 127;
    const int b  = tile >> 5;
    const int ot = (tile >> 3) & 3;
    const int qt = tile & 7;
    const int ob = ot << 7;
    const int qb = qt << 7;
    const int kb = split << 12;         // *4096

    __shared__ __align__(16) short As[2][128 * 64];  // [o][k] linear (gl_lds)
    __shared__ __align__(16) short Bs[2][128 * 64];  // [q][k]

    const int tid  = threadIdx.x;
    const int lane = tid & 63;
    const int w    = tid >> 6;
    const int wm   = (w >> 1) << 6;   // 0/64 (o)
    const int wn   = (w & 1) << 6;    // 0/64 (q)
    const int la   = lane & 15;
    const int kg   = lane >> 4;

    // staging: per wave 4 issues each for A,B; issue covers 8 rows x 64 bf16
    size_t offA[4], offB[4];
    int lbo[4];
#pragma unroll
    for (int i = 0; i < 4; ++i) {
        const int rowb = (w << 5) + (i << 3);
        const int rl   = rowb + (lane >> 3);
        const int gs   = (lane & 7) ^ FSW(rl);
        offA[i] = (size_t)(ob + rl) * NMEM + gs * 8;
        offB[i] = (size_t)(qb + rl) * NMEM + gs * 8;
        lbo[i]  = rowb * 64;
    }
    const short* eTb = eT + ((size_t)b << 24);

#define SK_STAGE(BUF, K0)                                                      \
    do {                                                                       \
        _Pragma("unroll")                                                      \
        for (int i = 0; i < 4; ++i) {                                          \
            gl16(mobf + offA[i] + (K0), &As[BUF][lbo[i]]);                     \
            gl16(eTb  + offB[i] + (K0), &Bs[BUF][lbo[i]]);                     \
        }                                                                      \
    } while (0)

    // frag read offsets (swizzled): 8 granules/row of 64 bf16
    int rA[4][2], rB[4][2];
#pragma unroll
    for (int f = 0; f < 4; ++f) {
        const int rowA = wm + f * 16 + la;
        const int rowB = wn + f * 16 + la;
#pragma unroll
        for (int s = 0; s < 2; ++s) {
            rA[f][s] = rowA * 64 + ((((s << 2) + kg) ^ FSW(rowA)) << 3);
            rB[f][s] = rowB * 64 + ((((s << 2) + kg) ^ FSW(rowB)) << 3);
        }
    }

    f32x4 acc[4][4];
#pragma unroll
    for (int i = 0; i < 4; ++i)
#pragma unroll
        for (int j = 0; j < 4; ++j) acc[i][j] = (f32x4){0.f, 0.f, 0.f, 0.f};

    SK_STAGE(0, kb);
    __syncthreads();

    int cur = 0;
    for (int t = 0; t < 64; ++t) {
        const bool pf = (t + 1) < 64;
        if (pf) SK_STAGE(cur ^ 1, kb + (t + 1) * 64);

#pragma unroll
        for (int s = 0; s < 2; ++s) {
            short8v af[4], bf[4];
#pragma unroll
            for (int f = 0; f < 4; ++f) {
                af[f] = *(const short8v*)&As[cur][rA[f][s]];
                bf[f] = *(const short8v*)&Bs[cur][rB[f][s]];
            }
#pragma unroll
            for (int fm = 0; fm < 4; ++fm)
#pragma unroll
                for (int fn = 0; fn < 4; ++fn)
                    acc[fm][fn] = __builtin_amdgcn_mfma_f32_16x16x32_bf16(
                        af[fm], bf[fn], acc[fm][fn], 0, 0, 0);
        }
        __syncthreads();
        cur ^= 1;
    }

    // epilogue: C layout col=lane&15 (q), row=(lane>>4)*4+r (o)
    if (split == 0) {
        float* outb = out0 + ((size_t)b << 20);
#pragma unroll
        for (int fm = 0; fm < 4; ++fm)
#pragma unroll
            for (int fn = 0; fn < 4; ++fn)
#pragma unroll
                for (int r = 0; r < 4; ++r) {
                    const int o = ob + wm + fm * 16 + (kg << 2) + r;
                    const int q = qb + wn + fn * 16 + la;
                    outb[(size_t)o * 1024 + q] = acc[fm][fn][r];
                }
    } else {
        float* pp = part + (size_t)(split - 1) * 2097152;
#pragma unroll
        for (int fm = 0; fm < 4; ++fm)
#pragma unroll
            for (int fn = 0; fn < 4; ++fn)
#pragma unroll
                for (int r = 0; r < 4; ++r) {
                    const int o = ob + wm + fm * 16 + (kg << 2) + r;
                    const int q = qb + wn + fn * 16 + la;
                    pp[(((size_t)(b << 9) + o) << 10) + q] = acc[fm][fn][r];
                }
    }
#undef SK_STAGE
}

// K6: out0.mem = (s0 + s1 + s2 + s3) * invsum. grid 2048 x 256.
__global__ __launch_bounds__(256)
void k6_comb(float* __restrict__ out0, const float* __restrict__ part,
             const float* __restrict__ invsum)
{
    const size_t t = (size_t)blockIdx.x * 256 + threadIdx.x;
    if (t < 524288ull) {
        const size_t v = t << 2;             // flat index into 2M partial
        const int b = (int)(v >> 19);
        const int q = (int)(v & 1023);
        float* dst = out0 + v + ((size_t)b << 19);
        f32x4 s0 = *(const f32x4*)dst;
        f32x4 s1 = *(const f32x4*)(part + v);
        f32x4 s2 = *(const f32x4*)(part + v + 2097152);
        f32x4 s3 = *(const f32x4*)(part + v + 4194304);
        f32x4 inv = *(const f32x4*)(invsum + (b << 10) + q);
        f32x4 o;
#pragma unroll
        for (int h = 0; h < 4; ++h)
            o[h] = (s0[h] + s1[h] + s2[h] + s3[h]) * inv[h];
        *(f32x4*)dst = o;
    }
}

// K4 (fallback, 64x64 tile): mem = (mo . e) * invsum epilogue.
// HASMOBF=1: A via gl_lds from mobf; 0: A reg-staged from fp32 mo.
template <int HASMOBF>
__global__ __launch_bounds__(256, 2)
void k4_gl(const float* __restrict__ mo, const short* __restrict__ mobf,
           const short* __restrict__ eT, const float* __restrict__ invsum,
           float* __restrict__ out0)
{
    const int sw = ((blockIdx.x & 7) << 6) | (blockIdx.x >> 3);
    const int b  = sw >> 7;
    const int ot = (sw & 127) >> 4;
    const int qt = sw & 15;
    const int ob = ot << 6;
    const int qb = qt << 6;

    __shared__ __align__(16) short As[2][64 * 128];
    __shared__ __align__(16) short Bs[2][64 * 128];

    const int tid  = threadIdx.x;
    const int lane = tid & 63;
    const int w    = tid >> 6;
    const int w16  = w << 4;
    const int wm   = (w >> 1) << 5;
    const int wn   = (w & 1) << 5;

    const int ln4 = lane >> 4;
    const int lg  = lane & 15;
    size_t off[4];
    int    lbo[4];
#pragma unroll
    for (int i = 0; i < 4; ++i) {
        const int rl = w16 + i * 4 + ln4;
        const int gs = lg ^ FSW(rl);
        off[i] = (size_t)rl * NMEM + gs * 8;
        lbo[i] = (w16 + i * 4) * 128;
    }
    const short* eTb = eT + (((size_t)(b << 10) + qb) * NMEM);
    const short* moA = mobf + (size_t)ob * NMEM;

    const int aro = tid >> 4;
    const int ak8 = (tid & 15) << 3;
    int sAf[4];
    f32x4 aA[4][2];
    const float* gA = mo + (size_t)(ob + aro) * NMEM + ak8;
#pragma unroll
    for (int j = 0; j < 4; ++j) {
        const int rl = aro + 16 * j;
        sAf[j] = rl * 128 + (((ak8 >> 3) ^ FSW(rl)) << 3);
    }

#define STAGE_B(BUF, K0)                                                       \
    do {                                                                       \
        _Pragma("unroll")                                                      \
        for (int i = 0; i < 4; ++i)                                            \
            gl16(eTb + off[i] + (K0), &Bs[BUF][lbo[i]]);                       \
    } while (0)
#define STAGE_A(BUF, K0)                                                       \
    do {                                                                       \
        _Pragma("unroll")                                                      \
        for (int i = 0; i < 4; ++i)                                            \
            gl16(moA + off[i] + (K0), &As[BUF][lbo[i]]);                       \
    } while (0)
#define LOADA_REG(K0)                                                          \
    do {                                                                       \
        _Pragma("unroll")                                                      \
        for (int j = 0; j < 4; ++j) {                                          \
            aA[j][0] = *(const f32x4*)(gA + (size_t)(16 * j) * NMEM + (K0));   \
            aA[j][1] = *(const f32x4*)(gA + (size_t)(16 * j) * NMEM + (K0)+4); \
        }                                                                      \
    } while (0)
#define STOREA_REG(BUF)                                                        \
    do {                                                                       \
        _Pragma("unroll")                                                      \
        for (int j = 0; j < 4; ++j) {                                          \
            short8v v;                                                         \
            _Pragma("unroll")                                                  \
            for (int h = 0; h < 4; ++h) { v[h] = f2bf(aA[j][0][h]);            \
                                          v[h + 4] = f2bf(aA[j][1][h]); }      \
            *(short8v*)&As[BUF][sAf[j]] = v;                                   \
        }                                                                      \
    } while (0)

    f32x4 acc[2][2];
#pragma unroll
    for (int i = 0; i < 2; ++i)
#pragma unroll
        for (int j = 0; j < 2; ++j) acc[i][j] = (f32x4){0.f, 0.f, 0.f, 0.f};

    if (HASMOBF) { STAGE_A(0, 0); } else { LOADA_REG(0); STOREA_REG(0); }
    STAGE_B(0, 0);
    __syncthreads();

    const int la = lane & 15;
    const int kg = lane >> 4;

    int rA[2][4], rB[2][4];
#pragma unroll
    for (int fm = 0; fm < 2; ++fm) {
        const int rowA = wm + la + 16 * fm;
        const int rowB = wn + la + 16 * fm;
#pragma unroll
        for (int s = 0; s < 4; ++s) {
            rA[fm][s] = rowA * 128 + ((((s << 2) + kg) ^ FSW(rowA)) << 3);
            rB[fm][s] = rowB * 128 + ((((s << 2) + kg) ^ FSW(rowB)) << 3);
        }
    }

    int cur = 0;
    for (int t = 0; t < NMEM / 128; ++t) {
        const bool pf = (t + 1) < NMEM / 128;
        if (pf) {
            if (HASMOBF) STAGE_A(cur ^ 1, (size_t)(t + 1) * 128);
            else         LOADA_REG((t + 1) * 128);
            STAGE_B(cur ^ 1, (size_t)(t + 1) * 128);
        }
#pragma unroll
        for (int s = 0; s < 4; ++s) {
            short8v a0 = *(const short8v*)&As[cur][rA[0][s]];
            short8v a1 = *(const short8v*)&As[cur][rA[1][s]];
            short8v b0 = *(const short8v*)&Bs[cur][rB[0][s]];
            short8v b1 = *(const short8v*)&Bs[cur][rB[1][s]];
            acc[0][0] = __builtin_amdgcn_mfma_f32_16x16x32_bf16(a0, b0, acc[0][0], 0, 0, 0);
            acc[0][1] = __builtin_amdgcn_mfma_f32_16x16x32_bf16(a0, b1, acc[0][1], 0, 0, 0);
            acc[1][0] = __builtin_amdgcn_mfma_f32_16x16x32_bf16(a1, b0, acc[1][0], 0, 0, 0);
            acc[1][1] = __builtin_amdgcn_mfma_f32_16x16x32_bf16(a1, b1, acc[1][1], 0, 0, 0);
        }
        if (!HASMOBF && pf) STOREA_REG(cur ^ 1);
        __syncthreads();
        cur ^= 1;
    }

    const int orow = ob + wm + (kg << 2);
    const int qcol = qb + wn + la;
    const float i0 = invsum[(b << 10) + qcol];
    const float i1 = invsum[(b << 10) + qcol + 16];
    float* __restrict__ outb = out0 + ((size_t)b << 20);
#pragma unroll
    for (int fm = 0; fm < 2; ++fm)
#pragma unroll
        for (int r = 0; r < 4; ++r) {
            outb[(size_t)(orow + 16 * fm + r) * 1024 + qcol]      = acc[fm][0][r] * i0;
            outb[(size_t)(orow + 16 * fm + r) * 1024 + qcol + 16] = acc[fm][1][r] * i1;
        }
#undef STAGE_A
#undef STAGE_B
#undef LOADA_REG
#undef STOREA_REG
}

// ===========================================================================
// SMALL-WS FALLBACK PATH (R4 pipeline)
// ===========================================================================

__global__ __launch_bounds__(256, 2)
void k1_p(const float* __restrict__ mi, const float* __restrict__ qi,
          float* __restrict__ p, float* __restrict__ partial)
{
    const int qb = blockIdx.x << 7;
    const int nb = blockIdx.y << 7;
    const int b  = blockIdx.z;
    const float* __restrict__ qib = qi + (size_t)b * (DE * QCOL);

    __shared__ float As[8][132];
    __shared__ float Bs[8][132];
    __shared__ float red[16][128];

    const int tid = threadIdx.x;
    const int tx  = tid & 15;
    const int ty  = tid >> 4;

    float acc[8][8];
#pragma unroll
    for (int i = 0; i < 8; ++i)
#pragma unroll
        for (int j = 0; j < 8; ++j) acc[i][j] = 0.f;

    const int ld_d = tid >> 5;
    const int ld_n = (tid & 31) << 2;

    for (int k0 = 0; k0 < DE; k0 += 8) {
        float4 av = *(const float4*)(mi  + (size_t)(k0 + ld_d) * NMEM + nb + ld_n);
        float4 bv = *(const float4*)(qib + (size_t)(k0 + ld_d) * QCOL + qb + ld_n);
        *(float4*)&As[ld_d][ld_n] = av;
        *(float4*)&Bs[ld_d][ld_n] = bv;
        __syncthreads();
#pragma unroll
        for (int kk = 0; kk < 8; ++kk) {
            float a[8], bb[8];
            *(float4*)&a[0]  = *(float4*)&As[kk][ty * 8];
            *(float4*)&a[4]  = *(float4*)&As[kk][ty * 8 + 4];
            *(float4*)&bb[0] = *(float4*)&Bs[kk][tx * 8];
            *(float4*)&bb[4] = *(float4*)&Bs[kk][tx * 8 + 4];
#pragma unroll
            for (int i = 0; i < 8; ++i)
#pragma unroll
                for (int j = 0; j < 8; ++j)
                    acc[i][j] += a[i] * bb[j];
        }
        __syncthreads();
    }

    const float scale = 0.08838834764831845f;
    float cs[8];
#pragma unroll
    for (int j = 0; j < 8; ++j) cs[j] = 0.f;
    float* __restrict__ pb = p + ((size_t)b << 24);
#pragma unroll
    for (int i = 0; i < 8; ++i) {
        const int n = nb + ty * 8 + i;
        float e[8];
#pragma unroll
        for (int j = 0; j < 8; ++j) {
            e[j] = __expf(acc[i][j] * scale);
            cs[j] += e[j];
        }
        *(float4*)(pb + ((size_t)n << 10) + qb + tx * 8)     = *(float4*)&e[0];
        *(float4*)(pb + ((size_t)n << 10) + qb + tx * 8 + 4) = *(float4*)&e[4];
    }

#pragma unroll
    for (int j = 0; j < 8; ++j) red[ty][tx * 8 + j] = cs[j];
    __syncthreads();
    if (tid < 128) {
        float s = 0.f;
#pragma unroll
        for (int t = 0; t < 16; ++t) s += red[t][tid];
        partial[(size_t)blockIdx.y * 4096 + (b << 10) + qb + tid] = s;
    }
}

__global__ __launch_bounds__(256)
void k3_small(float* __restrict__ p, const float* __restrict__ invsum)
{
    const size_t stride = (size_t)gridDim.x * blockDim.x;
    for (size_t t = (size_t)blockIdx.x * 256 + threadIdx.x; t < 16777216ull; t += stride) {
        const size_t i = t << 2;
        float4 v = *(float4*)(p + i);
        const int q = (int)(i & 1023);
        const int b = (int)(i >> 24);
        const float4 inv = *(const float4*)(invsum + (b << 10) + q);
        v.x *= inv.x; v.y *= inv.y; v.z *= inv.z; v.w *= inv.w;
        *(float4*)(p + i) = v;
    }
}

__global__ __launch_bounds__(256, 2)
void k4_reg(const float* __restrict__ mo, const float* __restrict__ p,
            float* __restrict__ out0)
{
    const int qb = blockIdx.x << 6;
    const int ob = blockIdx.y << 6;
    const int b  = blockIdx.z;
    const float* __restrict__ pb = p + ((size_t)b << 24);

    __shared__ __align__(16) short As[2][64 * 128];
    __shared__ __align__(16) short Bs[2][64 * 128];

    const int tid  = threadIdx.x;
    const int lane = tid & 63;
    const int w    = tid >> 6;
    const int wm   = (w >> 1) << 5;
    const int wn   = (w & 1) << 5;

    const int aro = tid >> 4;
    const int ak8 = (tid & 15) << 3;
    const int bn8 = (tid >> 4) << 3;
    const int bq4 = (tid & 15) << 2;

    int sA[4], sB[4];
#pragma unroll
    for (int j = 0; j < 4; ++j) {
        const int rlA = aro + 16 * j;
        sA[j] = rlA * 128 + ((((ak8 >> 3) ^ FSW(rlA))) << 3);
        const int rlB = bq4 + j;
        sB[j] = rlB * 128 + ((((bn8 >> 3) ^ FSW(rlB))) << 3);
    }

    const float* __restrict__ gA = mo + (size_t)(ob + aro) * NMEM + ak8;
    const float* __restrict__ gB = pb + (size_t)bn8 * QCOL + qb + bq4;

    f32x4 aA[4][2], aB[8];

#define K4_LOAD(K0)                                                              \
    do {                                                                         \
        _Pragma("unroll")                                                        \
        for (int j = 0; j < 4; ++j) {                                            \
            aA[j][0] = *(const f32x4*)(gA + (size_t)(16 * j) * NMEM + (K0));     \
            aA[j][1] = *(const f32x4*)(gA + (size_t)(16 * j) * NMEM + (K0) + 4); \
        }                                                                        \
        _Pragma("unroll")                                                        \
        for (int i = 0; i < 8; ++i)                                              \
            aB[i] = *(const f32x4*)(gB + ((size_t)(K0) + i) * QCOL);             \
    } while (0)

#define K4_STORE(BUF)                                                            \
    do {                                                                         \
        _Pragma("unroll")                                                        \
        for (int j = 0; j < 4; ++j) {                                            \
            short8v v;                                                           \
            _Pragma("unroll")                                                    \
            for (int h = 0; h < 4; ++h) { v[h] = f2bf(aA[j][0][h]);              \
                                          v[h + 4] = f2bf(aA[j][1][h]); }        \
            *(short8v*)&As[BUF][sA[j]] = v;                                      \
        }                                                                        \
        _Pragma("unroll")                                                        \
        for (int j = 0; j < 4; ++j) {                                            \
            short8v v;                                                           \
            _Pragma("unroll")                                                    \
            for (int i = 0; i < 8; ++i) v[i] = f2bf(aB[i][j]);                   \
            *(short8v*)&Bs[BUF][sB[j]] = v;                                      \
        }                                                                        \
    } while (0)

    f32x4 acc[2][2];
#pragma unroll
    for (int i = 0; i < 2; ++i)
#pragma unroll
        for (int j = 0; j < 2; ++j) acc[i][j] = (f32x4){0.f, 0.f, 0.f, 0.f};

    K4_LOAD(0);
    K4_STORE(0);
    __syncthreads();

    const int la = lane & 15;
    const int kg = lane >> 4;

    int rA[2][4], rB[2][4];
#pragma unroll
    for (int fm = 0; fm < 2; ++fm) {
        const int rowA = wm + la + 16 * fm;
        const int rowB = wn + la + 16 * fm;
#pragma unroll
        for (int s = 0; s < 4; ++s) {
            rA[fm][s] = rowA * 128 + ((((s << 2) + kg) ^ FSW(rowA)) << 3);
            rB[fm][s] = rowB * 128 + ((((s << 2) + kg) ^ FSW(rowB)) << 3);
        }
    }

    int cur = 0;
    for (int t = 0; t < NMEM / 128; ++t) {
        const bool pf = (t + 1) < NMEM / 128;
        if (pf) K4_LOAD((t + 1) * 128);

#pragma unroll
        for (int s = 0; s < 4; ++s) {
            short8v a0 = *(const short8v*)&As[cur][rA[0][s]];
            short8v a1 = *(const short8v*)&As[cur][rA[1][s]];
            short8v b0 = *(const short8v*)&Bs[cur][rB[0][s]];
            short8v b1 = *(const short8v*)&Bs[cur][rB[1][s]];
            acc[0][0] = __builtin_amdgcn_mfma_f32_16x16x32_bf16(a0, b0, acc[0][0], 0, 0, 0);
            acc[0][1] = __builtin_amdgcn_mfma_f32_16x16x32_bf16(a0, b1, acc[0][1], 0, 0, 0);
            acc[1][0] = __builtin_amdgcn_mfma_f32_16x16x32_bf16(a1, b0, acc[1][0], 0, 0, 0);
            acc[1][1] = __builtin_amdgcn_mfma_f32_16x16x32_bf16(a1, b1, acc[1][1], 0, 0, 0);
        }

        if (pf) K4_STORE(cur ^ 1);
        __syncthreads();
        cur ^= 1;
    }

    const int orow = ob + wm + (kg << 2);
    const int qcol = qb + wn + la;
    float* __restrict__ outb = out0 + ((size_t)b << 20);
#pragma unroll
    for (int fm = 0; fm < 2; ++fm)
#pragma unroll
        for (int fn = 0; fn < 2; ++fn)
#pragma unroll
            for (int r = 0; r < 4; ++r)
                outb[(size_t)(orow + 16 * fm + r) * 1024 + qcol + 16 * fn] =
                    acc[fm][fn][r];
#undef K4_LOAD
#undef K4_STORE
}

// ===========================================================================
// SHARED
// ===========================================================================

__global__ __launch_bounds__(256)
void k2b_red(const float* __restrict__ partial, float* __restrict__ invsum)
{
    __shared__ float red[8][32];
    const int col = blockIdx.x * 32 + (threadIdx.x & 31);
    const int g   = threadIdx.x >> 5;
    float s = 0.f;
#pragma unroll
    for (int r = 0; r < 16; ++r)
        s += partial[(size_t)(g * 16 + r) * 4096 + col];
    red[g][threadIdx.x & 31] = s;
    __syncthreads();
    if (threadIdx.x < 32) {
        float t = 0.f;
#pragma unroll
        for (int g2 = 0; g2 < 8; ++g2) t += red[g2][threadIdx.x];
        invsum[col] = 1.0f / t;
    }
}

__global__ __launch_bounds__(256)
void k5_copy(const float* __restrict__ qo, float* __restrict__ out0)
{
    const size_t t = (size_t)blockIdx.x * 256 + threadIdx.x;
    if (t < 524288ull) {
        const size_t i = t << 2;
        const size_t b = i >> 19;
        const float4 v = *(const float4*)(qo + i);
        *(float4*)(out0 + i + ((b + 1) << 19)) = v;
    }
}

extern "C" void kernel_launch(void* const* d_in, const int* in_sizes, int n_in,
                              void* d_out, int out_size, void* d_ws, size_t ws_size,
                              hipStream_t stream)
{
    const float* m_in  = (const float*)d_in[0];
    const float* m_out = (const float*)d_in[1];
    const float* q_in  = (const float*)d_in[2];
    const float* q_out = (const float*)d_in[3];

    float* out0 = (float*)d_out;              // 4,194,304 floats
    float* p    = out0 + 4194304;             // 67,108,864 floats

    short* eT    = (short*)d_ws;              // 134MB bf16 [4][1024][16384]
    short* mobf  = (short*)d_ws + 67108864;   // +16MB bf16 [512][16384]
    float* wpart = (float*)((char*)d_ws + 150994944);  // +24MB splitK partials

    // scratch in out0's q_out-copy regions (overwritten later by k5):
    float* partial = out0 + 524288;           // b=0 region: [128][4][1024]
    float* invsum  = out0 + 1048576 + 524288; // b=1 region: [4][1024]

    const size_t need_eT   = 134217728ull;
    const size_t need_full = need_eT + 16777216ull;
    const size_t need_sk   = need_full + 3ull * 8388608ull;

    if (ws_size >= need_eT) {
        if (ws_size >= need_full)
            convm<<<dim3(1024), 256, 0, stream>>>(m_out, mobf);

        k1_mfma<<<dim3(8, 128, 4),  256, 0, stream>>>(m_in, q_in, eT, partial);
        k2b_red<<<dim3(128),        256, 0, stream>>>(partial, invsum);
        k3_big <<<dim3(16, 128, 4), 256, 0, stream>>>(p, eT, invsum);

        if (ws_size >= need_sk) {
            k4_sk  <<<dim3(512),  256, 0, stream>>>(mobf, eT, out0, wpart);
            k6_comb<<<dim3(2048), 256, 0, stream>>>(out0, wpart, invsum);
        } else if (ws_size >= need_full) {
            k4_gl<1><<<dim3(512), 256, 0, stream>>>(m_out, mobf, eT, invsum, out0);
        } else {
            k4_gl<0><<<dim3(512), 256, 0, stream>>>(m_out, mobf, eT, invsum, out0);
        }
    } else {
        k1_p    <<<dim3(8, 128, 4), 256, 0, stream>>>(m_in, q_in, p, partial);
        k2b_red <<<dim3(128),       256, 0, stream>>>(partial, invsum);
        k3_small<<<dim3(2048),      256, 0, stream>>>(p, invsum);
        k4_reg  <<<dim3(16, 8, 4),  256, 0, stream>>>(m_out, p, out0);
    }
    k5_copy<<<dim3(2048), 256, 0, stream>>>(q_out, out0);
}

// Round 10
// 295.170 us; speedup vs baseline: 6.3383x; 1.0395x over previous
//
#include <hip/hip_runtime.h>
#include <hip/hip_bf16.h>
#include <cstddef>

// m_in  raw-viewed as mi [128][16384]   fp32
// m_out raw-viewed as mo [512][16384]   fp32
// q_in  = qi [4][128][1024]             fp32
// q_out = qo [4][512][1024]             fp32
// out0  = mem_out [4][1024][1024]  (ch 0..511 = mem, ch 512..1023 = q_out copy)
// out1  = p [4][16384][1024] softmax over the 16384 axis
//
// ws layout (gated on ws_size):
//   [0,134MB)      eT bf16 [4][1024][16384]  (raw e = exp(score/sqrt(128)))
//   [134,151MB)    mobf bf16 [512][16384]
//   [151,175MB)    split-K partials: 3 x 2M fp32

#define DE   128
#define DO   512
#define NMEM 16384
#define QCOL 1024

typedef __attribute__((ext_vector_type(8))) short    short8v;
typedef __attribute__((ext_vector_type(4))) short    short4v;
typedef __attribute__((ext_vector_type(8))) _Float16 half8v;
typedef __attribute__((ext_vector_type(4))) float    f32x4;

__device__ __forceinline__ short f2bf(float x) {
    union { __hip_bfloat16 h; short s; } u;
    u.h = __float2bfloat16(x);
    return u.s;
}
__device__ __forceinline__ float bf2f(short s) {
    union { __hip_bfloat16 h; short s; } u;
    u.s = s;
    return __bfloat162float(u.h);
}

// bank-balancing XOR swizzle (granule-level), bijective per 8-row stripe
#define FSW(r) ((((r) >> 3) ^ (r)) & 7)

__device__ __forceinline__ void gl16(const short* g, short* l) {
    __builtin_amdgcn_global_load_lds(
        (const __attribute__((address_space(1))) void*)g,
        (__attribute__((address_space(3))) void*)l, 16, 0, 0);
}

// ===========================================================================
// BIG-WS PATH
// ===========================================================================

// K1 (big, MFMA): C[n][q] = sum_d mi[d][n]*qi[d][q] via f16 MFMA (A=mi, B=qi
// -- swapped so each lane holds 4 CONSECUTIVE n at fixed q), e=exp ->
// eT bf16 [b][q][n] + per-128n-tile column sums. Block 128q x 128n, K=128.
// grid (8 qt, 128 nt, 4 b).
__global__ __launch_bounds__(256, 2)
void k1_mfma(const float* __restrict__ mi, const float* __restrict__ qi,
             short* __restrict__ eT, float* __restrict__ partial)
{
    const int qb = blockIdx.x << 7;
    const int nb = blockIdx.y << 7;
    const int b  = blockIdx.z;

    __shared__ __align__(16) short AfBf[2][128 * 128]; // f16 as shorts
    __shared__ float red2[2][128];

    short* Bq = AfBf[0];   // [q][d] swizzled (B operand)
    short* An = AfBf[1];   // [n][d] swizzled (A operand)
    short* T  = AfBf[0];   // reused after MFMA: [q][n] bf16 swizzled

    const int tid  = threadIdx.x;
    const int lane = tid & 63;
    const int w    = tid >> 6;
    const int wn2  = (w >> 1) << 6;   // n-half 0/64
    const int wq   = (w & 1) << 6;    // q-half 0/64
    const int la   = lane & 15;
    const int kg   = lane >> 4;

    // staging: thread covers 8 d-rows x (2 x 4 cols), reg-transpose, swizzled
    {
        const int d8 = (tid >> 4) << 3;       // 0..120
        const int c4 = (tid & 15) << 2;       // 0..60
        const float* qib = qi + (size_t)b * (DE * QCOL) + (size_t)d8 * QCOL + qb;
        const float* mib = mi + (size_t)d8 * NMEM + nb;
#pragma unroll
        for (int half = 0; half < 2; ++half) {
            const int c = c4 + (half << 6);   // 0..124
            f32x4 qv[8], mv[8];
#pragma unroll
            for (int i = 0; i < 8; ++i) {
                qv[i] = *(const f32x4*)(qib + (size_t)i * QCOL + c);
                mv[i] = *(const f32x4*)(mib + (size_t)i * NMEM + c);
            }
#pragma unroll
            for (int j = 0; j < 4; ++j) {
                const int row = c + j;
                const int off = row * 128 + ((((d8 >> 3) ^ FSW(row))) << 3);
                half8v av, bv;
#pragma unroll
                for (int i = 0; i < 8; ++i) {
                    av[i] = (_Float16)qv[i][j];
                    bv[i] = (_Float16)mv[i][j];
                }
                *(half8v*)&Bq[off] = av;
                *(half8v*)&An[off] = bv;
            }
        }
    }
    __syncthreads();

    // MFMA: A = mi rows (n), B = qi rows (q). acc[fm][fn]:
    //   row n = wn2 + fm*16 + (kg<<2)+r ; col q = wq + fn*16 + la
    f32x4 acc[4][4];
#pragma unroll
    for (int i = 0; i < 4; ++i)
#pragma unroll
        for (int j = 0; j < 4; ++j) acc[i][j] = (f32x4){0.f, 0.f, 0.f, 0.f};

#pragma unroll
    for (int ks = 0; ks < 4; ++ks) {
        half8v af[4], bf[4];
#pragma unroll
        for (int f = 0; f < 4; ++f) {
            const int ra = wn2 + f * 16 + la;   // A rows: n
            const int rb = wq  + f * 16 + la;   // B rows: q
            af[f] = *(const half8v*)&An[ra * 128 + ((((ks << 2) + kg) ^ FSW(ra)) << 3)];
            bf[f] = *(const half8v*)&Bq[rb * 128 + ((((ks << 2) + kg) ^ FSW(rb)) << 3)];
        }
#pragma unroll
        for (int fm = 0; fm < 4; ++fm)
#pragma unroll
            for (int fn = 0; fn < 4; ++fn)
                acc[fm][fn] = __builtin_amdgcn_mfma_f32_16x16x32_f16(
                    af[fm], bf[fn], acc[fm][fn], 0, 0, 0);
    }

    const float scale = 0.08838834764831845f; // 1/sqrt(128)
#pragma unroll
    for (int fm = 0; fm < 4; ++fm)
#pragma unroll
        for (int fn = 0; fn < 4; ++fn)
#pragma unroll
            for (int r = 0; r < 4; ++r)
                acc[fm][fn][r] = __expf(acc[fm][fn][r] * scale);

    // colsum over n per q-col: lane-local over (fm,r), then kg-reduce
    float val[4];
#pragma unroll
    for (int fn = 0; fn < 4; ++fn) {
        float s = 0.f;
#pragma unroll
        for (int fm = 0; fm < 4; ++fm)
#pragma unroll
            for (int r = 0; r < 4; ++r) s += acc[fm][fn][r];
        s += __shfl_xor(s, 16);
        s += __shfl_xor(s, 32);
        val[fn] = s;   // sum over this wave's 64 n for q = wq+fn*16+la
    }

    __syncthreads();   // An/Bq reads done; T may overwrite AfBf[0]

    // T[q][n] bf16 (swizzled): per (fm,fn) write 4 consecutive n as b64
#pragma unroll
    for (int fn = 0; fn < 4; ++fn) {
        const int q  = wq + fn * 16 + la;
        const int fq = FSW(q);
#pragma unroll
        for (int fm = 0; fm < 4; ++fm) {
            const int n0 = wn2 + fm * 16 + (kg << 2);
            short4v v;
#pragma unroll
            for (int r = 0; r < 4; ++r) v[r] = f2bf(acc[fm][fn][r]);
            *(short4v*)&T[q * 128 + (((n0 >> 3) ^ fq) << 3) + (n0 & 7)] = v;
        }
    }
    if (kg == 0) {
#pragma unroll
        for (int fn = 0; fn < 4; ++fn)
            red2[w >> 1][wq + fn * 16 + la] = val[fn];
    }
    __syncthreads();

    if (tid < 128) {
        partial[(size_t)blockIdx.y * 4096 + (b << 10) + qb + tid] =
            red2[0][tid] + red2[1][tid];
    }

    // gather T -> eT global (128B contiguous per thread)
    {
        const int ql = tid >> 1;
        const int h  = tid & 1;
        const int fq = FSW(ql);
        short* dst = eT + ((size_t)b << 24) + (size_t)(qb + ql) * NMEM + nb;
#pragma unroll
        for (int k = 0; k < 8; ++k) {
            const int m = h * 8 + k;
            short8v v = *(const short8v*)&T[ql * 128 + ((m ^ fq) << 3)];
            *(short8v*)(dst + m * 8) = v;
        }
    }
}

// K3 (big): read eT bf16 [q][n] (read-only), scale by invsum[q], write
// p fp32 [n][q] via LDS transpose. Block = 64 q x 128 n. grid (16,128,4).
__global__ __launch_bounds__(256)
void k3_big(float* __restrict__ p, const short* __restrict__ eT,
            const float* __restrict__ invsum)
{
    const int qb = blockIdx.x << 6;
    const int nb = blockIdx.y << 7;
    const int b  = blockIdx.z;

    __shared__ __align__(16) float P[64 * 128];

    const int tid = threadIdx.x;

    {
        const int ql  = tid >> 2;
        const int nc  = (tid & 3) << 5;
        const int fq  = FSW(ql);
        const float inv = invsum[(b << 10) + qb + ql];
        const short* rowp = eT + ((size_t)b << 24) + (size_t)(qb + ql) * NMEM + nb + nc;
#pragma unroll
        for (int k = 0; k < 4; ++k) {
            short8v v = *(const short8v*)(rowp + k * 8);
            float f[8];
#pragma unroll
            for (int h = 0; h < 8; ++h) f[h] = bf2f(v[h]) * inv;
            const int gg0 = (nc >> 2) + k * 2;
            *(f32x4*)&P[ql * 128 + (((gg0)     ^ fq) << 2)] = *(f32x4*)&f[0];
            *(f32x4*)&P[ql * 128 + (((gg0 + 1) ^ fq) << 2)] = *(f32x4*)&f[4];
        }
    }
    __syncthreads();

    {
        const int tx  = tid & 15;
        const int tyy = tid >> 4;
        float* pb = p + ((size_t)b << 24);
#pragma unroll
        for (int r = 0; r < 2; ++r) {
            const int gg = tyy + 16 * r;
            f32x4 v[4];
#pragma unroll
            for (int i = 0; i < 4; ++i) {
                const int ql = tx * 4 + i;
                v[i] = *(const f32x4*)&P[ql * 128 + ((gg ^ FSW(ql)) << 2)];
            }
#pragma unroll
            for (int jj = 0; jj < 4; ++jj) {
                f32x4 o = {v[0][jj], v[1][jj], v[2][jj], v[3][jj]};
                *(f32x4*)(pb + (size_t)(nb + gg * 4 + jj) * QCOL + qb + tx * 4) = o;
            }
        }
    }
}

// convm: mo fp32 [512][16384] -> mobf bf16. grid 1024 x 256 thr x 4 units.
__global__ __launch_bounds__(256)
void convm(const float* __restrict__ mo, short* __restrict__ mobf)
{
    const size_t u = (size_t)blockIdx.x * 256 + threadIdx.x;  // 0..262143
#pragma unroll
    for (int r = 0; r < 4; ++r) {
        const size_t i = (u + (size_t)r * 262144) << 3;       // float index
        f32x4 a = *(const f32x4*)(mo + i);
        f32x4 c = *(const f32x4*)(mo + i + 4);
        short8v v;
#pragma unroll
        for (int h = 0; h < 4; ++h) { v[h] = f2bf(a[h]); v[h + 4] = f2bf(c[h]); }
        *(short8v*)(mobf + i) = v;
    }
}

// ---------------------------------------------------------------------------
// K4 split-K: mem_raw[b][o][q] = sum_n mobf[o][n]*eT[b][q][n], K split x4.
// 128x128 tile, 4 waves each 64x64 (4x4 frags), BK=64, gl_lds staging.
// split 0 -> out0 mem region (raw); splits 1..3 -> part[]. Combine applies
// (s0+s1+s2+s3)*invsum. grid 512 flat XCD-swizzled, 2 blocks/CU.
// ---------------------------------------------------------------------------
__global__ __launch_bounds__(256, 2)
void k4_sk(const short* __restrict__ mobf, const short* __restrict__ eT,
           float* __restrict__ out0, float* __restrict__ part)
{
    const int sw    = ((blockIdx.x & 7) << 6) | (blockIdx.x >> 3);
    const int split = sw >> 7;          // 0..3
    const int tile  = sw & 127;
    const int b  = tile >> 5;
    const int ot = (tile >> 3) & 3;
    const int qt = tile & 7;
    const int ob = ot << 7;
    const int qb = qt << 7;
    const int kb = split << 12;         // *4096

    __shared__ __align__(16) short As[2][128 * 64];  // [o][k] linear (gl_lds)
    __shared__ __align__(16) short Bs[2][128 * 64];  // [q][k]

    const int tid  = threadIdx.x;
    const int lane = tid & 63;
    const int w    = tid >> 6;
    const int wm   = (w >> 1) << 6;   // 0/64 (o)
    const int wn   = (w & 1) << 6;    // 0/64 (q)
    const int la   = lane & 15;
    const int kg   = lane >> 4;

    // staging: per wave 4 issues each for A,B; issue covers 8 rows x 64 bf16
    size_t offA[4], offB[4];
    int lbo[4];
#pragma unroll
    for (int i = 0; i < 4; ++i) {
        const int rowb = (w << 5) + (i << 3);
        const int rl   = rowb + (lane >> 3);
        const int gs   = (lane & 7) ^ FSW(rl);
        offA[i] = (size_t)(ob + rl) * NMEM + gs * 8;
        offB[i] = (size_t)(qb + rl) * NMEM + gs * 8;
        lbo[i]  = rowb * 64;
    }
    const short* eTb = eT + ((size_t)b << 24);

#define SK_STAGE(BUF, K0)                                                      \
    do {                                                                       \
        _Pragma("unroll")                                                      \
        for (int i = 0; i < 4; ++i) {                                          \
            gl16(mobf + offA[i] + (K0), &As[BUF][lbo[i]]);                     \
            gl16(eTb  + offB[i] + (K0), &Bs[BUF][lbo[i]]);                     \
        }                                                                      \
    } while (0)

    // frag read offsets (swizzled): 8 granules/row of 64 bf16
    int rA[4][2], rB[4][2];
#pragma unroll
    for (int f = 0; f < 4; ++f) {
        const int rowA = wm + f * 16 + la;
        const int rowB = wn + f * 16 + la;
#pragma unroll
        for (int s = 0; s < 2; ++s) {
            rA[f][s] = rowA * 64 + ((((s << 2) + kg) ^ FSW(rowA)) << 3);
            rB[f][s] = rowB * 64 + ((((s << 2) + kg) ^ FSW(rowB)) << 3);
        }
    }

    f32x4 acc[4][4];
#pragma unroll
    for (int i = 0; i < 4; ++i)
#pragma unroll
        for (int j = 0; j < 4; ++j) acc[i][j] = (f32x4){0.f, 0.f, 0.f, 0.f};

    SK_STAGE(0, kb);
    __syncthreads();

    int cur = 0;
    for (int t = 0; t < 64; ++t) {
        const bool pf = (t + 1) < 64;
        if (pf) SK_STAGE(cur ^ 1, kb + (t + 1) * 64);

#pragma unroll
        for (int s = 0; s < 2; ++s) {
            short8v af[4], bf[4];
#pragma unroll
            for (int f = 0; f < 4; ++f) {
                af[f] = *(const short8v*)&As[cur][rA[f][s]];
                bf[f] = *(const short8v*)&Bs[cur][rB[f][s]];
            }
#pragma unroll
            for (int fm = 0; fm < 4; ++fm)
#pragma unroll
                for (int fn = 0; fn < 4; ++fn)
                    acc[fm][fn] = __builtin_amdgcn_mfma_f32_16x16x32_bf16(
                        af[fm], bf[fn], acc[fm][fn], 0, 0, 0);
        }
        __syncthreads();
        cur ^= 1;
    }

    // epilogue: C layout col=lane&15 (q), row=(lane>>4)*4+r (o)
    if (split == 0) {
        float* outb = out0 + ((size_t)b << 20);
#pragma unroll
        for (int fm = 0; fm < 4; ++fm)
#pragma unroll
            for (int fn = 0; fn < 4; ++fn)
#pragma unroll
                for (int r = 0; r < 4; ++r) {
                    const int o = ob + wm + fm * 16 + (kg << 2) + r;
                    const int q = qb + wn + fn * 16 + la;
                    outb[(size_t)o * 1024 + q] = acc[fm][fn][r];
                }
    } else {
        float* pp = part + (size_t)(split - 1) * 2097152;
#pragma unroll
        for (int fm = 0; fm < 4; ++fm)
#pragma unroll
            for (int fn = 0; fn < 4; ++fn)
#pragma unroll
                for (int r = 0; r < 4; ++r) {
                    const int o = ob + wm + fm * 16 + (kg << 2) + r;
                    const int q = qb + wn + fn * 16 + la;
                    pp[(((size_t)(b << 9) + o) << 10) + q] = acc[fm][fn][r];
                }
    }
#undef SK_STAGE
}

// K6: out0.mem = (s0 + s1 + s2 + s3) * invsum. grid 2048 x 256.
__global__ __launch_bounds__(256)
void k6_comb(float* __restrict__ out0, const float* __restrict__ part,
             const float* __restrict__ invsum)
{
    const size_t t = (size_t)blockIdx.x * 256 + threadIdx.x;
    if (t < 524288ull) {
        const size_t v = t << 2;             // flat index into 2M partial
        const int b = (int)(v >> 19);
        const int q = (int)(v & 1023);
        float* dst = out0 + v + ((size_t)b << 19);
        f32x4 s0 = *(const f32x4*)dst;
        f32x4 s1 = *(const f32x4*)(part + v);
        f32x4 s2 = *(const f32x4*)(part + v + 2097152);
        f32x4 s3 = *(const f32x4*)(part + v + 4194304);
        f32x4 inv = *(const f32x4*)(invsum + (b << 10) + q);
        f32x4 o;
#pragma unroll
        for (int h = 0; h < 4; ++h)
            o[h] = (s0[h] + s1[h] + s2[h] + s3[h]) * inv[h];
        *(f32x4*)dst = o;
    }
}

// K4 (fallback, 64x64 tile): mem = (mo . e) * invsum epilogue.
// HASMOBF=1: A via gl_lds from mobf; 0: A reg-staged from fp32 mo.
template <int HASMOBF>
__global__ __launch_bounds__(256, 2)
void k4_gl(const float* __restrict__ mo, const short* __restrict__ mobf,
           const short* __restrict__ eT, const float* __restrict__ invsum,
           float* __restrict__ out0)
{
    const int sw = ((blockIdx.x & 7) << 6) | (blockIdx.x >> 3);
    const int b  = sw >> 7;
    const int ot = (sw & 127) >> 4;
    const int qt = sw & 15;
    const int ob = ot << 6;
    const int qb = qt << 6;

    __shared__ __align__(16) short As[2][64 * 128];
    __shared__ __align__(16) short Bs[2][64 * 128];

    const int tid  = threadIdx.x;
    const int lane = tid & 63;
    const int w    = tid >> 6;
    const int w16  = w << 4;
    const int wm   = (w >> 1) << 5;
    const int wn   = (w & 1) << 5;

    const int ln4 = lane >> 4;
    const int lg  = lane & 15;
    size_t off[4];
    int    lbo[4];
#pragma unroll
    for (int i = 0; i < 4; ++i) {
        const int rl = w16 + i * 4 + ln4;
        const int gs = lg ^ FSW(rl);
        off[i] = (size_t)rl * NMEM + gs * 8;
        lbo[i] = (w16 + i * 4) * 128;
    }
    const short* eTb = eT + (((size_t)(b << 10) + qb) * NMEM);
    const short* moA = mobf + (size_t)ob * NMEM;

    const int aro = tid >> 4;
    const int ak8 = (tid & 15) << 3;
    int sAf[4];
    f32x4 aA[4][2];
    const float* gA = mo + (size_t)(ob + aro) * NMEM + ak8;
#pragma unroll
    for (int j = 0; j < 4; ++j) {
        const int rl = aro + 16 * j;
        sAf[j] = rl * 128 + (((ak8 >> 3) ^ FSW(rl)) << 3);
    }

#define STAGE_B(BUF, K0)                                                       \
    do {                                                                       \
        _Pragma("unroll")                                                      \
        for (int i = 0; i < 4; ++i)                                            \
            gl16(eTb + off[i] + (K0), &Bs[BUF][lbo[i]]);                       \
    } while (0)
#define STAGE_A(BUF, K0)                                                       \
    do {                                                                       \
        _Pragma("unroll")                                                      \
        for (int i = 0; i < 4; ++i)                                            \
            gl16(moA + off[i] + (K0), &As[BUF][lbo[i]]);                       \
    } while (0)
#define LOADA_REG(K0)                                                          \
    do {                                                                       \
        _Pragma("unroll")                                                      \
        for (int j = 0; j < 4; ++j) {                                          \
            aA[j][0] = *(const f32x4*)(gA + (size_t)(16 * j) * NMEM + (K0));   \
            aA[j][1] = *(const f32x4*)(gA + (size_t)(16 * j) * NMEM + (K0)+4); \
        }                                                                      \
    } while (0)
#define STOREA_REG(BUF)                                                        \
    do {                                                                       \
        _Pragma("unroll")                                                      \
        for (int j = 0; j < 4; ++j) {                                          \
            short8v v;                                                         \
            _Pragma("unroll")                                                  \
            for (int h = 0; h < 4; ++h) { v[h] = f2bf(aA[j][0][h]);            \
                                          v[h + 4] = f2bf(aA[j][1][h]); }      \
            *(short8v*)&As[BUF][sAf[j]] = v;                                   \
        }                                                                      \
    } while (0)

    f32x4 acc[2][2];
#pragma unroll
    for (int i = 0; i < 2; ++i)
#pragma unroll
        for (int j = 0; j < 2; ++j) acc[i][j] = (f32x4){0.f, 0.f, 0.f, 0.f};

    if (HASMOBF) { STAGE_A(0, 0); } else { LOADA_REG(0); STOREA_REG(0); }
    STAGE_B(0, 0);
    __syncthreads();

    const int la = lane & 15;
    const int kg = lane >> 4;

    int rA[2][4], rB[2][4];
#pragma unroll
    for (int fm = 0; fm < 2; ++fm) {
        const int rowA = wm + la + 16 * fm;
        const int rowB = wn + la + 16 * fm;
#pragma unroll
        for (int s = 0; s < 4; ++s) {
            rA[fm][s] = rowA * 128 + ((((s << 2) + kg) ^ FSW(rowA)) << 3);
            rB[fm][s] = rowB * 128 + ((((s << 2) + kg) ^ FSW(rowB)) << 3);
        }
    }

    int cur = 0;
    for (int t = 0; t < NMEM / 128; ++t) {
        const bool pf = (t + 1) < NMEM / 128;
        if (pf) {
            if (HASMOBF) STAGE_A(cur ^ 1, (size_t)(t + 1) * 128);
            else         LOADA_REG((t + 1) * 128);
            STAGE_B(cur ^ 1, (size_t)(t + 1) * 128);
        }
#pragma unroll
        for (int s = 0; s < 4; ++s) {
            short8v a0 = *(const short8v*)&As[cur][rA[0][s]];
            short8v a1 = *(const short8v*)&As[cur][rA[1][s]];
            short8v b0 = *(const short8v*)&Bs[cur][rB[0][s]];
            short8v b1 = *(const short8v*)&Bs[cur][rB[1][s]];
            acc[0][0] = __builtin_amdgcn_mfma_f32_16x16x32_bf16(a0, b0, acc[0][0], 0, 0, 0);
            acc[0][1] = __builtin_amdgcn_mfma_f32_16x16x32_bf16(a0, b1, acc[0][1], 0, 0, 0);
            acc[1][0] = __builtin_amdgcn_mfma_f32_16x16x32_bf16(a1, b0, acc[1][0], 0, 0, 0);
            acc[1][1] = __builtin_amdgcn_mfma_f32_16x16x32_bf16(a1, b1, acc[1][1], 0, 0, 0);
        }
        if (!HASMOBF && pf) STOREA_REG(cur ^ 1);
        __syncthreads();
        cur ^= 1;
    }

    const int orow = ob + wm + (kg << 2);
    const int qcol = qb + wn + la;
    const float i0 = invsum[(b << 10) + qcol];
    const float i1 = invsum[(b << 10) + qcol + 16];
    float* __restrict__ outb = out0 + ((size_t)b << 20);
#pragma unroll
    for (int fm = 0; fm < 2; ++fm)
#pragma unroll
        for (int r = 0; r < 4; ++r) {
            outb[(size_t)(orow + 16 * fm + r) * 1024 + qcol]      = acc[fm][0][r] * i0;
            outb[(size_t)(orow + 16 * fm + r) * 1024 + qcol + 16] = acc[fm][1][r] * i1;
        }
#undef STAGE_A
#undef STAGE_B
#undef LOADA_REG
#undef STOREA_REG
}

// ===========================================================================
// SMALL-WS FALLBACK PATH (R4 pipeline)
// ===========================================================================

__global__ __launch_bounds__(256, 2)
void k1_p(const float* __restrict__ mi, const float* __restrict__ qi,
          float* __restrict__ p, float* __restrict__ partial)
{
    const int qb = blockIdx.x << 7;
    const int nb = blockIdx.y << 7;
    const int b  = blockIdx.z;
    const float* __restrict__ qib = qi + (size_t)b * (DE * QCOL);

    __shared__ float As[8][132];
    __shared__ float Bs[8][132];
    __shared__ float red[16][128];

    const int tid = threadIdx.x;
    const int tx  = tid & 15;
    const int ty  = tid >> 4;

    float acc[8][8];
#pragma unroll
    for (int i = 0; i < 8; ++i)
#pragma unroll
        for (int j = 0; j < 8; ++j) acc[i][j] = 0.f;

    const int ld_d = tid >> 5;
    const int ld_n = (tid & 31) << 2;

    for (int k0 = 0; k0 < DE; k0 += 8) {
        float4 av = *(const float4*)(mi  + (size_t)(k0 + ld_d) * NMEM + nb + ld_n);
        float4 bv = *(const float4*)(qib + (size_t)(k0 + ld_d) * QCOL + qb + ld_n);
        *(float4*)&As[ld_d][ld_n] = av;
        *(float4*)&Bs[ld_d][ld_n] = bv;
        __syncthreads();
#pragma unroll
        for (int kk = 0; kk < 8; ++kk) {
            float a[8], bb[8];
            *(float4*)&a[0]  = *(float4*)&As[kk][ty * 8];
            *(float4*)&a[4]  = *(float4*)&As[kk][ty * 8 + 4];
            *(float4*)&bb[0] = *(float4*)&Bs[kk][tx * 8];
            *(float4*)&bb[4] = *(float4*)&Bs[kk][tx * 8 + 4];
#pragma unroll
            for (int i = 0; i < 8; ++i)
#pragma unroll
                for (int j = 0; j < 8; ++j)
                    acc[i][j] += a[i] * bb[j];
        }
        __syncthreads();
    }

    const float scale = 0.08838834764831845f;
    float cs[8];
#pragma unroll
    for (int j = 0; j < 8; ++j) cs[j] = 0.f;
    float* __restrict__ pb = p + ((size_t)b << 24);
#pragma unroll
    for (int i = 0; i < 8; ++i) {
        const int n = nb + ty * 8 + i;
        float e[8];
#pragma unroll
        for (int j = 0; j < 8; ++j) {
            e[j] = __expf(acc[i][j] * scale);
            cs[j] += e[j];
        }
        *(float4*)(pb + ((size_t)n << 10) + qb + tx * 8)     = *(float4*)&e[0];
        *(float4*)(pb + ((size_t)n << 10) + qb + tx * 8 + 4) = *(float4*)&e[4];
    }

#pragma unroll
    for (int j = 0; j < 8; ++j) red[ty][tx * 8 + j] = cs[j];
    __syncthreads();
    if (tid < 128) {
        float s = 0.f;
#pragma unroll
        for (int t = 0; t < 16; ++t) s += red[t][tid];
        partial[(size_t)blockIdx.y * 4096 + (b << 10) + qb + tid] = s;
    }
}

__global__ __launch_bounds__(256)
void k3_small(float* __restrict__ p, const float* __restrict__ invsum)
{
    const size_t stride = (size_t)gridDim.x * blockDim.x;
    for (size_t t = (size_t)blockIdx.x * 256 + threadIdx.x; t < 16777216ull; t += stride) {
        const size_t i = t << 2;
        float4 v = *(float4*)(p + i);
        const int q = (int)(i & 1023);
        const int b = (int)(i >> 24);
        const float4 inv = *(const float4*)(invsum + (b << 10) + q);
        v.x *= inv.x; v.y *= inv.y; v.z *= inv.z; v.w *= inv.w;
        *(float4*)(p + i) = v;
    }
}

__global__ __launch_bounds__(256, 2)
void k4_reg(const float* __restrict__ mo, const float* __restrict__ p,
            float* __restrict__ out0)
{
    const int qb = blockIdx.x << 6;
    const int ob = blockIdx.y << 6;
    const int b  = blockIdx.z;
    const float* __restrict__ pb = p + ((size_t)b << 24);

    __shared__ __align__(16) short As[2][64 * 128];
    __shared__ __align__(16) short Bs[2][64 * 128];

    const int tid  = threadIdx.x;
    const int lane = tid & 63;
    const int w    = tid >> 6;
    const int wm   = (w >> 1) << 5;
    const int wn   = (w & 1) << 5;

    const int aro = tid >> 4;
    const int ak8 = (tid & 15) << 3;
    const int bn8 = (tid >> 4) << 3;
    const int bq4 = (tid & 15) << 2;

    int sA[4], sB[4];
#pragma unroll
    for (int j = 0; j < 4; ++j) {
        const int rlA = aro + 16 * j;
        sA[j] = rlA * 128 + ((((ak8 >> 3) ^ FSW(rlA))) << 3);
        const int rlB = bq4 + j;
        sB[j] = rlB * 128 + ((((bn8 >> 3) ^ FSW(rlB))) << 3);
    }

    const float* __restrict__ gA = mo + (size_t)(ob + aro) * NMEM + ak8;
    const float* __restrict__ gB = pb + (size_t)bn8 * QCOL + qb + bq4;

    f32x4 aA[4][2], aB[8];

#define K4_LOAD(K0)                                                              \
    do {                                                                         \
        _Pragma("unroll")                                                        \
        for (int j = 0; j < 4; ++j) {                                            \
            aA[j][0] = *(const f32x4*)(gA + (size_t)(16 * j) * NMEM + (K0));     \
            aA[j][1] = *(const f32x4*)(gA + (size_t)(16 * j) * NMEM + (K0) + 4); \
        }                                                                        \
        _Pragma("unroll")                                                        \
        for (int i = 0; i < 8; ++i)                                              \
            aB[i] = *(const f32x4*)(gB + ((size_t)(K0) + i) * QCOL);             \
    } while (0)

#define K4_STORE(BUF)                                                            \
    do {                                                                         \
        _Pragma("unroll")                                                        \
        for (int j = 0; j < 4; ++j) {                                            \
            short8v v;                                                           \
            _Pragma("unroll")                                                    \
            for (int h = 0; h < 4; ++h) { v[h] = f2bf(aA[j][0][h]);              \
                                          v[h + 4] = f2bf(aA[j][1][h]); }        \
            *(short8v*)&As[BUF][sA[j]] = v;                                      \
        }                                                                        \
        _Pragma("unroll")                                                        \
        for (int j = 0; j < 4; ++j) {                                            \
            short8v v;                                                           \
            _Pragma("unroll")                                                    \
            for (int i = 0; i < 8; ++i) v[i] = f2bf(aB[i][j]);                   \
            *(short8v*)&Bs[BUF][sB[j]] = v;                                      \
        }                                                                        \
    } while (0)

    f32x4 acc[2][2];
#pragma unroll
    for (int i = 0; i < 2; ++i)
#pragma unroll
        for (int j = 0; j < 2; ++j) acc[i][j] = (f32x4){0.f, 0.f, 0.f, 0.f};

    K4_LOAD(0);
    K4_STORE(0);
    __syncthreads();

    const int la = lane & 15;
    const int kg = lane >> 4;

    int rA[2][4], rB[2][4];
#pragma unroll
    for (int fm = 0; fm < 2; ++fm) {
        const int rowA = wm + la + 16 * fm;
        const int rowB = wn + la + 16 * fm;
#pragma unroll
        for (int s = 0; s < 4; ++s) {
            rA[fm][s] = rowA * 128 + ((((s << 2) + kg) ^ FSW(rowA)) << 3);
            rB[fm][s] = rowB * 128 + ((((s << 2) + kg) ^ FSW(rowB)) << 3);
        }
    }

    int cur = 0;
    for (int t = 0; t < NMEM / 128; ++t) {
        const bool pf = (t + 1) < NMEM / 128;
        if (pf) K4_LOAD((t + 1) * 128);

#pragma unroll
        for (int s = 0; s < 4; ++s) {
            short8v a0 = *(const short8v*)&As[cur][rA[0][s]];
            short8v a1 = *(const short8v*)&As[cur][rA[1][s]];
            short8v b0 = *(const short8v*)&Bs[cur][rB[0][s]];
            short8v b1 = *(const short8v*)&Bs[cur][rB[1][s]];
            acc[0][0] = __builtin_amdgcn_mfma_f32_16x16x32_bf16(a0, b0, acc[0][0], 0, 0, 0);
            acc[0][1] = __builtin_amdgcn_mfma_f32_16x16x32_bf16(a0, b1, acc[0][1], 0, 0, 0);
            acc[1][0] = __builtin_amdgcn_mfma_f32_16x16x32_bf16(a1, b0, acc[1][0], 0, 0, 0);
            acc[1][1] = __builtin_amdgcn_mfma_f32_16x16x32_bf16(a1, b1, acc[1][1], 0, 0, 0);
        }

        if (pf) K4_STORE(cur ^ 1);
        __syncthreads();
        cur ^= 1;
    }

    const int orow = ob + wm + (kg << 2);
    const int qcol = qb + wn + la;
    float* __restrict__ outb = out0 + ((size_t)b << 20);
#pragma unroll
    for (int fm = 0; fm < 2; ++fm)
#pragma unroll
        for (int fn = 0; fn < 2; ++fn)
#pragma unroll
            for (int r = 0; r < 4; ++r)
                outb[(size_t)(orow + 16 * fm + r) * 1024 + qcol + 16 * fn] =
                    acc[fm][fn][r];
#undef K4_LOAD
#undef K4_STORE
}

// ===========================================================================
// SHARED
// ===========================================================================

__global__ __launch_bounds__(256)
void k2b_red(const float* __restrict__ partial, float* __restrict__ invsum)
{
    __shared__ float red[8][32];
    const int col = blockIdx.x * 32 + (threadIdx.x & 31);
    const int g   = threadIdx.x >> 5;
    float s = 0.f;
#pragma unroll
    for (int r = 0; r < 16; ++r)
        s += partial[(size_t)(g * 16 + r) * 4096 + col];
    red[g][threadIdx.x & 31] = s;
    __syncthreads();
    if (threadIdx.x < 32) {
        float t = 0.f;
#pragma unroll
        for (int g2 = 0; g2 < 8; ++g2) t += red[g2][threadIdx.x];
        invsum[col] = 1.0f / t;
    }
}

__global__ __launch_bounds__(256)
void k5_copy(const float* __restrict__ qo, float* __restrict__ out0)
{
    const size_t t = (size_t)blockIdx.x * 256 + threadIdx.x;
    if (t < 524288ull) {
        const size_t i = t << 2;
        const size_t b = i >> 19;
        const float4 v = *(const float4*)(qo + i);
        *(float4*)(out0 + i + ((b + 1) << 19)) = v;
    }
}

extern "C" void kernel_launch(void* const* d_in, const int* in_sizes, int n_in,
                              void* d_out, int out_size, void* d_ws, size_t ws_size,
                              hipStream_t stream)
{
    const float* m_in  = (const float*)d_in[0];
    const float* m_out = (const float*)d_in[1];
    const float* q_in  = (const float*)d_in[2];
    const float* q_out = (const float*)d_in[3];

    float* out0 = (float*)d_out;              // 4,194,304 floats
    float* p    = out0 + 4194304;             // 67,108,864 floats

    short* eT    = (short*)d_ws;              // 134MB bf16 [4][1024][16384]
    short* mobf  = (short*)d_ws + 67108864;   // +16MB bf16 [512][16384]
    float* wpart = (float*)((char*)d_ws + 150994944);  // +24MB splitK partials

    // scratch in out0's q_out-copy regions (overwritten later by k5):
    float* partial = out0 + 524288;           // b=0 region: [128][4][1024]
    float* invsum  = out0 + 1048576 + 524288; // b=1 region: [4][1024]

    const size_t need_eT   = 134217728ull;
    const size_t need_full = need_eT + 16777216ull;
    const size_t need_sk   = need_full + 3ull * 8388608ull;

    if (ws_size >= need_eT) {
        if (ws_size >= need_full)
            convm<<<dim3(1024), 256, 0, stream>>>(m_out, mobf);

        k1_mfma<<<dim3(8, 128, 4),  256, 0, stream>>>(m_in, q_in, eT, partial);
        k2b_red<<<dim3(128),        256, 0, stream>>>(partial, invsum);
        k3_big <<<dim3(16, 128, 4), 256, 0, stream>>>(p, eT, invsum);

        if (ws_size >= need_sk) {
            k4_sk  <<<dim3(512),  256, 0, stream>>>(mobf, eT, out0, wpart);
            k6_comb<<<dim3(2048), 256, 0, stream>>>(out0, wpart, invsum);
        } else if (ws_size >= need_full) {
            k4_gl<1><<<dim3(512), 256, 0, stream>>>(m_out, mobf, eT, invsum, out0);
        } else {
            k4_gl<0><<<dim3(512), 256, 0, stream>>>(m_out, mobf, eT, invsum, out0);
        }
    } else {
        k1_p    <<<dim3(8, 128, 4), 256, 0, stream>>>(m_in, q_in, p, partial);
        k2b_red <<<dim3(128),       256, 0, stream>>>(partial, invsum);
        k3_small<<<dim3(2048),      256, 0, stream>>>(p, invsum);
        k4_reg  <<<dim3(16, 8, 4),  256, 0, stream>>>(m_out, p, out0);
    }
    k5_copy<<<dim3(2048), 256, 0, stream>>>(q_out, out0);
}

// Round 11
// 200.112 us; speedup vs baseline: 9.3492x; 1.4750x over previous
//
#include <hip/hip_runtime.h>
#include <hip/hip_bf16.h>
#include <cstddef>

// m_in  raw-viewed as mi [128][16384]   fp32
// m_out raw-viewed as mo [512][16384]   fp32
// q_in  = qi [4][128][1024]             fp32
// q_out = qo [4][512][1024]             fp32
// out0  = mem_out [4][1024][1024]  (ch 0..511 = mem, ch 512..1023 = q_out copy)
// out1  = p [4][16384][1024] softmax over the 16384 axis
//
// ws layout (big path, gated on ws_size >= 176160768 -- known satisfied):
//   [0, 64MB)      e8  fp8 e4m3 [4][1024][16384]  (raw e = exp(score/sqrt(128)))
//   [64MB, 72MB)   mo8 fp8 e4m3 [512][16384]
//   [72MB, 96MB)   split-K partials: 3 x 2M fp32

#define DE   128
#define DO   512
#define NMEM 16384
#define QCOL 1024

typedef __attribute__((ext_vector_type(8))) short    short8v;
typedef __attribute__((ext_vector_type(4))) short    short4v;
typedef __attribute__((ext_vector_type(8))) _Float16 half8v;
typedef __attribute__((ext_vector_type(4))) float    f32x4;
typedef __attribute__((ext_vector_type(2))) float    f32x2;
typedef __attribute__((ext_vector_type(2))) unsigned u32x2;
typedef __attribute__((ext_vector_type(4))) unsigned u32x4;

__device__ __forceinline__ short f2bf(float x) {
    union { __hip_bfloat16 h; short s; } u;
    u.h = __float2bfloat16(x);
    return u.s;
}
__device__ __forceinline__ float bf2f(short s) {
    union { __hip_bfloat16 h; short s; } u;
    u.s = s;
    return __bfloat162float(u.h);
}

// pack 4 f32 -> 4 fp8(e4m3) in a u32 (byte i = fp8(f_i))
__device__ __forceinline__ unsigned pk_fp8x4(float f0, float f1, float f2, float f3) {
    unsigned r = __builtin_amdgcn_cvt_pk_fp8_f32(f0, f1, 0, false);
    r = __builtin_amdgcn_cvt_pk_fp8_f32(f2, f3, r, true);
    return r;
}

// bank-balancing XOR swizzle (granule-level), bijective per 8-row stripe
#define FSW(r) ((((r) >> 3) ^ (r)) & 7)

__device__ __forceinline__ void gl16(const short* g, short* l) {
    __builtin_amdgcn_global_load_lds(
        (const __attribute__((address_space(1))) void*)g,
        (__attribute__((address_space(3))) void*)l, 16, 0, 0);
}
__device__ __forceinline__ void gl16c(const unsigned char* g, unsigned char* l) {
    __builtin_amdgcn_global_load_lds(
        (const __attribute__((address_space(1))) void*)g,
        (__attribute__((address_space(3))) void*)l, 16, 0, 0);
}

// ===========================================================================
// BIG-WS PATH (fp8)
// ===========================================================================

// K1: C[n][q] = sum_d mi[d][n]*qi[d][q] via f16 MFMA (A=mi so each lane holds
// 4 consecutive n at fixed q), e = exp(C/sqrt128) -> e8 fp8 [b][q][n]
// + per-128n-tile column sums (fp32, pre-quantization).
// Block 128q x 128n, K=128 one-shot. grid (8 qt, 128 nt, 4 b).
__global__ __launch_bounds__(256, 2)
void k1_mfma(const float* __restrict__ mi, const float* __restrict__ qi,
             unsigned char* __restrict__ e8, float* __restrict__ partial)
{
    const int qb = blockIdx.x << 7;
    const int nb = blockIdx.y << 7;
    const int b  = blockIdx.z;

    __shared__ __align__(16) short AfBf[2][128 * 128]; // f16 as shorts
    __shared__ float red2[2][128];

    short* Bq = AfBf[0];   // [q][d] swizzled (B operand)
    short* An = AfBf[1];   // [n][d] swizzled (A operand)
    unsigned char* T8 = (unsigned char*)AfBf[0];  // reused: [q][n] fp8 swizzled (16KB)

    const int tid  = threadIdx.x;
    const int lane = tid & 63;
    const int w    = tid >> 6;
    const int wn2  = (w >> 1) << 6;   // n-half 0/64
    const int wq   = (w & 1) << 6;    // q-half 0/64
    const int la   = lane & 15;
    const int kg   = lane >> 4;

    // staging: thread covers 8 d-rows x (2 x 4 cols), reg-transpose, swizzled
    {
        const int d8 = (tid >> 4) << 3;       // 0..120
        const int c4 = (tid & 15) << 2;       // 0..60
        const float* qib = qi + (size_t)b * (DE * QCOL) + (size_t)d8 * QCOL + qb;
        const float* mib = mi + (size_t)d8 * NMEM + nb;
#pragma unroll
        for (int half = 0; half < 2; ++half) {
            const int c = c4 + (half << 6);   // 0..124
            f32x4 qv[8], mv[8];
#pragma unroll
            for (int i = 0; i < 8; ++i) {
                qv[i] = *(const f32x4*)(qib + (size_t)i * QCOL + c);
                mv[i] = *(const f32x4*)(mib + (size_t)i * NMEM + c);
            }
#pragma unroll
            for (int j = 0; j < 4; ++j) {
                const int row = c + j;
                const int off = row * 128 + ((((d8 >> 3) ^ FSW(row))) << 3);
                half8v av, bv;
#pragma unroll
                for (int i = 0; i < 8; ++i) {
                    av[i] = (_Float16)qv[i][j];
                    bv[i] = (_Float16)mv[i][j];
                }
                *(half8v*)&Bq[off] = av;
                *(half8v*)&An[off] = bv;
            }
        }
    }
    __syncthreads();

    // MFMA: acc[fm][fn]: row n = wn2+fm*16+(kg<<2)+r ; col q = wq+fn*16+la
    f32x4 acc[4][4];
#pragma unroll
    for (int i = 0; i < 4; ++i)
#pragma unroll
        for (int j = 0; j < 4; ++j) acc[i][j] = (f32x4){0.f, 0.f, 0.f, 0.f};

#pragma unroll
    for (int ks = 0; ks < 4; ++ks) {
        half8v af[4], bf[4];
#pragma unroll
        for (int f = 0; f < 4; ++f) {
            const int ra = wn2 + f * 16 + la;   // A rows: n
            const int rb = wq  + f * 16 + la;   // B rows: q
            af[f] = *(const half8v*)&An[ra * 128 + ((((ks << 2) + kg) ^ FSW(ra)) << 3)];
            bf[f] = *(const half8v*)&Bq[rb * 128 + ((((ks << 2) + kg) ^ FSW(rb)) << 3)];
        }
#pragma unroll
        for (int fm = 0; fm < 4; ++fm)
#pragma unroll
            for (int fn = 0; fn < 4; ++fn)
                acc[fm][fn] = __builtin_amdgcn_mfma_f32_16x16x32_f16(
                    af[fm], bf[fn], acc[fm][fn], 0, 0, 0);
    }

    const float scale = 0.08838834764831845f; // 1/sqrt(128)
#pragma unroll
    for (int fm = 0; fm < 4; ++fm)
#pragma unroll
        for (int fn = 0; fn < 4; ++fn)
#pragma unroll
            for (int r = 0; r < 4; ++r)
                acc[fm][fn][r] = __expf(acc[fm][fn][r] * scale);

    // colsum over n per q-col
    float val[4];
#pragma unroll
    for (int fn = 0; fn < 4; ++fn) {
        float s = 0.f;
#pragma unroll
        for (int fm = 0; fm < 4; ++fm)
#pragma unroll
            for (int r = 0; r < 4; ++r) s += acc[fm][fn][r];
        s += __shfl_xor(s, 16);
        s += __shfl_xor(s, 32);
        val[fn] = s;
    }

    __syncthreads();   // An/Bq reads done; T8 may overwrite AfBf[0]

    // T8[q][n] fp8 swizzled (16B granules, 8/row): 4 consecutive n per u32
#pragma unroll
    for (int fn = 0; fn < 4; ++fn) {
        const int q  = wq + fn * 16 + la;
        const int fq = FSW(q);
#pragma unroll
        for (int fm = 0; fm < 4; ++fm) {
            const int n0 = wn2 + fm * 16 + (kg << 2);
            const unsigned r = pk_fp8x4(acc[fm][fn][0], acc[fm][fn][1],
                                        acc[fm][fn][2], acc[fm][fn][3]);
            *(unsigned*)&T8[q * 128 + (((n0 >> 4) ^ fq) << 4) + (n0 & 15)] = r;
        }
    }
    if (kg == 0) {
#pragma unroll
        for (int fn = 0; fn < 4; ++fn)
            red2[w >> 1][wq + fn * 16 + la] = val[fn];
    }
    __syncthreads();

    if (tid < 128) {
        partial[(size_t)blockIdx.y * 4096 + (b << 10) + qb + tid] =
            red2[0][tid] + red2[1][tid];
    }

    // gather T8 -> e8 global (64B contiguous per thread, 2 threads/row)
    {
        const int ql = tid >> 1;
        const int h  = tid & 1;
        const int fq = FSW(ql);
        unsigned char* dst = e8 + ((size_t)b << 24) + (size_t)(qb + ql) * NMEM + nb;
#pragma unroll
        for (int k = 0; k < 4; ++k) {
            const int m = h * 4 + k;           // granule 0..7
            u32x4 v = *(const u32x4*)&T8[ql * 128 + ((m ^ fq) << 4)];
            *(u32x4*)(dst + m * 16) = v;
        }
    }
}

// K3: read e8 fp8 [q][n], scale by invsum[q], write p fp32 [n][q] via LDS
// transpose. Block = 64 q x 128 n. grid (16,128,4).
__global__ __launch_bounds__(256)
void k3_big(float* __restrict__ p, const unsigned char* __restrict__ e8,
            const float* __restrict__ invsum)
{
    const int qb = blockIdx.x << 6;
    const int nb = blockIdx.y << 7;
    const int b  = blockIdx.z;

    __shared__ __align__(16) float P[64 * 128];

    const int tid = threadIdx.x;

    {
        const int ql  = tid >> 2;
        const int nc  = (tid & 3) << 5;        // 32 n per thread
        const int fq  = FSW(ql);
        const float inv = invsum[(b << 10) + qb + ql];
        const unsigned char* rowp = e8 + ((size_t)b << 24)
                                       + (size_t)(qb + ql) * NMEM + nb + nc;
#pragma unroll
        for (int k = 0; k < 4; ++k) {
            u32x2 v = *(const u32x2*)(rowp + k * 8);
            f32x2 d0 = __builtin_amdgcn_cvt_pk_f32_fp8(v[0], false);
            f32x2 d1 = __builtin_amdgcn_cvt_pk_f32_fp8(v[0], true);
            f32x2 d2 = __builtin_amdgcn_cvt_pk_f32_fp8(v[1], false);
            f32x2 d3 = __builtin_amdgcn_cvt_pk_f32_fp8(v[1], true);
            float f[8];
            f[0] = d0[0] * inv; f[1] = d0[1] * inv;
            f[2] = d1[0] * inv; f[3] = d1[1] * inv;
            f[4] = d2[0] * inv; f[5] = d2[1] * inv;
            f[6] = d3[0] * inv; f[7] = d3[1] * inv;
            const int gg0 = (nc >> 2) + k * 2;
            *(f32x4*)&P[ql * 128 + (((gg0)     ^ fq) << 2)] = *(f32x4*)&f[0];
            *(f32x4*)&P[ql * 128 + (((gg0 + 1) ^ fq) << 2)] = *(f32x4*)&f[4];
        }
    }
    __syncthreads();

    {
        const int tx  = tid & 15;
        const int tyy = tid >> 4;
        float* pb = p + ((size_t)b << 24);
#pragma unroll
        for (int r = 0; r < 2; ++r) {
            const int gg = tyy + 16 * r;
            f32x4 v[4];
#pragma unroll
            for (int i = 0; i < 4; ++i) {
                const int ql = tx * 4 + i;
                v[i] = *(const f32x4*)&P[ql * 128 + ((gg ^ FSW(ql)) << 2)];
            }
#pragma unroll
            for (int jj = 0; jj < 4; ++jj) {
                f32x4 o = {v[0][jj], v[1][jj], v[2][jj], v[3][jj]};
                *(f32x4*)(pb + (size_t)(nb + gg * 4 + jj) * QCOL + qb + tx * 4) = o;
            }
        }
    }
}

// conv8: mo fp32 [512][16384] -> mo8 fp8. 1,048,576 8-float units.
// grid 1024 x 256 thr x 4 units = exact cover.
__global__ __launch_bounds__(256)
void conv8(const float* __restrict__ mo, unsigned char* __restrict__ mo8)
{
    const size_t u = (size_t)blockIdx.x * 256 + threadIdx.x;  // 0..262143
#pragma unroll
    for (int r = 0; r < 4; ++r) {
        const size_t i = (u + (size_t)r * 262144) << 3;       // float index
        f32x4 a = *(const f32x4*)(mo + i);
        f32x4 c = *(const f32x4*)(mo + i + 4);
        u32x2 v;
        v[0] = pk_fp8x4(a[0], a[1], a[2], a[3]);
        v[1] = pk_fp8x4(c[0], c[1], c[2], c[3]);
        *(u32x2*)(mo8 + i) = v;
    }
}

// ---------------------------------------------------------------------------
// K4 split-K fp8: mem_raw[b][o][q] = sum_n mo8[o][n]*e8[b][q][n], K split x4.
// 128x128 tile, 4 waves each 64x64 (4x4 frags of 16x16x32 fp8), BK=128
// bytes (32 steps/split). gl_lds staging, pre-swizzled global src, linear
// LDS dest, XOR-swizzled b64 frag reads. split0 -> out0 raw, 1..3 -> part.
// grid 512 flat XCD-swizzled, 2 blocks/CU.
// ---------------------------------------------------------------------------
__global__ __launch_bounds__(256, 2)
void k4_sk8(const unsigned char* __restrict__ mo8,
            const unsigned char* __restrict__ e8,
            float* __restrict__ out0, float* __restrict__ part)
{
    const int sw    = ((blockIdx.x & 7) << 6) | (blockIdx.x >> 3);
    const int split = sw >> 7;          // 0..3
    const int tile  = sw & 127;
    const int b  = tile >> 5;
    const int ot = (tile >> 3) & 3;
    const int qt = tile & 7;
    const int ob = ot << 7;
    const int qb = qt << 7;
    const int kb = split << 12;         // byte offset (1B/elt)

    __shared__ __align__(16) unsigned char As[2][128 * 128];  // [o][k] 16KB
    __shared__ __align__(16) unsigned char Bs[2][128 * 128];  // [q][k]

    const int tid  = threadIdx.x;
    const int lane = tid & 63;
    const int w    = tid >> 6;
    const int wm   = (w >> 1) << 6;   // 0/64 (o)
    const int wn   = (w & 1) << 6;    // 0/64 (q)
    const int la   = lane & 15;
    const int kg   = lane >> 4;

    // staging: per wave 4 issues/operand; issue covers 8 rows x 128B
    size_t offA[4], offB[4];
    int lbo[4];
#pragma unroll
    for (int i = 0; i < 4; ++i) {
        const int rb  = (w << 5) + (i << 3);       // wave-uniform
        const int row = rb + (lane >> 3);
        const int gs  = (lane & 7) ^ FSW(row);     // pre-swizzled src granule
        offA[i] = (size_t)(ob + row) * NMEM + gs * 16;
        offB[i] = (size_t)(qb + row) * NMEM + gs * 16;
        lbo[i]  = rb * 128;
    }
    const unsigned char* e8b = e8 + ((size_t)b << 24);

#define SK_STAGE(BUF, K0)                                                      \
    do {                                                                       \
        _Pragma("unroll")                                                      \
        for (int i = 0; i < 4; ++i) {                                          \
            gl16c(mo8 + offA[i] + (K0), &As[BUF][lbo[i]]);                     \
            gl16c(e8b + offB[i] + (K0), &Bs[BUF][lbo[i]]);                     \
        }                                                                      \
    } while (0)

    // frag read offsets: k-bytes ks*32 + kg*8 -> granule ks*2+(kg>>1), +8*(kg&1)
    int rA[4][4], rB[4][4];
#pragma unroll
    for (int f = 0; f < 4; ++f) {
        const int rowA = wm + f * 16 + la;
        const int rowB = wn + f * 16 + la;
#pragma unroll
        for (int ks = 0; ks < 4; ++ks) {
            const int g = ks * 2 + (kg >> 1);
            rA[f][ks] = rowA * 128 + ((g ^ FSW(rowA)) << 4) + ((kg & 1) << 3);
            rB[f][ks] = rowB * 128 + ((g ^ FSW(rowB)) << 4) + ((kg & 1) << 3);
        }
    }

    f32x4 acc[4][4];
#pragma unroll
    for (int i = 0; i < 4; ++i)
#pragma unroll
        for (int j = 0; j < 4; ++j) acc[i][j] = (f32x4){0.f, 0.f, 0.f, 0.f};

    SK_STAGE(0, kb);
    __syncthreads();

    int cur = 0;
    for (int t = 0; t < 32; ++t) {
        const bool pf = (t + 1) < 32;
        if (pf) SK_STAGE(cur ^ 1, kb + (t + 1) * 128);

#pragma unroll
        for (int ks = 0; ks < 4; ++ks) {
            long af[4], bf[4];
#pragma unroll
            for (int f = 0; f < 4; ++f) {
                af[f] = *(const long*)&As[cur][rA[f][ks]];
                bf[f] = *(const long*)&Bs[cur][rB[f][ks]];
            }
#pragma unroll
            for (int fm = 0; fm < 4; ++fm)
#pragma unroll
                for (int fn = 0; fn < 4; ++fn)
                    acc[fm][fn] = __builtin_amdgcn_mfma_f32_16x16x32_fp8_fp8(
                        af[fm], bf[fn], acc[fm][fn], 0, 0, 0);
        }
        __syncthreads();
        cur ^= 1;
    }

    // epilogue: C layout col=lane&15 (q), row=(lane>>4)*4+r (o)
    if (split == 0) {
        float* outb = out0 + ((size_t)b << 20);
#pragma unroll
        for (int fm = 0; fm < 4; ++fm)
#pragma unroll
            for (int fn = 0; fn < 4; ++fn)
#pragma unroll
                for (int r = 0; r < 4; ++r) {
                    const int o = ob + wm + fm * 16 + (kg << 2) + r;
                    const int q = qb + wn + fn * 16 + la;
                    outb[(size_t)o * 1024 + q] = acc[fm][fn][r];
                }
    } else {
        float* pp = part + (size_t)(split - 1) * 2097152;
#pragma unroll
        for (int fm = 0; fm < 4; ++fm)
#pragma unroll
            for (int fn = 0; fn < 4; ++fn)
#pragma unroll
                for (int r = 0; r < 4; ++r) {
                    const int o = ob + wm + fm * 16 + (kg << 2) + r;
                    const int q = qb + wn + fn * 16 + la;
                    pp[(((size_t)(b << 9) + o) << 10) + q] = acc[fm][fn][r];
                }
    }
#undef SK_STAGE
}

// K6: out0.mem = (s0 + s1 + s2 + s3) * invsum. grid 2048 x 256.
__global__ __launch_bounds__(256)
void k6_comb(float* __restrict__ out0, const float* __restrict__ part,
             const float* __restrict__ invsum)
{
    const size_t t = (size_t)blockIdx.x * 256 + threadIdx.x;
    if (t < 524288ull) {
        const size_t v = t << 2;
        const int b = (int)(v >> 19);
        const int q = (int)(v & 1023);
        float* dst = out0 + v + ((size_t)b << 19);
        f32x4 s0 = *(const f32x4*)dst;
        f32x4 s1 = *(const f32x4*)(part + v);
        f32x4 s2 = *(const f32x4*)(part + v + 2097152);
        f32x4 s3 = *(const f32x4*)(part + v + 4194304);
        f32x4 inv = *(const f32x4*)(invsum + (b << 10) + q);
        f32x4 o;
#pragma unroll
        for (int h = 0; h < 4; ++h)
            o[h] = (s0[h] + s1[h] + s2[h] + s3[h]) * inv[h];
        *(f32x4*)dst = o;
    }
}

// ===========================================================================
// SMALL-WS FALLBACK PATH (R4 pipeline, fp32/bf16, self-contained)
// ===========================================================================

__global__ __launch_bounds__(256, 2)
void k1_p(const float* __restrict__ mi, const float* __restrict__ qi,
          float* __restrict__ p, float* __restrict__ partial)
{
    const int qb = blockIdx.x << 7;
    const int nb = blockIdx.y << 7;
    const int b  = blockIdx.z;
    const float* __restrict__ qib = qi + (size_t)b * (DE * QCOL);

    __shared__ float As[8][132];
    __shared__ float Bs[8][132];
    __shared__ float red[16][128];

    const int tid = threadIdx.x;
    const int tx  = tid & 15;
    const int ty  = tid >> 4;

    float acc[8][8];
#pragma unroll
    for (int i = 0; i < 8; ++i)
#pragma unroll
        for (int j = 0; j < 8; ++j) acc[i][j] = 0.f;

    const int ld_d = tid >> 5;
    const int ld_n = (tid & 31) << 2;

    for (int k0 = 0; k0 < DE; k0 += 8) {
        float4 av = *(const float4*)(mi  + (size_t)(k0 + ld_d) * NMEM + nb + ld_n);
        float4 bv = *(const float4*)(qib + (size_t)(k0 + ld_d) * QCOL + qb + ld_n);
        *(float4*)&As[ld_d][ld_n] = av;
        *(float4*)&Bs[ld_d][ld_n] = bv;
        __syncthreads();
#pragma unroll
        for (int kk = 0; kk < 8; ++kk) {
            float a[8], bb[8];
            *(float4*)&a[0]  = *(float4*)&As[kk][ty * 8];
            *(float4*)&a[4]  = *(float4*)&As[kk][ty * 8 + 4];
            *(float4*)&bb[0] = *(float4*)&Bs[kk][tx * 8];
            *(float4*)&bb[4] = *(float4*)&Bs[kk][tx * 8 + 4];
#pragma unroll
            for (int i = 0; i < 8; ++i)
#pragma unroll
                for (int j = 0; j < 8; ++j)
                    acc[i][j] += a[i] * bb[j];
        }
        __syncthreads();
    }

    const float scale = 0.08838834764831845f;
    float cs[8];
#pragma unroll
    for (int j = 0; j < 8; ++j) cs[j] = 0.f;
    float* __restrict__ pb = p + ((size_t)b << 24);
#pragma unroll
    for (int i = 0; i < 8; ++i) {
        const int n = nb + ty * 8 + i;
        float e[8];
#pragma unroll
        for (int j = 0; j < 8; ++j) {
            e[j] = __expf(acc[i][j] * scale);
            cs[j] += e[j];
        }
        *(float4*)(pb + ((size_t)n << 10) + qb + tx * 8)     = *(float4*)&e[0];
        *(float4*)(pb + ((size_t)n << 10) + qb + tx * 8 + 4) = *(float4*)&e[4];
    }

#pragma unroll
    for (int j = 0; j < 8; ++j) red[ty][tx * 8 + j] = cs[j];
    __syncthreads();
    if (tid < 128) {
        float s = 0.f;
#pragma unroll
        for (int t = 0; t < 16; ++t) s += red[t][tid];
        partial[(size_t)blockIdx.y * 4096 + (b << 10) + qb + tid] = s;
    }
}

__global__ __launch_bounds__(256)
void k3_small(float* __restrict__ p, const float* __restrict__ invsum)
{
    const size_t stride = (size_t)gridDim.x * blockDim.x;
    for (size_t t = (size_t)blockIdx.x * 256 + threadIdx.x; t < 16777216ull; t += stride) {
        const size_t i = t << 2;
        float4 v = *(float4*)(p + i);
        const int q = (int)(i & 1023);
        const int b = (int)(i >> 24);
        const float4 inv = *(const float4*)(invsum + (b << 10) + q);
        v.x *= inv.x; v.y *= inv.y; v.z *= inv.z; v.w *= inv.w;
        *(float4*)(p + i) = v;
    }
}

__global__ __launch_bounds__(256, 2)
void k4_reg(const float* __restrict__ mo, const float* __restrict__ p,
            float* __restrict__ out0)
{
    const int qb = blockIdx.x << 6;
    const int ob = blockIdx.y << 6;
    const int b  = blockIdx.z;
    const float* __restrict__ pb = p + ((size_t)b << 24);

    __shared__ __align__(16) short As[2][64 * 128];
    __shared__ __align__(16) short Bs[2][64 * 128];

    const int tid  = threadIdx.x;
    const int lane = tid & 63;
    const int w    = tid >> 6;
    const int wm   = (w >> 1) << 5;
    const int wn   = (w & 1) << 5;

    const int aro = tid >> 4;
    const int ak8 = (tid & 15) << 3;
    const int bn8 = (tid >> 4) << 3;
    const int bq4 = (tid & 15) << 2;

    int sA[4], sB[4];
#pragma unroll
    for (int j = 0; j < 4; ++j) {
        const int rlA = aro + 16 * j;
        sA[j] = rlA * 128 + ((((ak8 >> 3) ^ FSW(rlA))) << 3);
        const int rlB = bq4 + j;
        sB[j] = rlB * 128 + ((((bn8 >> 3) ^ FSW(rlB))) << 3);
    }

    const float* __restrict__ gA = mo + (size_t)(ob + aro) * NMEM + ak8;
    const float* __restrict__ gB = pb + (size_t)bn8 * QCOL + qb + bq4;

    f32x4 aA[4][2], aB[8];

#define K4_LOAD(K0)                                                              \
    do {                                                                         \
        _Pragma("unroll")                                                        \
        for (int j = 0; j < 4; ++j) {                                            \
            aA[j][0] = *(const f32x4*)(gA + (size_t)(16 * j) * NMEM + (K0));     \
            aA[j][1] = *(const f32x4*)(gA + (size_t)(16 * j) * NMEM + (K0) + 4); \
        }                                                                        \
        _Pragma("unroll")                                                        \
        for (int i = 0; i < 8; ++i)                                              \
            aB[i] = *(const f32x4*)(gB + ((size_t)(K0) + i) * QCOL);             \
    } while (0)

#define K4_STORE(BUF)                                                            \
    do {                                                                         \
        _Pragma("unroll")                                                        \
        for (int j = 0; j < 4; ++j) {                                            \
            short8v v;                                                           \
            _Pragma("unroll")                                                    \
            for (int h = 0; h < 4; ++h) { v[h] = f2bf(aA[j][0][h]);              \
                                          v[h + 4] = f2bf(aA[j][1][h]); }        \
            *(short8v*)&As[BUF][sA[j]] = v;                                      \
        }                                                                        \
        _Pragma("unroll")                                                        \
        for (int j = 0; j < 4; ++j) {                                            \
            short8v v;                                                           \
            _Pragma("unroll")                                                    \
            for (int i = 0; i < 8; ++i) v[i] = f2bf(aB[i][j]);                   \
            *(short8v*)&Bs[BUF][sB[j]] = v;                                      \
        }                                                                        \
    } while (0)

    f32x4 acc[2][2];
#pragma unroll
    for (int i = 0; i < 2; ++i)
#pragma unroll
        for (int j = 0; j < 2; ++j) acc[i][j] = (f32x4){0.f, 0.f, 0.f, 0.f};

    K4_LOAD(0);
    K4_STORE(0);
    __syncthreads();

    const int la = lane & 15;
    const int kg = lane >> 4;

    int rA[2][4], rB[2][4];
#pragma unroll
    for (int fm = 0; fm < 2; ++fm) {
        const int rowA = wm + la + 16 * fm;
        const int rowB = wn + la + 16 * fm;
#pragma unroll
        for (int s = 0; s < 4; ++s) {
            rA[fm][s] = rowA * 128 + ((((s << 2) + kg) ^ FSW(rowA)) << 3);
            rB[fm][s] = rowB * 128 + ((((s << 2) + kg) ^ FSW(rowB)) << 3);
        }
    }

    int cur = 0;
    for (int t = 0; t < NMEM / 128; ++t) {
        const bool pf = (t + 1) < NMEM / 128;
        if (pf) K4_LOAD((t + 1) * 128);

#pragma unroll
        for (int s = 0; s < 4; ++s) {
            short8v a0 = *(const short8v*)&As[cur][rA[0][s]];
            short8v a1 = *(const short8v*)&As[cur][rA[1][s]];
            short8v b0 = *(const short8v*)&Bs[cur][rB[0][s]];
            short8v b1 = *(const short8v*)&Bs[cur][rB[1][s]];
            acc[0][0] = __builtin_amdgcn_mfma_f32_16x16x32_bf16(a0, b0, acc[0][0], 0, 0, 0);
            acc[0][1] = __builtin_amdgcn_mfma_f32_16x16x32_bf16(a0, b1, acc[0][1], 0, 0, 0);
            acc[1][0] = __builtin_amdgcn_mfma_f32_16x16x32_bf16(a1, b0, acc[1][0], 0, 0, 0);
            acc[1][1] = __builtin_amdgcn_mfma_f32_16x16x32_bf16(a1, b1, acc[1][1], 0, 0, 0);
        }

        if (pf) K4_STORE(cur ^ 1);
        __syncthreads();
        cur ^= 1;
    }

    const int orow = ob + wm + (kg << 2);
    const int qcol = qb + wn + la;
    float* __restrict__ outb = out0 + ((size_t)b << 20);
#pragma unroll
    for (int fm = 0; fm < 2; ++fm)
#pragma unroll
        for (int fn = 0; fn < 2; ++fn)
#pragma unroll
            for (int r = 0; r < 4; ++r)
                outb[(size_t)(orow + 16 * fm + r) * 1024 + qcol + 16 * fn] =
                    acc[fm][fn][r];
#undef K4_LOAD
#undef K4_STORE
}

// ===========================================================================
// SHARED
// ===========================================================================

__global__ __launch_bounds__(256)
void k2b_red(const float* __restrict__ partial, float* __restrict__ invsum)
{
    __shared__ float red[8][32];
    const int col = blockIdx.x * 32 + (threadIdx.x & 31);
    const int g   = threadIdx.x >> 5;
    float s = 0.f;
#pragma unroll
    for (int r = 0; r < 16; ++r)
        s += partial[(size_t)(g * 16 + r) * 4096 + col];
    red[g][threadIdx.x & 31] = s;
    __syncthreads();
    if (threadIdx.x < 32) {
        float t = 0.f;
#pragma unroll
        for (int g2 = 0; g2 < 8; ++g2) t += red[g2][threadIdx.x];
        invsum[col] = 1.0f / t;
    }
}

__global__ __launch_bounds__(256)
void k5_copy(const float* __restrict__ qo, float* __restrict__ out0)
{
    const size_t t = (size_t)blockIdx.x * 256 + threadIdx.x;
    if (t < 524288ull) {
        const size_t i = t << 2;
        const size_t b = i >> 19;
        const float4 v = *(const float4*)(qo + i);
        *(float4*)(out0 + i + ((b + 1) << 19)) = v;
    }
}

extern "C" void kernel_launch(void* const* d_in, const int* in_sizes, int n_in,
                              void* d_out, int out_size, void* d_ws, size_t ws_size,
                              hipStream_t stream)
{
    const float* m_in  = (const float*)d_in[0];
    const float* m_out = (const float*)d_in[1];
    const float* q_in  = (const float*)d_in[2];
    const float* q_out = (const float*)d_in[3];

    float* out0 = (float*)d_out;              // 4,194,304 floats
    float* p    = out0 + 4194304;             // 67,108,864 floats

    unsigned char* e8  = (unsigned char*)d_ws;        // 67,108,864 B fp8
    unsigned char* mo8 = e8 + 67108864;               // 8,388,608 B fp8
    float* wpart = (float*)(e8 + 75497472);           // 3 x 2M fp32 partials

    // scratch in out0's q_out-copy regions (overwritten later by k5):
    float* partial = out0 + 524288;           // b=0 region: [128][4][1024]
    float* invsum  = out0 + 1048576 + 524288; // b=1 region: [4][1024]

    // gate at the R9-proven threshold (known satisfied on this harness)
    const size_t need_big = 176160768ull;

    if (ws_size >= need_big) {
        conv8  <<<dim3(1024),       256, 0, stream>>>(m_out, mo8);
        k1_mfma<<<dim3(8, 128, 4),  256, 0, stream>>>(m_in, q_in, e8, partial);
        k2b_red<<<dim3(128),        256, 0, stream>>>(partial, invsum);
        k3_big <<<dim3(16, 128, 4), 256, 0, stream>>>(p, e8, invsum);
        k4_sk8 <<<dim3(512),        256, 0, stream>>>(mo8, e8, out0, wpart);
        k6_comb<<<dim3(2048),       256, 0, stream>>>(out0, wpart, invsum);
    } else {
        k1_p    <<<dim3(8, 128, 4), 256, 0, stream>>>(m_in, q_in, p, partial);
        k2b_red <<<dim3(128),       256, 0, stream>>>(partial, invsum);
        k3_small<<<dim3(2048),      256, 0, stream>>>(p, invsum);
        k4_reg  <<<dim3(16, 8, 4),  256, 0, stream>>>(m_out, p, out0);
    }
    k5_copy<<<dim3(2048), 256, 0, stream>>>(q_out, out0);
}

// Round 12
// 192.158 us; speedup vs baseline: 9.7362x; 1.0414x over previous
//
#include <hip/hip_runtime.h>
#include <hip/hip_bf16.h>
#include <cstddef>

// m_in  raw-viewed as mi [128][16384]   fp32
// m_out raw-viewed as mo [512][16384]   fp32
// q_in  = qi [4][128][1024]             fp32
// q_out = qo [4][512][1024]             fp32
// out0  = mem_out [4][1024][1024]  (ch 0..511 = mem, ch 512..1023 = q_out copy)
// out1  = p [4][16384][1024] softmax over the 16384 axis
//
// ws layout (big path, gate ws_size >= 176160768):
//   [0, 64MB)        e8  fp8 e4m3 [4][1024][16384]
//   [64MB, 72MB)     mo8 fp8 e4m3 [512][16384]
//   [72MB, 96MB)     split-K partials: 3 x 2M fp32
//   [96MB, 98MB)     partial colsums [128][4][1024] fp32
//   [98MB, +16KB)    invsum [4][1024] fp32

#define DE   128
#define DO   512
#define NMEM 16384
#define QCOL 1024

typedef __attribute__((ext_vector_type(8))) short    short8v;
typedef __attribute__((ext_vector_type(8))) _Float16 half8v;
typedef __attribute__((ext_vector_type(4))) float    f32x4;
typedef __attribute__((ext_vector_type(2))) float    f32x2;
typedef __attribute__((ext_vector_type(2))) unsigned u32x2;
typedef __attribute__((ext_vector_type(4))) unsigned u32x4;

__device__ __forceinline__ short f2bf(float x) {
    union { __hip_bfloat16 h; short s; } u;
    u.h = __float2bfloat16(x);
    return u.s;
}

// pack 4 f32 -> 4 fp8(e4m3) in a u32
__device__ __forceinline__ unsigned pk_fp8x4(float f0, float f1, float f2, float f3) {
    unsigned r = __builtin_amdgcn_cvt_pk_fp8_f32(f0, f1, 0, false);
    r = __builtin_amdgcn_cvt_pk_fp8_f32(f2, f3, r, true);
    return r;
}

// bank-balancing XOR swizzle (granule-level), bijective per 8-row stripe
#define FSW(r) ((((r) >> 3) ^ (r)) & 7)

__device__ __forceinline__ void gl16c(const unsigned char* g, unsigned char* l) {
    __builtin_amdgcn_global_load_lds(
        (const __attribute__((address_space(1))) void*)g,
        (__attribute__((address_space(3))) void*)l, 16, 0, 0);
}

// ===========================================================================
// BIG-WS PATH (fp8)
// ===========================================================================

// K1: C[n][q] = sum_d mi[d][n]*qi[d][q] via f16 MFMA, e=exp -> e8 fp8 [b][q][n]
// + per-128n-tile column sums. Block 128q x 128n, K=128 one-shot.
// Flat grid 4096, XCD-grouped: bid%8 keys (nt,b)-group so the 8 qt-blocks
// sharing an mi tile land on one XCD (L2 locality; R6 FETCH showed 8x re-read).
__global__ __launch_bounds__(256, 2)
void k1_mfma(const float* __restrict__ mi, const float* __restrict__ qi,
             unsigned char* __restrict__ e8, float* __restrict__ partial)
{
    // decode XCD-grouped flat id: bid = c + 8*(qt + 8*ghi); g = ghi*8+c
    const int bid = blockIdx.x;
    const int c   = bid & 7;
    const int r   = bid >> 3;
    const int qt  = r & 7;
    const int g   = ((r >> 3) << 3) | c;   // 0..511
    const int nt  = g & 127;
    const int b   = g >> 7;
    const int qb  = qt << 7;
    const int nb  = nt << 7;

    __shared__ __align__(16) short AfBf[2][128 * 128]; // f16 as shorts
    __shared__ float red2[2][128];

    short* Bq = AfBf[0];   // [q][d] swizzled (B operand)
    short* An = AfBf[1];   // [n][d] swizzled (A operand)
    unsigned char* T8 = (unsigned char*)AfBf[0];  // reused: [q][n] fp8 swizzled

    const int tid  = threadIdx.x;
    const int lane = tid & 63;
    const int w    = tid >> 6;
    const int wn2  = (w >> 1) << 6;   // n-half 0/64
    const int wq   = (w & 1) << 6;    // q-half 0/64
    const int la   = lane & 15;
    const int kg   = lane >> 4;

    // staging: thread covers 8 d-rows x (2 x 4 cols), reg-transpose, swizzled
    {
        const int d8 = (tid >> 4) << 3;       // 0..120
        const int c4 = (tid & 15) << 2;       // 0..60
        const float* qib = qi + (size_t)b * (DE * QCOL) + (size_t)d8 * QCOL + qb;
        const float* mib = mi + (size_t)d8 * NMEM + nb;
#pragma unroll
        for (int half = 0; half < 2; ++half) {
            const int cc = c4 + (half << 6);  // 0..124
            f32x4 qv[8], mv[8];
#pragma unroll
            for (int i = 0; i < 8; ++i) {
                qv[i] = *(const f32x4*)(qib + (size_t)i * QCOL + cc);
                mv[i] = *(const f32x4*)(mib + (size_t)i * NMEM + cc);
            }
#pragma unroll
            for (int j = 0; j < 4; ++j) {
                const int row = cc + j;
                const int off = row * 128 + ((((d8 >> 3) ^ FSW(row))) << 3);
                half8v av, bv;
#pragma unroll
                for (int i = 0; i < 8; ++i) {
                    av[i] = (_Float16)qv[i][j];
                    bv[i] = (_Float16)mv[i][j];
                }
                *(half8v*)&Bq[off] = av;
                *(half8v*)&An[off] = bv;
            }
        }
    }
    __syncthreads();

    // MFMA: acc[fm][fn]: row n = wn2+fm*16+(kg<<2)+r ; col q = wq+fn*16+la
    f32x4 acc[4][4];
#pragma unroll
    for (int i = 0; i < 4; ++i)
#pragma unroll
        for (int j = 0; j < 4; ++j) acc[i][j] = (f32x4){0.f, 0.f, 0.f, 0.f};

#pragma unroll
    for (int ks = 0; ks < 4; ++ks) {
        half8v af[4], bf[4];
#pragma unroll
        for (int f = 0; f < 4; ++f) {
            const int ra = wn2 + f * 16 + la;   // A rows: n
            const int rb = wq  + f * 16 + la;   // B rows: q
            af[f] = *(const half8v*)&An[ra * 128 + ((((ks << 2) + kg) ^ FSW(ra)) << 3)];
            bf[f] = *(const half8v*)&Bq[rb * 128 + ((((ks << 2) + kg) ^ FSW(rb)) << 3)];
        }
#pragma unroll
        for (int fm = 0; fm < 4; ++fm)
#pragma unroll
            for (int fn = 0; fn < 4; ++fn)
                acc[fm][fn] = __builtin_amdgcn_mfma_f32_16x16x32_f16(
                    af[fm], bf[fn], acc[fm][fn], 0, 0, 0);
    }

    const float scale = 0.08838834764831845f; // 1/sqrt(128)
#pragma unroll
    for (int fm = 0; fm < 4; ++fm)
#pragma unroll
        for (int fn = 0; fn < 4; ++fn)
#pragma unroll
            for (int rr = 0; rr < 4; ++rr)
                acc[fm][fn][rr] = __expf(acc[fm][fn][rr] * scale);

    // colsum over n per q-col
    float val[4];
#pragma unroll
    for (int fn = 0; fn < 4; ++fn) {
        float s = 0.f;
#pragma unroll
        for (int fm = 0; fm < 4; ++fm)
#pragma unroll
            for (int rr = 0; rr < 4; ++rr) s += acc[fm][fn][rr];
        s += __shfl_xor(s, 16);
        s += __shfl_xor(s, 32);
        val[fn] = s;
    }

    __syncthreads();   // An/Bq reads done; T8 may overwrite AfBf[0]

    // T8[q][n] fp8 swizzled (16B granules, 8/row): 4 consecutive n per u32
#pragma unroll
    for (int fn = 0; fn < 4; ++fn) {
        const int q  = wq + fn * 16 + la;
        const int fq = FSW(q);
#pragma unroll
        for (int fm = 0; fm < 4; ++fm) {
            const int n0 = wn2 + fm * 16 + (kg << 2);
            const unsigned rv = pk_fp8x4(acc[fm][fn][0], acc[fm][fn][1],
                                         acc[fm][fn][2], acc[fm][fn][3]);
            *(unsigned*)&T8[q * 128 + (((n0 >> 4) ^ fq) << 4) + (n0 & 15)] = rv;
        }
    }
    if (kg == 0) {
#pragma unroll
        for (int fn = 0; fn < 4; ++fn)
            red2[w >> 1][wq + fn * 16 + la] = val[fn];
    }
    __syncthreads();

    if (tid < 128) {
        partial[(size_t)nt * 4096 + (b << 10) + qb + tid] =
            red2[0][tid] + red2[1][tid];
    }

    // gather T8 -> e8 global (64B contiguous per thread, 2 threads/row)
    {
        const int ql = tid >> 1;
        const int h  = tid & 1;
        const int fq = FSW(ql);
        unsigned char* dst = e8 + ((size_t)b << 24) + (size_t)(qb + ql) * NMEM + nb;
#pragma unroll
        for (int k = 0; k < 4; ++k) {
            const int m = h * 4 + k;           // granule 0..7
            u32x4 v = *(const u32x4*)&T8[ql * 128 + ((m ^ fq) << 4)];
            *(u32x4*)(dst + m * 16) = v;
        }
    }
}

// K3: read e8 fp8 [q][n], scale by invsum[q], write p fp32 [n][q] via LDS
// transpose. Block = 64 q x 128 n. grid (16,128,4).
__global__ __launch_bounds__(256)
void k3_big(float* __restrict__ p, const unsigned char* __restrict__ e8,
            const float* __restrict__ invsum)
{
    const int qb = blockIdx.x << 6;
    const int nb = blockIdx.y << 7;
    const int b  = blockIdx.z;

    __shared__ __align__(16) float P[64 * 128];

    const int tid = threadIdx.x;

    {
        const int ql  = tid >> 2;
        const int nc  = (tid & 3) << 5;        // 32 n per thread
        const int fq  = FSW(ql);
        const float inv = invsum[(b << 10) + qb + ql];
        const unsigned char* rowp = e8 + ((size_t)b << 24)
                                       + (size_t)(qb + ql) * NMEM + nb + nc;
#pragma unroll
        for (int k = 0; k < 4; ++k) {
            u32x2 v = *(const u32x2*)(rowp + k * 8);
            f32x2 d0 = __builtin_amdgcn_cvt_pk_f32_fp8(v[0], false);
            f32x2 d1 = __builtin_amdgcn_cvt_pk_f32_fp8(v[0], true);
            f32x2 d2 = __builtin_amdgcn_cvt_pk_f32_fp8(v[1], false);
            f32x2 d3 = __builtin_amdgcn_cvt_pk_f32_fp8(v[1], true);
            float f[8];
            f[0] = d0[0] * inv; f[1] = d0[1] * inv;
            f[2] = d1[0] * inv; f[3] = d1[1] * inv;
            f[4] = d2[0] * inv; f[5] = d2[1] * inv;
            f[6] = d3[0] * inv; f[7] = d3[1] * inv;
            const int gg0 = (nc >> 2) + k * 2;
            *(f32x4*)&P[ql * 128 + (((gg0)     ^ fq) << 2)] = *(f32x4*)&f[0];
            *(f32x4*)&P[ql * 128 + (((gg0 + 1) ^ fq) << 2)] = *(f32x4*)&f[4];
        }
    }
    __syncthreads();

    {
        const int tx  = tid & 15;
        const int tyy = tid >> 4;
        float* pb = p + ((size_t)b << 24);
#pragma unroll
        for (int rr = 0; rr < 2; ++rr) {
            const int gg = tyy + 16 * rr;
            f32x4 v[4];
#pragma unroll
            for (int i = 0; i < 4; ++i) {
                const int ql = tx * 4 + i;
                v[i] = *(const f32x4*)&P[ql * 128 + ((gg ^ FSW(ql)) << 2)];
            }
#pragma unroll
            for (int jj = 0; jj < 4; ++jj) {
                f32x4 o = {v[0][jj], v[1][jj], v[2][jj], v[3][jj]};
                *(f32x4*)(pb + (size_t)(nb + gg * 4 + jj) * QCOL + qb + tx * 4) = o;
            }
        }
    }
}

// conv8: mo fp32 [512][16384] -> mo8 fp8. grid 1024 x 256 thr x 4 units.
__global__ __launch_bounds__(256)
void conv8(const float* __restrict__ mo, unsigned char* __restrict__ mo8)
{
    const size_t u = (size_t)blockIdx.x * 256 + threadIdx.x;  // 0..262143
#pragma unroll
    for (int r = 0; r < 4; ++r) {
        const size_t i = (u + (size_t)r * 262144) << 3;       // float index
        f32x4 a = *(const f32x4*)(mo + i);
        f32x4 c = *(const f32x4*)(mo + i + 4);
        u32x2 v;
        v[0] = pk_fp8x4(a[0], a[1], a[2], a[3]);
        v[1] = pk_fp8x4(c[0], c[1], c[2], c[3]);
        *(u32x2*)(mo8 + i) = v;
    }
}

// ---------------------------------------------------------------------------
// K4 split-K fp8: mem_raw[b][o][q] = sum_n mo8[o][n]*e8[b][q][n], K split x4.
// 128x128 tile, 4 waves each 64x64 (4x4 frags of 16x16x32 fp8), BK=128 bytes.
// gl_lds staging, pre-swizzled global src, linear LDS dest, swizzled b64
// frag reads. split0 -> out0 raw, 1..3 -> part. grid 512 XCD-swizzled.
// ---------------------------------------------------------------------------
__global__ __launch_bounds__(256, 2)
void k4_sk8(const unsigned char* __restrict__ mo8,
            const unsigned char* __restrict__ e8,
            float* __restrict__ out0, float* __restrict__ part)
{
    const int sw    = ((blockIdx.x & 7) << 6) | (blockIdx.x >> 3);
    const int split = sw >> 7;          // 0..3
    const int tile  = sw & 127;
    const int b  = tile >> 5;
    const int ot = (tile >> 3) & 3;
    const int qt = tile & 7;
    const int ob = ot << 7;
    const int qb = qt << 7;
    const int kb = split << 12;         // byte offset

    __shared__ __align__(16) unsigned char As[2][128 * 128];
    __shared__ __align__(16) unsigned char Bs[2][128 * 128];

    const int tid  = threadIdx.x;
    const int lane = tid & 63;
    const int w    = tid >> 6;
    const int wm   = (w >> 1) << 6;   // 0/64 (o)
    const int wn   = (w & 1) << 6;    // 0/64 (q)
    const int la   = lane & 15;
    const int kg   = lane >> 4;

    size_t offA[4], offB[4];
    int lbo[4];
#pragma unroll
    for (int i = 0; i < 4; ++i) {
        const int rb  = (w << 5) + (i << 3);
        const int row = rb + (lane >> 3);
        const int gs  = (lane & 7) ^ FSW(row);
        offA[i] = (size_t)(ob + row) * NMEM + gs * 16;
        offB[i] = (size_t)(qb + row) * NMEM + gs * 16;
        lbo[i]  = rb * 128;
    }
    const unsigned char* e8b = e8 + ((size_t)b << 24);

#define SK_STAGE(BUF, K0)                                                      \
    do {                                                                       \
        _Pragma("unroll")                                                      \
        for (int i = 0; i < 4; ++i) {                                          \
            gl16c(mo8 + offA[i] + (K0), &As[BUF][lbo[i]]);                     \
            gl16c(e8b + offB[i] + (K0), &Bs[BUF][lbo[i]]);                     \
        }                                                                      \
    } while (0)

    int rA[4][4], rB[4][4];
#pragma unroll
    for (int f = 0; f < 4; ++f) {
        const int rowA = wm + f * 16 + la;
        const int rowB = wn + f * 16 + la;
#pragma unroll
        for (int ks = 0; ks < 4; ++ks) {
            const int gg = ks * 2 + (kg >> 1);
            rA[f][ks] = rowA * 128 + ((gg ^ FSW(rowA)) << 4) + ((kg & 1) << 3);
            rB[f][ks] = rowB * 128 + ((gg ^ FSW(rowB)) << 4) + ((kg & 1) << 3);
        }
    }

    f32x4 acc[4][4];
#pragma unroll
    for (int i = 0; i < 4; ++i)
#pragma unroll
        for (int j = 0; j < 4; ++j) acc[i][j] = (f32x4){0.f, 0.f, 0.f, 0.f};

    SK_STAGE(0, kb);
    __syncthreads();

    int cur = 0;
    for (int t = 0; t < 32; ++t) {
        const bool pf = (t + 1) < 32;
        if (pf) SK_STAGE(cur ^ 1, kb + (t + 1) * 128);

#pragma unroll
        for (int ks = 0; ks < 4; ++ks) {
            long af[4], bf[4];
#pragma unroll
            for (int f = 0; f < 4; ++f) {
                af[f] = *(const long*)&As[cur][rA[f][ks]];
                bf[f] = *(const long*)&Bs[cur][rB[f][ks]];
            }
#pragma unroll
            for (int fm = 0; fm < 4; ++fm)
#pragma unroll
                for (int fn = 0; fn < 4; ++fn)
                    acc[fm][fn] = __builtin_amdgcn_mfma_f32_16x16x32_fp8_fp8(
                        af[fm], bf[fn], acc[fm][fn], 0, 0, 0);
        }
        __syncthreads();
        cur ^= 1;
    }

    if (split == 0) {
        float* outb = out0 + ((size_t)b << 20);
#pragma unroll
        for (int fm = 0; fm < 4; ++fm)
#pragma unroll
            for (int fn = 0; fn < 4; ++fn)
#pragma unroll
                for (int rr = 0; rr < 4; ++rr) {
                    const int o = ob + wm + fm * 16 + (kg << 2) + rr;
                    const int q = qb + wn + fn * 16 + la;
                    outb[(size_t)o * 1024 + q] = acc[fm][fn][rr];
                }
    } else {
        float* pp = part + (size_t)(split - 1) * 2097152;
#pragma unroll
        for (int fm = 0; fm < 4; ++fm)
#pragma unroll
            for (int fn = 0; fn < 4; ++fn)
#pragma unroll
                for (int rr = 0; rr < 4; ++rr) {
                    const int o = ob + wm + fm * 16 + (kg << 2) + rr;
                    const int q = qb + wn + fn * 16 + la;
                    pp[(((size_t)(b << 9) + o) << 10) + q] = acc[fm][fn][rr];
                }
    }
#undef SK_STAGE
}

// K56: fused combine + q_out copy (invsum lives in ws -> no aliasing hazard).
// grid 2048 x 256: thread t handles 4 floats of the mem combine AND 4 floats
// of the q_out copy (disjoint out0 regions).
__global__ __launch_bounds__(256)
void k56_fin(float* __restrict__ out0, const float* __restrict__ part,
             const float* __restrict__ invsum, const float* __restrict__ qo)
{
    const size_t t = (size_t)blockIdx.x * 256 + threadIdx.x;
    if (t < 524288ull) {
        const size_t v = t << 2;
        const int b = (int)(v >> 19);
        const int q = (int)(v & 1023);
        // combine: mem channels (first 512 per batch)
        float* dst = out0 + v + ((size_t)b << 19);
        f32x4 s0 = *(const f32x4*)dst;
        f32x4 s1 = *(const f32x4*)(part + v);
        f32x4 s2 = *(const f32x4*)(part + v + 2097152);
        f32x4 s3 = *(const f32x4*)(part + v + 4194304);
        f32x4 inv = *(const f32x4*)(invsum + (b << 10) + q);
        f32x4 o;
#pragma unroll
        for (int h = 0; h < 4; ++h)
            o[h] = (s0[h] + s1[h] + s2[h] + s3[h]) * inv[h];
        *(f32x4*)dst = o;
        // copy: q_out channels (second 512 per batch)
        const f32x4 cv = *(const f32x4*)(qo + v);
        *(f32x4*)(out0 + v + ((size_t)(b + 1) << 19)) = cv;
    }
}

// ===========================================================================
// SMALL-WS FALLBACK PATH (R4 pipeline, self-contained)
// ===========================================================================

__global__ __launch_bounds__(256, 2)
void k1_p(const float* __restrict__ mi, const float* __restrict__ qi,
          float* __restrict__ p, float* __restrict__ partial)
{
    const int qb = blockIdx.x << 7;
    const int nb = blockIdx.y << 7;
    const int b  = blockIdx.z;
    const float* __restrict__ qib = qi + (size_t)b * (DE * QCOL);

    __shared__ float As[8][132];
    __shared__ float Bs[8][132];
    __shared__ float red[16][128];

    const int tid = threadIdx.x;
    const int tx  = tid & 15;
    const int ty  = tid >> 4;

    float acc[8][8];
#pragma unroll
    for (int i = 0; i < 8; ++i)
#pragma unroll
        for (int j = 0; j < 8; ++j) acc[i][j] = 0.f;

    const int ld_d = tid >> 5;
    const int ld_n = (tid & 31) << 2;

    for (int k0 = 0; k0 < DE; k0 += 8) {
        float4 av = *(const float4*)(mi  + (size_t)(k0 + ld_d) * NMEM + nb + ld_n);
        float4 bv = *(const float4*)(qib + (size_t)(k0 + ld_d) * QCOL + qb + ld_n);
        *(float4*)&As[ld_d][ld_n] = av;
        *(float4*)&Bs[ld_d][ld_n] = bv;
        __syncthreads();
#pragma unroll
        for (int kk = 0; kk < 8; ++kk) {
            float a[8], bb[8];
            *(float4*)&a[0]  = *(float4*)&As[kk][ty * 8];
            *(float4*)&a[4]  = *(float4*)&As[kk][ty * 8 + 4];
            *(float4*)&bb[0] = *(float4*)&Bs[kk][tx * 8];
            *(float4*)&bb[4] = *(float4*)&Bs[kk][tx * 8 + 4];
#pragma unroll
            for (int i = 0; i < 8; ++i)
#pragma unroll
                for (int j = 0; j < 8; ++j)
                    acc[i][j] += a[i] * bb[j];
        }
        __syncthreads();
    }

    const float scale = 0.08838834764831845f;
    float cs[8];
#pragma unroll
    for (int j = 0; j < 8; ++j) cs[j] = 0.f;
    float* __restrict__ pb = p + ((size_t)b << 24);
#pragma unroll
    for (int i = 0; i < 8; ++i) {
        const int n = nb + ty * 8 + i;
        float e[8];
#pragma unroll
        for (int j = 0; j < 8; ++j) {
            e[j] = __expf(acc[i][j] * scale);
            cs[j] += e[j];
        }
        *(float4*)(pb + ((size_t)n << 10) + qb + tx * 8)     = *(float4*)&e[0];
        *(float4*)(pb + ((size_t)n << 10) + qb + tx * 8 + 4) = *(float4*)&e[4];
    }

#pragma unroll
    for (int j = 0; j < 8; ++j) red[ty][tx * 8 + j] = cs[j];
    __syncthreads();
    if (tid < 128) {
        float s = 0.f;
#pragma unroll
        for (int t = 0; t < 16; ++t) s += red[t][tid];
        partial[(size_t)blockIdx.y * 4096 + (b << 10) + qb + tid] = s;
    }
}

__global__ __launch_bounds__(256)
void k3_small(float* __restrict__ p, const float* __restrict__ invsum)
{
    const size_t stride = (size_t)gridDim.x * blockDim.x;
    for (size_t t = (size_t)blockIdx.x * 256 + threadIdx.x; t < 16777216ull; t += stride) {
        const size_t i = t << 2;
        float4 v = *(float4*)(p + i);
        const int q = (int)(i & 1023);
        const int b = (int)(i >> 24);
        const float4 inv = *(const float4*)(invsum + (b << 10) + q);
        v.x *= inv.x; v.y *= inv.y; v.z *= inv.z; v.w *= inv.w;
        *(float4*)(p + i) = v;
    }
}

__global__ __launch_bounds__(256, 2)
void k4_reg(const float* __restrict__ mo, const float* __restrict__ p,
            float* __restrict__ out0)
{
    const int qb = blockIdx.x << 6;
    const int ob = blockIdx.y << 6;
    const int b  = blockIdx.z;
    const float* __restrict__ pb = p + ((size_t)b << 24);

    __shared__ __align__(16) short As[2][64 * 128];
    __shared__ __align__(16) short Bs[2][64 * 128];

    const int tid  = threadIdx.x;
    const int lane = tid & 63;
    const int w    = tid >> 6;
    const int wm   = (w >> 1) << 5;
    const int wn   = (w & 1) << 5;

    const int aro = tid >> 4;
    const int ak8 = (tid & 15) << 3;
    const int bn8 = (tid >> 4) << 3;
    const int bq4 = (tid & 15) << 2;

    int sA[4], sB[4];
#pragma unroll
    for (int j = 0; j < 4; ++j) {
        const int rlA = aro + 16 * j;
        sA[j] = rlA * 128 + ((((ak8 >> 3) ^ FSW(rlA))) << 3);
        const int rlB = bq4 + j;
        sB[j] = rlB * 128 + ((((bn8 >> 3) ^ FSW(rlB))) << 3);
    }

    const float* __restrict__ gA = mo + (size_t)(ob + aro) * NMEM + ak8;
    const float* __restrict__ gB = pb + (size_t)bn8 * QCOL + qb + bq4;

    f32x4 aA[4][2], aB[8];

#define K4_LOAD(K0)                                                              \
    do {                                                                         \
        _Pragma("unroll")                                                        \
        for (int j = 0; j < 4; ++j) {                                            \
            aA[j][0] = *(const f32x4*)(gA + (size_t)(16 * j) * NMEM + (K0));     \
            aA[j][1] = *(const f32x4*)(gA + (size_t)(16 * j) * NMEM + (K0) + 4); \
        }                                                                        \
        _Pragma("unroll")                                                        \
        for (int i = 0; i < 8; ++i)                                              \
            aB[i] = *(const f32x4*)(gB + ((size_t)(K0) + i) * QCOL);             \
    } while (0)

#define K4_STORE(BUF)                                                            \
    do {                                                                         \
        _Pragma("unroll")                                                        \
        for (int j = 0; j < 4; ++j) {                                            \
            short8v v;                                                           \
            _Pragma("unroll")                                                    \
            for (int h = 0; h < 4; ++h) { v[h] = f2bf(aA[j][0][h]);              \
                                          v[h + 4] = f2bf(aA[j][1][h]); }        \
            *(short8v*)&As[BUF][sA[j]] = v;                                      \
        }                                                                        \
        _Pragma("unroll")                                                        \
        for (int j = 0; j < 4; ++j) {                                            \
            short8v v;                                                           \
            _Pragma("unroll")                                                    \
            for (int i = 0; i < 8; ++i) v[i] = f2bf(aB[i][j]);                   \
            *(short8v*)&Bs[BUF][sB[j]] = v;                                      \
        }                                                                        \
    } while (0)

    f32x4 acc[2][2];
#pragma unroll
    for (int i = 0; i < 2; ++i)
#pragma unroll
        for (int j = 0; j < 2; ++j) acc[i][j] = (f32x4){0.f, 0.f, 0.f, 0.f};

    K4_LOAD(0);
    K4_STORE(0);
    __syncthreads();

    const int la = lane & 15;
    const int kg = lane >> 4;

    int rA[2][4], rB[2][4];
#pragma unroll
    for (int fm = 0; fm < 2; ++fm) {
        const int rowA = wm + la + 16 * fm;
        const int rowB = wn + la + 16 * fm;
#pragma unroll
        for (int s = 0; s < 4; ++s) {
            rA[fm][s] = rowA * 128 + ((((s << 2) + kg) ^ FSW(rowA)) << 3);
            rB[fm][s] = rowB * 128 + ((((s << 2) + kg) ^ FSW(rowB)) << 3);
        }
    }

    int cur = 0;
    for (int t = 0; t < NMEM / 128; ++t) {
        const bool pf = (t + 1) < NMEM / 128;
        if (pf) K4_LOAD((t + 1) * 128);

#pragma unroll
        for (int s = 0; s < 4; ++s) {
            short8v a0 = *(const short8v*)&As[cur][rA[0][s]];
            short8v a1 = *(const short8v*)&As[cur][rA[1][s]];
            short8v b0 = *(const short8v*)&Bs[cur][rB[0][s]];
            short8v b1 = *(const short8v*)&Bs[cur][rB[1][s]];
            acc[0][0] = __builtin_amdgcn_mfma_f32_16x16x32_bf16(a0, b0, acc[0][0], 0, 0, 0);
            acc[0][1] = __builtin_amdgcn_mfma_f32_16x16x32_bf16(a0, b1, acc[0][1], 0, 0, 0);
            acc[1][0] = __builtin_amdgcn_mfma_f32_16x16x32_bf16(a1, b0, acc[1][0], 0, 0, 0);
            acc[1][1] = __builtin_amdgcn_mfma_f32_16x16x32_bf16(a1, b1, acc[1][1], 0, 0, 0);
        }

        if (pf) K4_STORE(cur ^ 1);
        __syncthreads();
        cur ^= 1;
    }

    const int orow = ob + wm + (kg << 2);
    const int qcol = qb + wn + la;
    float* __restrict__ outb = out0 + ((size_t)b << 20);
#pragma unroll
    for (int fm = 0; fm < 2; ++fm)
#pragma unroll
        for (int fn = 0; fn < 2; ++fn)
#pragma unroll
            for (int r = 0; r < 4; ++r)
                outb[(size_t)(orow + 16 * fm + r) * 1024 + qcol + 16 * fn] =
                    acc[fm][fn][r];
#undef K4_LOAD
#undef K4_STORE
}

__global__ __launch_bounds__(256)
void k5_copy(const float* __restrict__ qo, float* __restrict__ out0)
{
    const size_t t = (size_t)blockIdx.x * 256 + threadIdx.x;
    if (t < 524288ull) {
        const size_t i = t << 2;
        const size_t b = i >> 19;
        const float4 v = *(const float4*)(qo + i);
        *(float4*)(out0 + i + ((b + 1) << 19)) = v;
    }
}

// ===========================================================================
// SHARED
// ===========================================================================

__global__ __launch_bounds__(256)
void k2b_red(const float* __restrict__ partial, float* __restrict__ invsum)
{
    __shared__ float red[8][32];
    const int col = blockIdx.x * 32 + (threadIdx.x & 31);
    const int g   = threadIdx.x >> 5;
    float s = 0.f;
#pragma unroll
    for (int r = 0; r < 16; ++r)
        s += partial[(size_t)(g * 16 + r) * 4096 + col];
    red[g][threadIdx.x & 31] = s;
    __syncthreads();
    if (threadIdx.x < 32) {
        float t = 0.f;
#pragma unroll
        for (int g2 = 0; g2 < 8; ++g2) t += red[g2][threadIdx.x];
        invsum[col] = 1.0f / t;
    }
}

extern "C" void kernel_launch(void* const* d_in, const int* in_sizes, int n_in,
                              void* d_out, int out_size, void* d_ws, size_t ws_size,
                              hipStream_t stream)
{
    const float* m_in  = (const float*)d_in[0];
    const float* m_out = (const float*)d_in[1];
    const float* q_in  = (const float*)d_in[2];
    const float* q_out = (const float*)d_in[3];

    float* out0 = (float*)d_out;              // 4,194,304 floats
    float* p    = out0 + 4194304;             // 67,108,864 floats

    unsigned char* e8  = (unsigned char*)d_ws;        // 64MB fp8
    unsigned char* mo8 = e8 + 67108864;               // 8MB fp8
    float* wpart   = (float*)(e8 + 75497472);         // 3 x 2M fp32 partials
    float* partialW= (float*)(e8 + 100663296);        // [128][4][1024] fp32
    float* invsumW = (float*)(e8 + 102760448);        // [4][1024] fp32

    // fallback scratch in out0's q_out-copy regions (overwritten by k5):
    float* partialF = out0 + 524288;
    float* invsumF  = out0 + 1048576 + 524288;

    const size_t need_big = 176160768ull;

    if (ws_size >= need_big) {
        conv8  <<<dim3(1024),       256, 0, stream>>>(m_out, mo8);
        k1_mfma<<<dim3(4096),       256, 0, stream>>>(m_in, q_in, e8, partialW);
        k2b_red<<<dim3(128),        256, 0, stream>>>(partialW, invsumW);
        k3_big <<<dim3(16, 128, 4), 256, 0, stream>>>(p, e8, invsumW);
        k4_sk8 <<<dim3(512),        256, 0, stream>>>(mo8, e8, out0, wpart);
        k56_fin<<<dim3(2048),       256, 0, stream>>>(out0, wpart, invsumW, q_out);
    } else {
        k1_p    <<<dim3(8, 128, 4), 256, 0, stream>>>(m_in, q_in, p, partialF);
        k2b_red <<<dim3(128),       256, 0, stream>>>(partialF, invsumF);
        k3_small<<<dim3(2048),      256, 0, stream>>>(p, invsumF);
        k4_reg  <<<dim3(16, 8, 4),  256, 0, stream>>>(m_out, p, out0);
        k5_copy <<<dim3(2048),      256, 0, stream>>>(q_out, out0);
    }
}